// Round 2
// baseline (1403.367 us; speedup 1.0000x reference)
//
#include <hip/hip_runtime.h>
#include <hip/hip_bf16.h>

#define NB 32
#define NN 1000
#define NW 16        // 64-bit words per packed adjacency row (16*64 = 1024 >= NN)
#define COMD 64
#define HIDD 256
#define KSEL 500

typedef __hip_bfloat16 bf16;
typedef unsigned long long u64;

__device__ __forceinline__ float b2f(bf16 x){ return __bfloat162float(x); }

// Dtype-flexible loads: template guarantees only one load path is compiled
// per instantiation (no speculative wrong-dtype OOB reads).
template<bool F32>
__device__ __forceinline__ float ldf(const void* p, long i){
  return F32 ? ((const float*)p)[i] : b2f(((const bf16*)p)[i]);
}
template<bool BINT>
__device__ __forceinline__ bool ldb(const void* p, long i){
  return BINT ? (((const int*)p)[i] != 0) : (((const unsigned char*)p)[i] != 0);
}

__device__ __forceinline__ float wave_sum(float v){
#pragma unroll
  for (int o = 32; o > 0; o >>= 1) v += __shfl_down(v, o, 64);
  return v;
}
__device__ __forceinline__ float wave_max(float v){
#pragma unroll
  for (int o = 32; o > 0; o >>= 1) v = fmaxf(v, __shfl_down(v, o, 64));
  return v;
}
__device__ __forceinline__ unsigned fkey(float f){
  unsigned u = __float_as_uint(f);
  return (u & 0x80000000u) ? ~u : (u | 0x80000000u);
}

// ---------------- dtype sniffing ----------------
// distance ~ U[0,1): as bf16, every 16-bit half is a positive bf16 < 1 → < 0x8000.
// As f32, low mantissa halves are ~uniform bits: P(all 64 < 0x8000) = 2^-64.
// bools: byte encoding packs 4 per word (e.g. 0x00010001 > 1); int32 gives {0,1}.
__global__ void k_sniff(const void* dist, const void* adjc,
                        const void* wdc, const void* wdco,
                        int* flags, float* wd_out){
  if (blockIdx.x != 0 || threadIdx.x != 0) return;
  const unsigned* w = (const unsigned*)dist;
  int f32 = 0;
  for (int k = 0; k < 64; ++k) if ((w[k] & 0xFFFFu) >= 0x8000u){ f32 = 1; break; }
  const unsigned* bw = (const unsigned*)adjc;
  int as_int = 1;
  for (int k = 0; k < 64; ++k) if (bw[k] > 1u){ as_int = 0; break; }
  flags[0] = f32; flags[1] = as_int;
  wd_out[0] = f32 ? ((const float*)wdc)[0]  : b2f(((const bf16*)wdc)[0]);
  wd_out[1] = f32 ? ((const float*)wdco)[0] : b2f(((const bf16*)wdco)[0]);
}

// ---------------- distance transpose ----------------
template<bool F32>
__device__ __forceinline__ void dist_t_body(const void* dist, float* distT){
  int t = blockIdx.x * 256 + threadIdx.x;
  if (t >= NN * NN) return;
  int i = t / NN, j = t - i * NN;
  distT[t] = ldf<F32>(dist, (long)j * NN + i);
}
__global__ void k_dist_t(const int* flags, const void* dist, float* distT){
  if (flags[0]) dist_t_body<true>(dist, distT);
  else          dist_t_body<false>(dist, distT);
}

// ---------------- adjacency transpose + bit-pack ----------------
// adjP[b][i][w] bit jj = adj[b][w*64+jj][i]
template<bool BINT>
__device__ __forceinline__ void adj_pack_body(const void* adj, u64* adjP){
  __shared__ unsigned char tile[64][256];
  int t = threadIdx.x;
  int i0 = blockIdx.x * 256;
  int w  = blockIdx.y;
  int b  = blockIdx.z;
  long base = (long)b * NN * NN;
#pragma unroll 4
  for (int jj = 0; jj < 64; ++jj){
    int j = w * 64 + jj;
    int i = i0 + t;
    unsigned char v = 0;
    if (j < NN && i < NN) v = ldb<BINT>(adj, base + (long)j * NN + i) ? 1 : 0;
    tile[jj][t] = v;
  }
  __syncthreads();
  int i = i0 + t;
  if (i < NN){
    u64 word = 0;
#pragma unroll
    for (int jj = 0; jj < 64; ++jj)
      word |= (u64)tile[jj][t] << jj;
    adjP[((long)b * NN + i) * NW + w] = word;
  }
}
__global__ void k_adj_pack(const int* flags, const void* adj, u64* adjP){
  if (flags[1]) adj_pack_body<true>(adj, adjP);
  else          adj_pack_body<false>(adj, adjP);
}

// ---------------- embedding + h_c + attention scalars ----------------
template<bool F32>
__device__ __forceinline__ void embed_body(
    const int* op_idx, const void* vf, const void* cs_tab, const void* tp_tab,
    const void* Wc, const void* asrc, const void* adst,
    float* x_out, float* h_out, float* ed_out, float* es_out){
  int t = threadIdx.x;
  int w = t >> 6, lane = t & 63;
  int g = blockIdx.x * 4 + w;          // b*NN + n
  int n = g % NN;
  int op = op_idx[g];
  float xv = 0.f, hacc = 0.f;
#pragma unroll
  for (int f = 0; f < 15; ++f){
    float x_f;
    if (f < 4)      x_f = ldf<F32>(cs_tab, n * 4 + f);
    else if (f < 6) x_f = ldf<F32>(tp_tab, op * 2 + (f - 4));
    else            x_f = ldf<F32>(vf, (long)g * 9 + (f - 6));
    if (lane == f) xv = x_f;
    hacc += x_f * ldf<F32>(Wc, f * COMD + lane);
  }
  if (lane < 15) x_out[g * 15 + lane] = xv;
  h_out[(long)g * COMD + lane] = hacc;
  float sd = wave_sum(hacc * ldf<F32>(adst, lane));
  float ss = wave_sum(hacc * ldf<F32>(asrc, lane));
  if (lane == 0){ ed_out[g] = sd; es_out[g] = ss; }
}
__global__ void __launch_bounds__(256) k_embed(
    const int* flags, const int* op_idx, const void* vf, const void* cs_tab,
    const void* tp_tab, const void* Wc, const void* asrc, const void* adst,
    float* x_out, float* h_out, float* ed_out, float* es_out){
  if (flags[0]) embed_body<true >(op_idx, vf, cs_tab, tp_tab, Wc, asrc, adst, x_out, h_out, ed_out, es_out);
  else          embed_body<false>(op_idx, vf, cs_tab, tp_tab, Wc, asrc, adst, x_out, h_out, ed_out, es_out);
}

// ---------------- h_co = [x, comp] @ Wco ----------------
template<bool F32>
__device__ __forceinline__ void hco_body(
    const float* x_ws, const float* comp, const void* Wco,
    const void* asrc, const void* adst,
    float* h_out, float* ed_out, float* es_out){
  int t = threadIdx.x;
  int w = t >> 6, lane = t & 63;
  int g = blockIdx.x * 4 + w;
  float xl = (lane < 15) ? x_ws[g * 15 + lane] : 0.f;
  float cv = comp[(long)g * COMD + lane];
  float hacc = 0.f;
#pragma unroll
  for (int f = 0; f < 15; ++f)
    hacc += __shfl(xl, f, 64) * ldf<F32>(Wco, f * COMD + lane);
#pragma unroll
  for (int f = 0; f < 64; ++f)
    hacc += __shfl(cv, f, 64) * ldf<F32>(Wco, (15 + f) * COMD + lane);
  h_out[(long)g * COMD + lane] = hacc;
  float sd = wave_sum(hacc * ldf<F32>(adst, lane));
  float ss = wave_sum(hacc * ldf<F32>(asrc, lane));
  if (lane == 0){ ed_out[g] = sd; es_out[g] = ss; }
}
__global__ void __launch_bounds__(256) k_hco(
    const int* flags, const float* x_ws, const float* comp, const void* Wco,
    const void* asrc, const void* adst,
    float* h_out, float* ed_out, float* es_out){
  if (flags[0]) hco_body<true >(x_ws, comp, Wco, asrc, adst, h_out, ed_out, es_out);
  else          hco_body<false>(x_ws, comp, Wco, asrc, adst, h_out, ed_out, es_out);
}

// ---------------- masked-softmax GAT: 8 dst rows / block ----------------
__global__ void __launch_bounds__(256) k_gat(
    const float* __restrict__ h, const float* __restrict__ ed, const float* __restrict__ es,
    const float* __restrict__ wd_ws, int wd_idx, const u64* __restrict__ adjP,
    const float* __restrict__ distT, float* __restrict__ reps){
  __shared__ float e_lds[8 * NN];
  __shared__ float red[8][4];
  __shared__ float m_sh[8], z_sh[8];
  __shared__ float part[4][8][64];
  int t = threadIdx.x;
  int wv = t >> 6, lane = t & 63;
  int b = blockIdx.y;
  int i0 = blockIdx.x * 8;
  float wd = wd_ws[wd_idx];
  float ed_i[8];
#pragma unroll
  for (int ti = 0; ti < 8; ++ti) ed_i[ti] = ed[b * NN + i0 + ti];
  const u64* adjPb = adjP + (long)b * NN * NW;

  float lmax[8];
#pragma unroll
  for (int ti = 0; ti < 8; ++ti) lmax[ti] = -INFINITY;
  for (int j = t; j < NN; j += 256){
    float esj = es[b * NN + j];
    int w = j >> 6, bit = j & 63;
#pragma unroll
    for (int ti = 0; ti < 8; ++ti){
      int i = i0 + ti;
      float e = -INFINITY;
      if ((adjPb[(long)i * NW + w] >> bit) & 1ull){
        float v = ed_i[ti] + esj + wd * distT[i * NN + j];
        e = (v >= 0.f) ? v : 0.2f * v;
      }
      e_lds[ti * NN + j] = e;
      lmax[ti] = fmaxf(lmax[ti], e);
    }
  }
#pragma unroll
  for (int ti = 0; ti < 8; ++ti){
    float m = wave_max(lmax[ti]);
    if (lane == 0) red[ti][wv] = m;
  }
  __syncthreads();
  if (t < 8) m_sh[t] = fmaxf(fmaxf(red[t][0], red[t][1]), fmaxf(red[t][2], red[t][3]));
  __syncthreads();
  float mreg[8], lsum[8];
#pragma unroll
  for (int ti = 0; ti < 8; ++ti){ mreg[ti] = m_sh[ti]; lsum[ti] = 0.f; }
  for (int j = t; j < NN; j += 256){
#pragma unroll
    for (int ti = 0; ti < 8; ++ti){
      float e = e_lds[ti * NN + j];
      float p = (e > -INFINITY) ? expf(e - mreg[ti]) : 0.f;
      e_lds[ti * NN + j] = p;
      lsum[ti] += p;
    }
  }
#pragma unroll
  for (int ti = 0; ti < 8; ++ti){
    float s = wave_sum(lsum[ti]);
    if (lane == 0) red[ti][wv] = s;
  }
  __syncthreads();
  if (t < 8){
    float z = red[t][0] + red[t][1] + red[t][2] + red[t][3];
    z_sh[t] = (z > 0.f) ? 1.f / z : 0.f;
  }
  __syncthreads();
  float acc[8];
#pragma unroll
  for (int ti = 0; ti < 8; ++ti) acc[ti] = 0.f;
  for (int j = wv; j < NN; j += 4){
    float hv = h[((long)b * NN + j) * COMD + lane];
#pragma unroll
    for (int ti = 0; ti < 8; ++ti) acc[ti] += e_lds[ti * NN + j] * hv;
  }
#pragma unroll
  for (int ti = 0; ti < 8; ++ti) part[wv][ti][lane] = acc[ti];
  __syncthreads();
#pragma unroll
  for (int r = 0; r < 2; ++r){
    int ti = wv + 4 * r;
    float v = part[0][ti][lane] + part[1][ti][lane] + part[2][ti][lane] + part[3][ti][lane];
    v *= z_sh[ti];
    v = (v > 0.f) ? v : expm1f(v);
    reps[((long)b * NN + i0 + ti) * COMD + lane] = v;
  }
}

// ---------------- x_p = sag@Wp + bp, fused score dots ----------------
template<bool F32>
__device__ __forceinline__ void xp_body(
    const int* time_idx, const int* op_idx, const void* vf, const void* time_tab,
    const void* cs_tab, const void* tp_tab, const float* comp, const float* coop,
    const void* Wp, const void* bp, const void* vpd, const void* vpf,
    float* x_p, float* scf, float* scd){
  __shared__ float sag[4][147];
  __shared__ float sred[4][2][4];
  int t = threadIdx.x;
  int base = blockIdx.x * 4;
  for (int idx = t; idx < 4 * 147; idx += 256){
    int nl = idx / 147, f = idx - nl * 147;
    int g = base + nl;
    int n = g % NN;
    float v;
    if (f < 4)       v = ldf<F32>(time_tab, time_idx[g] * 4 + f);
    else if (f < 8)  v = ldf<F32>(cs_tab, n * 4 + (f - 4));
    else if (f < 10) v = ldf<F32>(tp_tab, op_idx[g] * 2 + (f - 8));
    else if (f < 19) v = ldf<F32>(vf, (long)g * 9 + (f - 10));
    else if (f < 83) v = comp[(long)g * COMD + (f - 19)];
    else             v = coop[(long)g * COMD + (f - 83)];
    sag[nl][f] = v;
  }
  __syncthreads();
  int hh = t;
  float a0 = 0.f, a1 = 0.f, a2 = 0.f, a3 = 0.f;
  for (int f = 0; f < 147; ++f){
    float wf = ldf<F32>(Wp, f * HIDD + hh);
    a0 += sag[0][f] * wf; a1 += sag[1][f] * wf;
    a2 += sag[2][f] * wf; a3 += sag[3][f] * wf;
  }
  float bb = ldf<F32>(bp, hh);
  a0 += bb; a1 += bb; a2 += bb; a3 += bb;
  x_p[(long)(base + 0) * HIDD + hh] = a0;
  x_p[(long)(base + 1) * HIDD + hh] = a1;
  x_p[(long)(base + 2) * HIDD + hh] = a2;
  x_p[(long)(base + 3) * HIDD + hh] = a3;
  float vd = ldf<F32>(vpd, hh), vfl = ldf<F32>(vpf, hh);
  float accs[4] = {a0, a1, a2, a3};
  int wv = t >> 6, lane = t & 63;
#pragma unroll
  for (int nl = 0; nl < 4; ++nl){
    float sD = wave_sum(accs[nl] * vd);
    float sF = wave_sum(accs[nl] * vfl);
    if (lane == 0){ sred[nl][0][wv] = sF; sred[nl][1][wv] = sD; }
  }
  __syncthreads();
  if (t < 8){
    int nl = t >> 1, st = t & 1;
    float s = sred[nl][st][0] + sred[nl][st][1] + sred[nl][st][2] + sred[nl][st][3];
    if (st == 0) scf[base + nl] = s; else scd[base + nl] = s;
  }
}
__global__ void __launch_bounds__(256) k_xp(
    const int* flags, const int* time_idx, const int* op_idx, const void* vf,
    const void* time_tab, const void* cs_tab, const void* tp_tab,
    const float* comp, const float* coop, const void* Wp, const void* bp,
    const void* vpd, const void* vpf, float* x_p, float* scf, float* scd){
  if (flags[0]) xp_body<true >(time_idx, op_idx, vf, time_tab, cs_tab, tp_tab, comp, coop, Wp, bp, vpd, vpf, x_p, scf, scd);
  else          xp_body<false>(time_idx, op_idx, vf, time_tab, cs_tab, tp_tab, comp, coop, Wp, bp, vpd, vpf, x_p, scf, scd);
}

// ---------------- top-k gated pool ----------------
template<bool F32, bool BINT>
__device__ __forceinline__ void pool_body(
    const float* scf, const float* scd, const void* mark,
    const float* x_p, void* out){
  __shared__ float s1[NN];
  __shared__ unsigned keys[NN];
  __shared__ float wls[NN];
  __shared__ float red[4];
  __shared__ int cnt;
  __shared__ float bc[2];
  int t = threadIdx.x;
  int wv = t >> 6, lane = t & 63;
  int b = blockIdx.x, pool = blockIdx.y;
  const float* sc = (pool == 0) ? scf : scd;

  float lm = -INFINITY;
  for (int n = t; n < NN; n += 256){
    float r = sc[b * NN + n];
    s1[n] = r;
    lm = fmaxf(lm, r);
  }
  lm = wave_max(lm);
  if (lane == 0) red[wv] = lm;
  __syncthreads();
  if (t == 0) bc[0] = fmaxf(fmaxf(red[0], red[1]), fmaxf(red[2], red[3]));
  __syncthreads();
  float m0 = bc[0];

  lm = -INFINITY;
  for (int n = t; n < NN; n += 256){
    bool mk = ldb<BINT>(mark, b * NN + n);
    bool valid = (pool == 0) ? !mk : mk;
    float v = valid ? (s1[n] - m0) : -1e8f;
    s1[n] = v;
    keys[n] = fkey(v);
    lm = fmaxf(lm, v);
  }
  lm = wave_max(lm);
  if (lane == 0) red[wv] = lm;
  __syncthreads();
  if (t == 0) bc[1] = fmaxf(fmaxf(red[0], red[1]), fmaxf(red[2], red[3]));
  __syncthreads();
  float m1 = bc[1];

  // exact k-th-largest threshold via binary search on monotone key space
  unsigned lo = 0u, hi = 0xFFFFFFFFu;
  for (int it = 0; it < 32; ++it){
    if (lo >= hi) break;
    unsigned mid = lo + (unsigned)((((unsigned long long)(hi - lo)) + 1ull) >> 1);
    if (t == 0) cnt = 0;
    __syncthreads();
    int c = 0;
    for (int n = t; n < NN; n += 256) c += (keys[n] >= mid) ? 1 : 0;
    atomicAdd(&cnt, c);
    __syncthreads();
    int total = cnt;
    __syncthreads();
    if (total >= KSEL) lo = mid; else hi = mid - 1;
  }

  float ls = 0.f;
  for (int n = t; n < NN; n += 256){
    float p = (keys[n] >= lo) ? expf(s1[n] - m1) : 0.f;
    wls[n] = p;
    ls += p;
  }
  ls = wave_sum(ls);
  if (lane == 0) red[wv] = ls;
  __syncthreads();
  if (t == 0){
    float z = red[0] + red[1] + red[2] + red[3];
    bc[0] = (z > 0.f) ? 1.f / z : 0.f;
  }
  __syncthreads();
  float zinv = bc[0];
  for (int n = t; n < NN; n += 256) wls[n] *= zinv;
  __syncthreads();

  int hh = t;
  float ssum = 0.f, smax = -INFINITY;
  for (int n = 0; n < NN; ++n){
    float xv = x_p[((long)b * NN + n) * HIDD + hh];
    float g = wls[n] * xv;
    ssum += g;
    smax = fmaxf(smax, g);
  }
  long ob = (long)b * 1024 + (long)pool * 512;
  if (F32){
    ((float*)out)[ob + hh] = ssum;
    ((float*)out)[ob + 256 + hh] = smax;
  } else {
    ((bf16*)out)[ob + hh] = __float2bfloat16(ssum);
    ((bf16*)out)[ob + 256 + hh] = __float2bfloat16(smax);
  }
}
__global__ void __launch_bounds__(256) k_pool(
    const int* flags, const float* scf, const float* scd, const void* mark,
    const float* x_p, void* out){
  if (flags[0]){
    if (flags[1]) pool_body<true , true >(scf, scd, mark, x_p, out);
    else          pool_body<true , false>(scf, scd, mark, x_p, out);
  } else {
    if (flags[1]) pool_body<false, true >(scf, scd, mark, x_p, out);
    else          pool_body<false, false>(scf, scd, mark, x_p, out);
  }
}

extern "C" void kernel_launch(void* const* d_in, const int* in_sizes, int n_in,
                              void* d_out, int out_size, void* d_ws, size_t ws_size,
                              hipStream_t stream){
  const int*  time_idx = (const int*)d_in[0];
  const int*  op_idx   = (const int*)d_in[1];
  const void* vfeat    = d_in[2];
  const void* dpcs     = d_in[3];
  const void* adj_comp = d_in[4];
  const void* adj_coop = d_in[5];
  const void* dist     = d_in[6];
  const void* time_tab = d_in[7];
  const void* tp_tab   = d_in[8];
  const void* cs_tab   = d_in[9];
  const void* Wc       = d_in[10];
  const void* asrc_c   = d_in[11];
  const void* adst_c   = d_in[12];
  const void* wd_c     = d_in[13];
  const void* Wco      = d_in[14];
  const void* asrc_co  = d_in[15];
  const void* adst_co  = d_in[16];
  const void* wd_co    = d_in[17];
  const void* Wp       = d_in[18];
  const void* bp       = d_in[19];
  const void* vpd      = d_in[20];
  const void* vpf      = d_in[21];

  char* ws = (char*)d_ws;
  size_t o = 0;
  auto alloc = [&](size_t bytes)->char*{
    char* p = ws + o; o = (o + bytes + 255) & ~(size_t)255; return p;
  };
  int*   flags = (int*)alloc(16);
  float* wd_ws = (float*)alloc(8);
  float* distT = (float*)alloc((size_t)NN * NN * 4);
  u64*   adjPc = (u64*)alloc((size_t)NB * NN * NW * 8);
  u64*   adjPo = (u64*)alloc((size_t)NB * NN * NW * 8);
  float* x_ws  = (float*)alloc((size_t)NB * NN * 15 * 4);
  float* h_c   = (float*)alloc((size_t)NB * NN * COMD * 4);
  float* h_o   = (float*)alloc((size_t)NB * NN * COMD * 4);
  float* comp  = (float*)alloc((size_t)NB * NN * COMD * 4);
  float* coop  = (float*)alloc((size_t)NB * NN * COMD * 4);
  float* ed_c  = (float*)alloc((size_t)NB * NN * 4);
  float* es_c  = (float*)alloc((size_t)NB * NN * 4);
  float* ed_o  = (float*)alloc((size_t)NB * NN * 4);
  float* es_o  = (float*)alloc((size_t)NB * NN * 4);
  float* scf   = (float*)alloc((size_t)NB * NN * 4);
  float* scd   = (float*)alloc((size_t)NB * NN * 4);
  float* x_p   = (float*)alloc((size_t)NB * NN * HIDD * 4);

  k_sniff<<<1, 64, 0, stream>>>(dist, adj_comp, wd_c, wd_co, flags, wd_ws);
  k_dist_t<<<dim3((NN * NN + 255) / 256), dim3(256), 0, stream>>>(flags, dist, distT);
  dim3 pg(4, NW, NB);
  k_adj_pack<<<pg, dim3(256), 0, stream>>>(flags, adj_comp, adjPc);
  k_adj_pack<<<pg, dim3(256), 0, stream>>>(flags, adj_coop, adjPo);
  k_embed<<<dim3(NB * NN / 4), dim3(256), 0, stream>>>(
      flags, op_idx, vfeat, cs_tab, tp_tab, Wc, asrc_c, adst_c, x_ws, h_c, ed_c, es_c);
  k_gat<<<dim3(NN / 8, NB), dim3(256), 0, stream>>>(
      h_c, ed_c, es_c, wd_ws, 0, adjPc, distT, comp);
  k_hco<<<dim3(NB * NN / 4), dim3(256), 0, stream>>>(
      flags, x_ws, comp, Wco, asrc_co, adst_co, h_o, ed_o, es_o);
  k_gat<<<dim3(NN / 8, NB), dim3(256), 0, stream>>>(
      h_o, ed_o, es_o, wd_ws, 1, adjPo, distT, coop);
  k_xp<<<dim3(NB * NN / 4), dim3(256), 0, stream>>>(
      flags, time_idx, op_idx, vfeat, time_tab, cs_tab, tp_tab, comp, coop,
      Wp, bp, vpd, vpf, x_p, scf, scd);
  k_pool<<<dim3(NB, 2), dim3(256), 0, stream>>>(flags, scf, scd, dpcs, x_p, d_out);
}

// Round 3
// 1225.425 us; speedup vs baseline: 1.1452x; 1.1452x over previous
//
#include <hip/hip_runtime.h>
#include <hip/hip_bf16.h>

#define NB 32
#define NN 1000
#define NW 16        // 64-bit words per packed adjacency row (16*64 = 1024 >= NN)
#define COMD 64
#define HIDD 256
#define KSEL 500
#define TI 16        // dst rows per k_gat block

typedef __hip_bfloat16 bf16;
typedef unsigned long long u64;

__device__ __forceinline__ float b2f(bf16 x){ return __bfloat162float(x); }

template<bool F32>
__device__ __forceinline__ float ldf(const void* p, long i){
  return F32 ? ((const float*)p)[i] : b2f(((const bf16*)p)[i]);
}
template<bool BINT>
__device__ __forceinline__ bool ldb(const void* p, long i){
  return BINT ? (((const int*)p)[i] != 0) : (((const unsigned char*)p)[i] != 0);
}

__device__ __forceinline__ float wave_sum(float v){
#pragma unroll
  for (int o = 32; o > 0; o >>= 1) v += __shfl_down(v, o, 64);
  return v;
}
__device__ __forceinline__ float wave_max(float v){
#pragma unroll
  for (int o = 32; o > 0; o >>= 1) v = fmaxf(v, __shfl_down(v, o, 64));
  return v;
}
// wave-uniform lane broadcast on the VALU/scalar path (NOT the LDS pipe,
// unlike __shfl which lowers to ds_bpermute).
__device__ __forceinline__ float rdlane(float v, int l){
  return __uint_as_float((unsigned)__builtin_amdgcn_readlane((int)__float_as_uint(v), l));
}
__device__ __forceinline__ unsigned fkey(float f){
  unsigned u = __float_as_uint(f);
  return (u & 0x80000000u) ? ~u : (u | 0x80000000u);
}

// ---------------- dtype sniffing ----------------
__global__ void k_sniff(const void* dist, const void* adjc,
                        const void* wdc, const void* wdco,
                        int* flags, float* wd_out){
  if (blockIdx.x != 0 || threadIdx.x != 0) return;
  const unsigned* w = (const unsigned*)dist;
  int f32 = 0;
  for (int k = 0; k < 64; ++k) if ((w[k] & 0xFFFFu) >= 0x8000u){ f32 = 1; break; }
  const unsigned* bw = (const unsigned*)adjc;
  int as_int = 1;
  for (int k = 0; k < 64; ++k) if (bw[k] > 1u){ as_int = 0; break; }
  flags[0] = f32; flags[1] = as_int;
  wd_out[0] = f32 ? ((const float*)wdc)[0]  : b2f(((const bf16*)wdc)[0]);
  wd_out[1] = f32 ? ((const float*)wdco)[0] : b2f(((const bf16*)wdco)[0]);
}

// ---------------- distance transpose ----------------
template<bool F32>
__device__ __forceinline__ void dist_t_body(const void* dist, float* distT){
  int t = blockIdx.x * 256 + threadIdx.x;
  if (t >= NN * NN) return;
  int i = t / NN, j = t - i * NN;
  distT[t] = ldf<F32>(dist, (long)j * NN + i);
}
__global__ void k_dist_t(const int* flags, const void* dist, float* distT){
  if (flags[0]) dist_t_body<true>(dist, distT);
  else          dist_t_body<false>(dist, distT);
}

// ---------------- adjacency transpose + bit-pack ----------------
template<bool BINT>
__device__ __forceinline__ void adj_pack_body(const void* adj, u64* adjP){
  __shared__ unsigned char tile[64][256];
  int t = threadIdx.x;
  int i0 = blockIdx.x * 256;
  int w  = blockIdx.y;
  int b  = blockIdx.z;
  long base = (long)b * NN * NN;
#pragma unroll 4
  for (int jj = 0; jj < 64; ++jj){
    int j = w * 64 + jj;
    int i = i0 + t;
    unsigned char v = 0;
    if (j < NN && i < NN) v = ldb<BINT>(adj, base + (long)j * NN + i) ? 1 : 0;
    tile[jj][t] = v;
  }
  __syncthreads();
  int i = i0 + t;
  if (i < NN){
    u64 word = 0;
#pragma unroll
    for (int jj = 0; jj < 64; ++jj)
      word |= (u64)tile[jj][t] << jj;
    adjP[((long)b * NN + i) * NW + w] = word;
  }
}
__global__ void k_adj_pack(const int* flags, const void* adj, u64* adjP){
  if (flags[1]) adj_pack_body<true>(adj, adjP);
  else          adj_pack_body<false>(adj, adjP);
}

// ---------------- embedding + h_c + attention scalars ----------------
template<bool F32>
__device__ __forceinline__ void embed_body(
    const int* op_idx, const void* vf, const void* cs_tab, const void* tp_tab,
    const void* Wc, const void* asrc, const void* adst,
    float* x_out, float* h_out, float* ed_out, float* es_out){
  int t = threadIdx.x;
  int w = t >> 6, lane = t & 63;
  int g = blockIdx.x * 4 + w;          // b*NN + n
  int n = g % NN;
  int op = op_idx[g];
  float xv = 0.f, hacc = 0.f;
#pragma unroll
  for (int f = 0; f < 15; ++f){
    float x_f;
    if (f < 4)      x_f = ldf<F32>(cs_tab, n * 4 + f);
    else if (f < 6) x_f = ldf<F32>(tp_tab, op * 2 + (f - 4));
    else            x_f = ldf<F32>(vf, (long)g * 9 + (f - 6));
    if (lane == f) xv = x_f;
    hacc += x_f * ldf<F32>(Wc, f * COMD + lane);
  }
  if (lane < 15) x_out[g * 15 + lane] = xv;
  h_out[(long)g * COMD + lane] = hacc;
  float sd = wave_sum(hacc * ldf<F32>(adst, lane));
  float ss = wave_sum(hacc * ldf<F32>(asrc, lane));
  if (lane == 0){ ed_out[g] = sd; es_out[g] = ss; }
}
__global__ void __launch_bounds__(256) k_embed(
    const int* flags, const int* op_idx, const void* vf, const void* cs_tab,
    const void* tp_tab, const void* Wc, const void* asrc, const void* adst,
    float* x_out, float* h_out, float* ed_out, float* es_out){
  if (flags[0]) embed_body<true >(op_idx, vf, cs_tab, tp_tab, Wc, asrc, adst, x_out, h_out, ed_out, es_out);
  else          embed_body<false>(op_idx, vf, cs_tab, tp_tab, Wc, asrc, adst, x_out, h_out, ed_out, es_out);
}

// ---------------- h_co = [x, comp] @ Wco ----------------
template<bool F32>
__device__ __forceinline__ void hco_body(
    const float* x_ws, const float* comp, const void* Wco,
    const void* asrc, const void* adst,
    float* h_out, float* ed_out, float* es_out){
  int t = threadIdx.x;
  int w = t >> 6, lane = t & 63;
  int g = blockIdx.x * 4 + w;
  float xl = (lane < 15) ? x_ws[g * 15 + lane] : 0.f;
  float cv = comp[(long)g * COMD + lane];
  float hacc = 0.f;
#pragma unroll
  for (int f = 0; f < 15; ++f)
    hacc += rdlane(xl, f) * ldf<F32>(Wco, f * COMD + lane);
#pragma unroll
  for (int f = 0; f < 64; ++f)
    hacc += rdlane(cv, f) * ldf<F32>(Wco, (15 + f) * COMD + lane);
  h_out[(long)g * COMD + lane] = hacc;
  float sd = wave_sum(hacc * ldf<F32>(adst, lane));
  float ss = wave_sum(hacc * ldf<F32>(asrc, lane));
  if (lane == 0){ ed_out[g] = sd; es_out[g] = ss; }
}
__global__ void __launch_bounds__(256) k_hco(
    const int* flags, const float* x_ws, const float* comp, const void* Wco,
    const void* asrc, const void* adst,
    float* h_out, float* ed_out, float* es_out){
  if (flags[0]) hco_body<true >(x_ws, comp, Wco, asrc, adst, h_out, ed_out, es_out);
  else          hco_body<false>(x_ws, comp, Wco, asrc, adst, h_out, ed_out, es_out);
}

// ---------------- masked-softmax GAT ----------------
// TI dst rows / block. Scores & softmax weights live in REGISTERS with a
// wave-stripe j-mapping (wave wv owns j in {c*256 + wv*64 + lane}); phase 3
// broadcasts alpha via v_readlane (VALU) -> zero LDS-pipe pressure.
__global__ void __launch_bounds__(256) k_gat(
    const float* __restrict__ h, const float* __restrict__ ed, const float* __restrict__ es,
    const float* __restrict__ wd_ws, int wd_idx, const u64* __restrict__ adjP,
    const float* __restrict__ distT, float* __restrict__ reps){
  __shared__ float redm[TI][4], redz[TI][4];
  __shared__ float m_sh[TI], z_sh[TI];
  __shared__ float part[4][TI][64];
  int t = threadIdx.x;
  int wv = t >> 6, lane = t & 63;
  int b = blockIdx.y;
  int i0 = blockIdx.x * TI;
  float wd = wd_ws[wd_idx];
  const u64* adjPb = adjP + (long)b * NN * NW;

  float ed_i[TI];
#pragma unroll
  for (int ti = 0; ti < TI; ++ti)
    ed_i[ti] = (i0 + ti < NN) ? ed[b * NN + i0 + ti] : 0.f;

  float p[TI][4];
  float m_l[TI];
#pragma unroll
  for (int ti = 0; ti < TI; ++ti) m_l[ti] = -INFINITY;

  // phase 1: scores into registers
#pragma unroll
  for (int c = 0; c < 4; ++c){
    int j = c * 256 + wv * 64 + lane;
    float esj = (j < NN) ? es[b * NN + j] : 0.f;
    int wi = c * 4 + wv;
#pragma unroll
    for (int ti = 0; ti < TI; ++ti){
      int i = i0 + ti;
      u64 word = (i < NN) ? adjPb[(long)i * NW + wi] : 0ull;
      bool edge = (word >> lane) & 1ull;
      float d = distT[(long)i * NN + j];      // garbage if masked; selected away
      float v = ed_i[ti] + esj + wd * d;
      v = fmaxf(v, 0.2f * v);                 // leaky_relu (valid since 0.2>0)
      float e = edge ? v : -INFINITY;
      p[ti][c] = e;
      m_l[ti] = fmaxf(m_l[ti], e);
    }
  }
#pragma unroll
  for (int ti = 0; ti < TI; ++ti){
    float m = wave_max(m_l[ti]);
    if (lane == 0) redm[ti][wv] = m;
  }
  __syncthreads();
  if (t < TI) m_sh[t] = fmaxf(fmaxf(redm[t][0], redm[t][1]), fmaxf(redm[t][2], redm[t][3]));
  __syncthreads();

  // phase 2: exp + row sum (registers)
  float z_l[TI];
#pragma unroll
  for (int ti = 0; ti < TI; ++ti){
    float m = m_sh[ti];
    float zs = 0.f;
#pragma unroll
    for (int c = 0; c < 4; ++c){
      float e = p[ti][c];
      float pp = (e > -INFINITY) ? __expf(e - m) : 0.f;
      p[ti][c] = pp;
      zs += pp;
    }
    z_l[ti] = zs;
  }
#pragma unroll
  for (int ti = 0; ti < TI; ++ti){
    float s = wave_sum(z_l[ti]);
    if (lane == 0) redz[ti][wv] = s;
  }
  __syncthreads();
  if (t < TI){
    float z = redz[t][0] + redz[t][1] + redz[t][2] + redz[t][3];
    z_sh[t] = (z > 0.f) ? 1.f / z : 0.f;
  }
  __syncthreads();

  // phase 3: acc[ti] += alpha_j * h[j][lane], alpha via readlane broadcast
  float acc[TI];
#pragma unroll
  for (int ti = 0; ti < TI; ++ti) acc[ti] = 0.f;
#pragma unroll
  for (int c = 0; c < 4; ++c){
    int jbase = c * 256 + wv * 64;
#pragma unroll 4
    for (int jj = 0; jj < 64; ++jj){
      int j = jbase + jj;
      float hv = (j < NN) ? h[((long)b * NN + j) * COMD + lane] : 0.f;
#pragma unroll
      for (int ti = 0; ti < TI; ++ti)
        acc[ti] += rdlane(p[ti][c], jj) * hv;
    }
  }
#pragma unroll
  for (int ti = 0; ti < TI; ++ti) part[wv][ti][lane] = acc[ti];
  __syncthreads();
#pragma unroll
  for (int r = 0; r < 4; ++r){
    int ti = r * 4 + wv;
    float v = part[0][ti][lane] + part[1][ti][lane] + part[2][ti][lane] + part[3][ti][lane];
    v *= z_sh[ti];
    v = (v > 0.f) ? v : expm1f(v);
    if (i0 + ti < NN)
      reps[((long)b * NN + i0 + ti) * COMD + lane] = v;
  }
}

// ---------------- x_p = sag@Wp + bp, fused score dots ----------------
// 8 nodes/block; sag staged in LDS once, then lane-distributed into 3 regs
// per node; inner loop uses readlane broadcast (VALU) instead of LDS reads.
template<bool F32>
__device__ __forceinline__ void xp_body(
    const int* time_idx, const int* op_idx, const void* vf, const void* time_tab,
    const void* cs_tab, const void* tp_tab, const float* comp, const float* coop,
    const void* Wp, const void* bp, const void* vpd, const void* vpf,
    float* x_p, float* scf, float* scd){
  __shared__ float sag[8][148];
  __shared__ float sred[8][2][4];
  int t = threadIdx.x;
  int wv = t >> 6, lane = t & 63;
  int base = blockIdx.x * 8;
  for (int idx = t; idx < 8 * 147; idx += 256){
    int nl = idx / 147, f = idx - nl * 147;
    int g = base + nl;
    int n = g % NN;
    float v;
    if (f < 4)       v = ldf<F32>(time_tab, time_idx[g] * 4 + f);
    else if (f < 8)  v = ldf<F32>(cs_tab, n * 4 + (f - 4));
    else if (f < 10) v = ldf<F32>(tp_tab, op_idx[g] * 2 + (f - 8));
    else if (f < 19) v = ldf<F32>(vf, (long)g * 9 + (f - 10));
    else if (f < 83) v = comp[(long)g * COMD + (f - 19)];
    else             v = coop[(long)g * COMD + (f - 83)];
    sag[nl][f] = v;
  }
  __syncthreads();
  float sg[8][3];
#pragma unroll
  for (int nl = 0; nl < 8; ++nl){
#pragma unroll
    for (int r = 0; r < 3; ++r){
      int f = r * 64 + lane;
      sg[nl][r] = (f < 147) ? sag[nl][f] : 0.f;
    }
  }
  int hh = t;
  float a[8];
#pragma unroll
  for (int nl = 0; nl < 8; ++nl) a[nl] = 0.f;
#pragma unroll
  for (int r = 0; r < 3; ++r){
    int flim = (r < 2) ? 64 : 19;   // 147 = 64+64+19
    for (int fl = 0; fl < flim; ++fl){
      float wf = ldf<F32>(Wp, (r * 64 + fl) * HIDD + hh);
#pragma unroll
      for (int nl = 0; nl < 8; ++nl)
        a[nl] += rdlane(sg[nl][r], fl) * wf;
    }
  }
  float bb = ldf<F32>(bp, hh);
#pragma unroll
  for (int nl = 0; nl < 8; ++nl){
    a[nl] += bb;
    x_p[(long)(base + nl) * HIDD + hh] = a[nl];
  }
  float vd = ldf<F32>(vpd, hh), vfl = ldf<F32>(vpf, hh);
#pragma unroll
  for (int nl = 0; nl < 8; ++nl){
    float sD = wave_sum(a[nl] * vd);
    float sF = wave_sum(a[nl] * vfl);
    if (lane == 0){ sred[nl][0][wv] = sF; sred[nl][1][wv] = sD; }
  }
  __syncthreads();
  if (t < 16){
    int nl = t >> 1, st = t & 1;
    float s = sred[nl][st][0] + sred[nl][st][1] + sred[nl][st][2] + sred[nl][st][3];
    if (st == 0) scf[base + nl] = s; else scd[base + nl] = s;
  }
}
__global__ void __launch_bounds__(256) k_xp(
    const int* flags, const int* time_idx, const int* op_idx, const void* vf,
    const void* time_tab, const void* cs_tab, const void* tp_tab,
    const float* comp, const float* coop, const void* Wp, const void* bp,
    const void* vpd, const void* vpf, float* x_p, float* scf, float* scd){
  if (flags[0]) xp_body<true >(time_idx, op_idx, vf, time_tab, cs_tab, tp_tab, comp, coop, Wp, bp, vpd, vpf, x_p, scf, scd);
  else          xp_body<false>(time_idx, op_idx, vf, time_tab, cs_tab, tp_tab, comp, coop, Wp, bp, vpd, vpf, x_p, scf, scd);
}

// ---------------- top-k gated pool ----------------
// grid (NB, 2, 4): blockIdx.z picks a 64-channel slice; score/top-k phases
// are redundantly recomputed per slice (cheap) for 4x more parallelism.
template<bool F32, bool BINT>
__device__ __forceinline__ void pool_body(
    const float* scf, const float* scd, const void* mark,
    const float* x_p, void* out){
  __shared__ float s1[NN];
  __shared__ unsigned keys[NN];
  __shared__ float wls[NN];
  __shared__ float red[4];
  __shared__ int cnt;
  __shared__ float bc[2];
  __shared__ float part_s[4][64], part_m[4][64];
  int t = threadIdx.x;
  int wv = t >> 6, lane = t & 63;
  int b = blockIdx.x, pool = blockIdx.y;
  int c0 = blockIdx.z * 64;
  const float* sc = (pool == 0) ? scf : scd;

  float lm = -INFINITY;
  for (int n = t; n < NN; n += 256){
    float r = sc[b * NN + n];
    s1[n] = r;
    lm = fmaxf(lm, r);
  }
  lm = wave_max(lm);
  if (lane == 0) red[wv] = lm;
  __syncthreads();
  if (t == 0) bc[0] = fmaxf(fmaxf(red[0], red[1]), fmaxf(red[2], red[3]));
  __syncthreads();
  float m0 = bc[0];

  lm = -INFINITY;
  for (int n = t; n < NN; n += 256){
    bool mk = ldb<BINT>(mark, b * NN + n);
    bool valid = (pool == 0) ? !mk : mk;
    float v = valid ? (s1[n] - m0) : -1e8f;
    s1[n] = v;
    keys[n] = fkey(v);
    lm = fmaxf(lm, v);
  }
  lm = wave_max(lm);
  if (lane == 0) red[wv] = lm;
  __syncthreads();
  if (t == 0) bc[1] = fmaxf(fmaxf(red[0], red[1]), fmaxf(red[2], red[3]));
  __syncthreads();
  float m1 = bc[1];

  unsigned lo = 0u, hi = 0xFFFFFFFFu;
  for (int it = 0; it < 32; ++it){
    if (lo >= hi) break;
    unsigned mid = lo + (unsigned)((((unsigned long long)(hi - lo)) + 1ull) >> 1);
    if (t == 0) cnt = 0;
    __syncthreads();
    int c = 0;
    for (int n = t; n < NN; n += 256) c += (keys[n] >= mid) ? 1 : 0;
    atomicAdd(&cnt, c);
    __syncthreads();
    int total = cnt;
    __syncthreads();
    if (total >= KSEL) lo = mid; else hi = mid - 1;
  }

  float ls = 0.f;
  for (int n = t; n < NN; n += 256){
    float p = (keys[n] >= lo) ? __expf(s1[n] - m1) : 0.f;
    wls[n] = p;
    ls += p;
  }
  ls = wave_sum(ls);
  if (lane == 0) red[wv] = ls;
  __syncthreads();
  if (t == 0){
    float z = red[0] + red[1] + red[2] + red[3];
    bc[0] = (z > 0.f) ? 1.f / z : 0.f;
  }
  __syncthreads();
  float zinv = bc[0];
  for (int n = t; n < NN; n += 256) wls[n] *= zinv;
  __syncthreads();

  int c = c0 + lane;
  float ssum = 0.f, smax = -INFINITY;
  for (int n = wv; n < NN; n += 4){
    float xv = x_p[((long)b * NN + n) * HIDD + c];
    float g = wls[n] * xv;
    ssum += g;
    smax = fmaxf(smax, g);
  }
  part_s[wv][lane] = ssum;
  part_m[wv][lane] = smax;
  __syncthreads();
  if (wv == 0){
    float s = part_s[0][lane] + part_s[1][lane] + part_s[2][lane] + part_s[3][lane];
    float m = fmaxf(fmaxf(part_m[0][lane], part_m[1][lane]),
                    fmaxf(part_m[2][lane], part_m[3][lane]));
    long ob = (long)b * 1024 + (long)pool * 512;
    if (F32){
      ((float*)out)[ob + c] = s;
      ((float*)out)[ob + 256 + c] = m;
    } else {
      ((bf16*)out)[ob + c] = __float2bfloat16(s);
      ((bf16*)out)[ob + 256 + c] = __float2bfloat16(m);
    }
  }
}
__global__ void __launch_bounds__(256) k_pool(
    const int* flags, const float* scf, const float* scd, const void* mark,
    const float* x_p, void* out){
  if (flags[0]){
    if (flags[1]) pool_body<true , true >(scf, scd, mark, x_p, out);
    else          pool_body<true , false>(scf, scd, mark, x_p, out);
  } else {
    if (flags[1]) pool_body<false, true >(scf, scd, mark, x_p, out);
    else          pool_body<false, false>(scf, scd, mark, x_p, out);
  }
}

extern "C" void kernel_launch(void* const* d_in, const int* in_sizes, int n_in,
                              void* d_out, int out_size, void* d_ws, size_t ws_size,
                              hipStream_t stream){
  const int*  time_idx = (const int*)d_in[0];
  const int*  op_idx   = (const int*)d_in[1];
  const void* vfeat    = d_in[2];
  const void* dpcs     = d_in[3];
  const void* adj_comp = d_in[4];
  const void* adj_coop = d_in[5];
  const void* dist     = d_in[6];
  const void* time_tab = d_in[7];
  const void* tp_tab   = d_in[8];
  const void* cs_tab   = d_in[9];
  const void* Wc       = d_in[10];
  const void* asrc_c   = d_in[11];
  const void* adst_c   = d_in[12];
  const void* wd_c     = d_in[13];
  const void* Wco      = d_in[14];
  const void* asrc_co  = d_in[15];
  const void* adst_co  = d_in[16];
  const void* wd_co    = d_in[17];
  const void* Wp       = d_in[18];
  const void* bp       = d_in[19];
  const void* vpd      = d_in[20];
  const void* vpf      = d_in[21];

  char* ws = (char*)d_ws;
  size_t o = 0;
  auto alloc = [&](size_t bytes)->char*{
    char* p = ws + o; o = (o + bytes + 255) & ~(size_t)255; return p;
  };
  int*   flags = (int*)alloc(16);
  float* wd_ws = (float*)alloc(8);
  float* distT = (float*)alloc((size_t)NN * NN * 4);
  u64*   adjPc = (u64*)alloc((size_t)NB * NN * NW * 8);
  u64*   adjPo = (u64*)alloc((size_t)NB * NN * NW * 8);
  float* x_ws  = (float*)alloc((size_t)NB * NN * 15 * 4);
  float* h_c   = (float*)alloc((size_t)NB * NN * COMD * 4);
  float* h_o   = (float*)alloc((size_t)NB * NN * COMD * 4);
  float* comp  = (float*)alloc((size_t)NB * NN * COMD * 4);
  float* coop  = (float*)alloc((size_t)NB * NN * COMD * 4);
  float* ed_c  = (float*)alloc((size_t)NB * NN * 4);
  float* es_c  = (float*)alloc((size_t)NB * NN * 4);
  float* ed_o  = (float*)alloc((size_t)NB * NN * 4);
  float* es_o  = (float*)alloc((size_t)NB * NN * 4);
  float* scf   = (float*)alloc((size_t)NB * NN * 4);
  float* scd   = (float*)alloc((size_t)NB * NN * 4);
  float* x_p   = (float*)alloc((size_t)NB * NN * HIDD * 4);

  k_sniff<<<1, 64, 0, stream>>>(dist, adj_comp, wd_c, wd_co, flags, wd_ws);
  k_dist_t<<<dim3((NN * NN + 255) / 256), dim3(256), 0, stream>>>(flags, dist, distT);
  dim3 pg(4, NW, NB);
  k_adj_pack<<<pg, dim3(256), 0, stream>>>(flags, adj_comp, adjPc);
  k_adj_pack<<<pg, dim3(256), 0, stream>>>(flags, adj_coop, adjPo);
  k_embed<<<dim3(NB * NN / 4), dim3(256), 0, stream>>>(
      flags, op_idx, vfeat, cs_tab, tp_tab, Wc, asrc_c, adst_c, x_ws, h_c, ed_c, es_c);
  k_gat<<<dim3((NN + TI - 1) / TI, NB), dim3(256), 0, stream>>>(
      h_c, ed_c, es_c, wd_ws, 0, adjPc, distT, comp);
  k_hco<<<dim3(NB * NN / 4), dim3(256), 0, stream>>>(
      flags, x_ws, comp, Wco, asrc_co, adst_co, h_o, ed_o, es_o);
  k_gat<<<dim3((NN + TI - 1) / TI, NB), dim3(256), 0, stream>>>(
      h_o, ed_o, es_o, wd_ws, 1, adjPo, distT, coop);
  k_xp<<<dim3(NB * NN / 8), dim3(256), 0, stream>>>(
      flags, time_idx, op_idx, vfeat, time_tab, cs_tab, tp_tab, comp, coop,
      Wp, bp, vpd, vpf, x_p, scf, scd);
  k_pool<<<dim3(NB, 2, 4), dim3(256), 0, stream>>>(flags, scf, scd, dpcs, x_p, d_out);
}

// Round 4
// 891.941 us; speedup vs baseline: 1.5734x; 1.3739x over previous
//
#include <hip/hip_runtime.h>
#include <hip/hip_bf16.h>

#define NB 32
#define NN 1000
#define NW 16        // 64-bit words per packed adjacency row (16*64 = 1024 >= NN)
#define COMD 64
#define HIDD 256
#define KSEL 500
#define TI 16        // dst rows per k_gat block

typedef __hip_bfloat16 bf16;
typedef unsigned long long u64;
typedef __attribute__((ext_vector_type(4))) float f32x4;
typedef __attribute__((ext_vector_type(8))) short s16x8;

__device__ __forceinline__ float b2f(bf16 x){ return __bfloat162float(x); }

template<bool F32>
__device__ __forceinline__ float ldf(const void* p, long i){
  return F32 ? ((const float*)p)[i] : b2f(((const bf16*)p)[i]);
}
template<bool BINT>
__device__ __forceinline__ bool ldb(const void* p, long i){
  return BINT ? (((const int*)p)[i] != 0) : (((const unsigned char*)p)[i] != 0);
}

__device__ __forceinline__ float wave_sum(float v){
#pragma unroll
  for (int o = 32; o > 0; o >>= 1) v += __shfl_down(v, o, 64);
  return v;
}
__device__ __forceinline__ float wave_max(float v){
#pragma unroll
  for (int o = 32; o > 0; o >>= 1) v = fmaxf(v, __shfl_down(v, o, 64));
  return v;
}
__device__ __forceinline__ float rdlane(float v, int l){
  return __uint_as_float((unsigned)__builtin_amdgcn_readlane((int)__float_as_uint(v), l));
}
__device__ __forceinline__ unsigned fkey(float f){
  unsigned u = __float_as_uint(f);
  return (u & 0x80000000u) ? ~u : (u | 0x80000000u);
}
// split fp32 into bf16 hi + bf16 lo with v ≈ hi + lo (residual ~2^-16 rel)
__device__ __forceinline__ void split_bf(float v, short& hi, short& lo){
  unsigned u = __float_as_uint(v);
  float hf = __uint_as_float(u & 0xFFFF0000u);
  hi = (short)(u >> 16);
  float r = v - hf;                 // exact
  lo = (short)(__float_as_uint(r) >> 16);
}

// ---------------- dtype sniffing ----------------
__global__ void k_sniff(const void* dist, const void* adjc,
                        const void* wdc, const void* wdco,
                        int* flags, float* wd_out){
  if (blockIdx.x != 0 || threadIdx.x != 0) return;
  const unsigned* w = (const unsigned*)dist;
  int f32 = 0;
  for (int k = 0; k < 64; ++k) if ((w[k] & 0xFFFFu) >= 0x8000u){ f32 = 1; break; }
  const unsigned* bw = (const unsigned*)adjc;
  int as_int = 1;
  for (int k = 0; k < 64; ++k) if (bw[k] > 1u){ as_int = 0; break; }
  flags[0] = f32; flags[1] = as_int;
  wd_out[0] = f32 ? ((const float*)wdc)[0]  : b2f(((const bf16*)wdc)[0]);
  wd_out[1] = f32 ? ((const float*)wdco)[0] : b2f(((const bf16*)wdco)[0]);
}

// ---------------- distance transpose ----------------
template<bool F32>
__device__ __forceinline__ void dist_t_body(const void* dist, float* distT){
  int t = blockIdx.x * 256 + threadIdx.x;
  if (t >= NN * NN) return;
  int i = t / NN, j = t - i * NN;
  distT[t] = ldf<F32>(dist, (long)j * NN + i);
}
__global__ void k_dist_t(const int* flags, const void* dist, float* distT){
  if (flags[0]) dist_t_body<true>(dist, distT);
  else          dist_t_body<false>(dist, distT);
}

// ---------------- adjacency transpose + bit-pack ----------------
template<bool BINT>
__device__ __forceinline__ void adj_pack_body(const void* adj, u64* adjP){
  __shared__ unsigned char tile[64][256];
  int t = threadIdx.x;
  int i0 = blockIdx.x * 256;
  int w  = blockIdx.y;
  int b  = blockIdx.z;
  long base = (long)b * NN * NN;
#pragma unroll 4
  for (int jj = 0; jj < 64; ++jj){
    int j = w * 64 + jj;
    int i = i0 + t;
    unsigned char v = 0;
    if (j < NN && i < NN) v = ldb<BINT>(adj, base + (long)j * NN + i) ? 1 : 0;
    tile[jj][t] = v;
  }
  __syncthreads();
  int i = i0 + t;
  if (i < NN){
    u64 word = 0;
#pragma unroll
    for (int jj = 0; jj < 64; ++jj)
      word |= (u64)tile[jj][t] << jj;
    adjP[((long)b * NN + i) * NW + w] = word;
  }
}
__global__ void k_adj_pack(const int* flags, const void* adj, u64* adjP){
  if (flags[1]) adj_pack_body<true>(adj, adjP);
  else          adj_pack_body<false>(adj, adjP);
}

// ---------------- embedding + h_c + attention scalars ----------------
template<bool F32>
__device__ __forceinline__ void embed_body(
    const int* op_idx, const void* vf, const void* cs_tab, const void* tp_tab,
    const void* Wc, const void* asrc, const void* adst,
    float* x_out, float* h_out, float* ed_out, float* es_out){
  int t = threadIdx.x;
  int w = t >> 6, lane = t & 63;
  int g = blockIdx.x * 4 + w;          // b*NN + n
  int n = g % NN;
  int op = op_idx[g];
  float xv = 0.f, hacc = 0.f;
#pragma unroll
  for (int f = 0; f < 15; ++f){
    float x_f;
    if (f < 4)      x_f = ldf<F32>(cs_tab, n * 4 + f);
    else if (f < 6) x_f = ldf<F32>(tp_tab, op * 2 + (f - 4));
    else            x_f = ldf<F32>(vf, (long)g * 9 + (f - 6));
    if (lane == f) xv = x_f;
    hacc += x_f * ldf<F32>(Wc, f * COMD + lane);
  }
  if (lane < 15) x_out[g * 15 + lane] = xv;
  h_out[(long)g * COMD + lane] = hacc;
  float sd = wave_sum(hacc * ldf<F32>(adst, lane));
  float ss = wave_sum(hacc * ldf<F32>(asrc, lane));
  if (lane == 0){ ed_out[g] = sd; es_out[g] = ss; }
}
__global__ void __launch_bounds__(256) k_embed(
    const int* flags, const int* op_idx, const void* vf, const void* cs_tab,
    const void* tp_tab, const void* Wc, const void* asrc, const void* adst,
    float* x_out, float* h_out, float* ed_out, float* es_out){
  if (flags[0]) embed_body<true >(op_idx, vf, cs_tab, tp_tab, Wc, asrc, adst, x_out, h_out, ed_out, es_out);
  else          embed_body<false>(op_idx, vf, cs_tab, tp_tab, Wc, asrc, adst, x_out, h_out, ed_out, es_out);
}

// ---------------- h_co = [x, comp] @ Wco ----------------
template<bool F32>
__device__ __forceinline__ void hco_body(
    const float* x_ws, const float* comp, const void* Wco,
    const void* asrc, const void* adst,
    float* h_out, float* ed_out, float* es_out){
  int t = threadIdx.x;
  int w = t >> 6, lane = t & 63;
  int g = blockIdx.x * 4 + w;
  float xl = (lane < 15) ? x_ws[g * 15 + lane] : 0.f;
  float cv = comp[(long)g * COMD + lane];
  float hacc = 0.f;
#pragma unroll
  for (int f = 0; f < 15; ++f)
    hacc += rdlane(xl, f) * ldf<F32>(Wco, f * COMD + lane);
#pragma unroll
  for (int f = 0; f < 64; ++f)
    hacc += rdlane(cv, f) * ldf<F32>(Wco, (15 + f) * COMD + lane);
  h_out[(long)g * COMD + lane] = hacc;
  float sd = wave_sum(hacc * ldf<F32>(adst, lane));
  float ss = wave_sum(hacc * ldf<F32>(asrc, lane));
  if (lane == 0){ ed_out[g] = sd; es_out[g] = ss; }
}
__global__ void __launch_bounds__(256) k_hco(
    const int* flags, const float* x_ws, const float* comp, const void* Wco,
    const void* asrc, const void* adst,
    float* h_out, float* ed_out, float* es_out){
  if (flags[0]) hco_body<true >(x_ws, comp, Wco, asrc, adst, h_out, ed_out, es_out);
  else          hco_body<false>(x_ws, comp, Wco, asrc, adst, h_out, ed_out, es_out);
}

// ---------------- h -> bf16 hi/lo planes in MFMA B-fragment order ----------------
// hB[b][kb(32)][g(4)][ch(64)][u(8)]; element (kb,g,ch,u) = h[b][kb*32+g*8+u][ch]
// (zero-padded for j >= NN). Reads coalesced over ch; writes 16B/lane contiguous.
__global__ void __launch_bounds__(256) k_hsplit(
    const float* __restrict__ h, short* __restrict__ hB_hi, short* __restrict__ hB_lo){
  int t = threadIdx.x, kb = blockIdx.x, b = blockIdx.y;
  int g = t >> 6, lane = t & 63;
  s16x8 vhi, vlo;
#pragma unroll
  for (int u = 0; u < 8; ++u){
    int j = kb * 32 + g * 8 + u;
    float v = (j < NN) ? h[((long)b * NN + j) * COMD + lane] : 0.f;
    short hi, lo; split_bf(v, hi, lo);
    vhi[u] = hi; vlo[u] = lo;
  }
  long obase = ((((long)b * 32 + kb) * 4 + g) * 64 + lane) * 8;
  *(s16x8*)&hB_hi[obase] = vhi;
  *(s16x8*)&hB_lo[obase] = vlo;
}

// ---------------- masked-softmax GAT, MFMA phase 3 ----------------
// 16 dst rows/block, wave wv owns 16-channel tile. Scores in regs (j striped
// by wave/lane), softmax reduced via LDS, then alpha staged per-256-j chunk
// into LDS in A-fragment order; D = alpha @ h via 3x bf16-hi/lo MFMAs.
__global__ void __launch_bounds__(256) k_gat(
    const float* __restrict__ ed, const float* __restrict__ es,
    const float* __restrict__ wd_ws, int wd_idx, const u64* __restrict__ adjP,
    const float* __restrict__ distT,
    const short* __restrict__ hB_hi, const short* __restrict__ hB_lo,
    float* __restrict__ reps){
  __shared__ u64 adjW[TI][NW];
  __shared__ short pA_hi[4096] __attribute__((aligned(16)));  // 8 kb x 64 rows x 8
  __shared__ short pA_lo[4096] __attribute__((aligned(16)));
  __shared__ float redm[TI][4], redz[TI][4];
  __shared__ float m_sh[TI], z_sh[TI];
  int t = threadIdx.x;
  int wv = t >> 6, lane = t & 63;
  int b = blockIdx.y;
  int i0 = blockIdx.x * TI;
  float wd = wd_ws[wd_idx];
  const u64* adjPb = adjP + (long)b * NN * NW;

  // stage adjacency words (wave-uniform reuse -> LDS)
  {
    int ti = t >> 4, w = t & 15;
    int i = i0 + ti;
    adjW[ti][w] = (i < NN) ? adjPb[(long)i * NW + w] : 0ull;
  }
  float ed_i[TI];
#pragma unroll
  for (int ti = 0; ti < TI; ++ti)
    ed_i[ti] = (i0 + ti < NN) ? ed[b * NN + i0 + ti] : 0.f;
  __syncthreads();

  // phase 1: scores into registers (j = c*256 + wv*64 + lane)
  float p[TI][4];
  float m_l[TI];
#pragma unroll
  for (int ti = 0; ti < TI; ++ti) m_l[ti] = -INFINITY;
#pragma unroll
  for (int c = 0; c < 4; ++c){
    int j = c * 256 + wv * 64 + lane;
    float esj = (j < NN) ? es[b * NN + j] : 0.f;
    int jc = (j < NN) ? j : (NN - 1);
#pragma unroll
    for (int ti = 0; ti < TI; ++ti){
      int i = i0 + ti;
      int ic = (i < NN) ? i : (NN - 1);
      u64 word = adjW[ti][c * 4 + wv];
      bool edge = (word >> lane) & 1ull;
      float d = distT[(long)ic * NN + jc];
      float v = ed_i[ti] + esj + wd * d;
      v = fmaxf(v, 0.2f * v);                 // leaky_relu
      float e = edge ? v : -INFINITY;
      p[ti][c] = e;
      m_l[ti] = fmaxf(m_l[ti], e);
    }
  }
#pragma unroll
  for (int ti = 0; ti < TI; ++ti){
    float m = wave_max(m_l[ti]);
    if (lane == 0) redm[ti][wv] = m;
  }
  __syncthreads();
  if (t < TI) m_sh[t] = fmaxf(fmaxf(redm[t][0], redm[t][1]), fmaxf(redm[t][2], redm[t][3]));
  __syncthreads();

  // phase 2: exp + row sums
  float z_l[TI];
#pragma unroll
  for (int ti = 0; ti < TI; ++ti){
    float m = m_sh[ti];
    float zs = 0.f;
#pragma unroll
    for (int c = 0; c < 4; ++c){
      float e = p[ti][c];
      float pp = (e > -INFINITY) ? __expf(e - m) : 0.f;
      p[ti][c] = pp;
      zs += pp;
    }
    z_l[ti] = zs;
  }
#pragma unroll
  for (int ti = 0; ti < TI; ++ti){
    float s = wave_sum(z_l[ti]);
    if (lane == 0) redz[ti][wv] = s;
  }
  __syncthreads();
  if (t < TI){
    float z = redz[t][0] + redz[t][1] + redz[t][2] + redz[t][3];
    z_sh[t] = (z > 0.f) ? 1.f / z : 0.f;
  }

  // phase 3: D = alpha @ h via MFMA (bf16 hi/lo split, fp32 accumulate)
  f32x4 acc = {0.f, 0.f, 0.f, 0.f};
  int wg = (lane >> 3) & 3, wu = lane & 7;       // write-side coords
  int kbW = wv * 2 + (lane >> 5);
  int Ag = lane >> 4, Am = lane & 15;            // read-side A coords
  long hBbase = (long)b * 65536;                 // 32kb*4g*64ch*8u
#pragma unroll
  for (int c = 0; c < 4; ++c){
    __syncthreads();   // prior-iteration frag reads done
    int widx = (kbW * 64 + wg * 16) * 8 + wu;
#pragma unroll
    for (int ti = 0; ti < TI; ++ti){
      short hi, lo; split_bf(p[ti][c], hi, lo);
      pA_hi[widx + ti * 8] = hi;
      pA_lo[widx + ti * 8] = lo;
    }
    __syncthreads();
#pragma unroll
    for (int kbL = 0; kbL < 8; ++kbL){
      int kb = c * 8 + kbL;
      int aidx = (kbL * 64 + Ag * 16 + Am) * 8;
      s16x8 a_hi = *(const s16x8*)&pA_hi[aidx];
      s16x8 a_lo = *(const s16x8*)&pA_lo[aidx];
      long bidx = hBbase + (((long)kb * 4 + Ag) * 64 + wv * 16 + Am) * 8;
      s16x8 b_hi = *(const s16x8*)&hB_hi[bidx];
      s16x8 b_lo = *(const s16x8*)&hB_lo[bidx];
      acc = __builtin_amdgcn_mfma_f32_16x16x32_bf16(a_hi, b_hi, acc, 0, 0, 0);
      acc = __builtin_amdgcn_mfma_f32_16x16x32_bf16(a_hi, b_lo, acc, 0, 0, 0);
      acc = __builtin_amdgcn_mfma_f32_16x16x32_bf16(a_lo, b_hi, acc, 0, 0, 0);
    }
  }
  // epilogue: D row = (lane>>4)*4+reg (dst ti), col = lane&15 (channel in tile)
#pragma unroll
  for (int reg = 0; reg < 4; ++reg){
    int ti = (lane >> 4) * 4 + reg;
    int ch = wv * 16 + (lane & 15);
    float v = acc[reg] * z_sh[ti];
    v = (v > 0.f) ? v : expm1f(v);
    if (i0 + ti < NN)
      reps[((long)b * NN + i0 + ti) * COMD + ch] = v;
  }
}

// ---------------- x_p = sag@Wp + bp, fused score dots ----------------
// LDS float4 broadcast reads (no readlane hazards, no per-lane addresses)
template<bool F32>
__device__ __forceinline__ void xp_body(
    const int* time_idx, const int* op_idx, const void* vf, const void* time_tab,
    const void* cs_tab, const void* tp_tab, const float* comp, const float* coop,
    const void* Wp, const void* bp, const void* vpd, const void* vpf,
    float* x_p, float* scf, float* scd){
  __shared__ float sag[8][148] __attribute__((aligned(16)));
  __shared__ float sred[8][2][4];
  int t = threadIdx.x;
  int wv = t >> 6, lane = t & 63;
  int base = blockIdx.x * 8;
  for (int idx = t; idx < 8 * 147; idx += 256){
    int nl = idx / 147, f = idx - nl * 147;
    int g = base + nl;
    int n = g % NN;
    float v;
    if (f < 4)       v = ldf<F32>(time_tab, time_idx[g] * 4 + f);
    else if (f < 8)  v = ldf<F32>(cs_tab, n * 4 + (f - 4));
    else if (f < 10) v = ldf<F32>(tp_tab, op_idx[g] * 2 + (f - 8));
    else if (f < 19) v = ldf<F32>(vf, (long)g * 9 + (f - 10));
    else if (f < 83) v = comp[(long)g * COMD + (f - 19)];
    else             v = coop[(long)g * COMD + (f - 83)];
    sag[nl][f] = v;
  }
  __syncthreads();
  int hh = t;
  float a[8];
#pragma unroll
  for (int nl = 0; nl < 8; ++nl) a[nl] = 0.f;
  for (int f4 = 0; f4 < 144; f4 += 4){
    float w0 = ldf<F32>(Wp, (f4 + 0) * HIDD + hh);
    float w1 = ldf<F32>(Wp, (f4 + 1) * HIDD + hh);
    float w2 = ldf<F32>(Wp, (f4 + 2) * HIDD + hh);
    float w3 = ldf<F32>(Wp, (f4 + 3) * HIDD + hh);
#pragma unroll
    for (int nl = 0; nl < 8; ++nl){
      float4 sv = *(const float4*)&sag[nl][f4];
      a[nl] += sv.x * w0 + sv.y * w1 + sv.z * w2 + sv.w * w3;
    }
  }
#pragma unroll
  for (int f = 144; f < 147; ++f){
    float wf = ldf<F32>(Wp, f * HIDD + hh);
#pragma unroll
    for (int nl = 0; nl < 8; ++nl)
      a[nl] += sag[nl][f] * wf;
  }
  float bb = ldf<F32>(bp, hh);
#pragma unroll
  for (int nl = 0; nl < 8; ++nl){
    a[nl] += bb;
    x_p[(long)(base + nl) * HIDD + hh] = a[nl];
  }
  float vd = ldf<F32>(vpd, hh), vfl = ldf<F32>(vpf, hh);
#pragma unroll
  for (int nl = 0; nl < 8; ++nl){
    float sD = wave_sum(a[nl] * vd);
    float sF = wave_sum(a[nl] * vfl);
    if (lane == 0){ sred[nl][0][wv] = sF; sred[nl][1][wv] = sD; }
  }
  __syncthreads();
  if (t < 16){
    int nl = t >> 1, st = t & 1;
    float s = sred[nl][st][0] + sred[nl][st][1] + sred[nl][st][2] + sred[nl][st][3];
    if (st == 0) scf[base + nl] = s; else scd[base + nl] = s;
  }
}
__global__ void __launch_bounds__(256) k_xp(
    const int* flags, const int* time_idx, const int* op_idx, const void* vf,
    const void* time_tab, const void* cs_tab, const void* tp_tab,
    const float* comp, const float* coop, const void* Wp, const void* bp,
    const void* vpd, const void* vpf, float* x_p, float* scf, float* scd){
  if (flags[0]) xp_body<true >(time_idx, op_idx, vf, time_tab, cs_tab, tp_tab, comp, coop, Wp, bp, vpd, vpf, x_p, scf, scd);
  else          xp_body<false>(time_idx, op_idx, vf, time_tab, cs_tab, tp_tab, comp, coop, Wp, bp, vpd, vpf, x_p, scf, scd);
}

// ---------------- top-k gated pool ----------------
template<bool F32, bool BINT>
__device__ __forceinline__ void pool_body(
    const float* scf, const float* scd, const void* mark,
    const float* x_p, void* out){
  __shared__ float s1[NN];
  __shared__ unsigned keys[NN];
  __shared__ float wls[NN];
  __shared__ float red[4];
  __shared__ int cnt;
  __shared__ float bc[2];
  __shared__ float part_s[4][64], part_m[4][64];
  int t = threadIdx.x;
  int wv = t >> 6, lane = t & 63;
  int b = blockIdx.x, pool = blockIdx.y;
  int c0 = blockIdx.z * 64;
  const float* sc = (pool == 0) ? scf : scd;

  float lm = -INFINITY;
  for (int n = t; n < NN; n += 256){
    float r = sc[b * NN + n];
    s1[n] = r;
    lm = fmaxf(lm, r);
  }
  lm = wave_max(lm);
  if (lane == 0) red[wv] = lm;
  __syncthreads();
  if (t == 0) bc[0] = fmaxf(fmaxf(red[0], red[1]), fmaxf(red[2], red[3]));
  __syncthreads();
  float m0 = bc[0];

  lm = -INFINITY;
  for (int n = t; n < NN; n += 256){
    bool mk = ldb<BINT>(mark, b * NN + n);
    bool valid = (pool == 0) ? !mk : mk;
    float v = valid ? (s1[n] - m0) : -1e8f;
    s1[n] = v;
    keys[n] = fkey(v);
    lm = fmaxf(lm, v);
  }
  lm = wave_max(lm);
  if (lane == 0) red[wv] = lm;
  __syncthreads();
  if (t == 0) bc[1] = fmaxf(fmaxf(red[0], red[1]), fmaxf(red[2], red[3]));
  __syncthreads();
  float m1 = bc[1];

  unsigned lo = 0u, hi = 0xFFFFFFFFu;
  for (int it = 0; it < 32; ++it){
    if (lo >= hi) break;
    unsigned mid = lo + (unsigned)((((unsigned long long)(hi - lo)) + 1ull) >> 1);
    if (t == 0) cnt = 0;
    __syncthreads();
    int c = 0;
    for (int n = t; n < NN; n += 256) c += (keys[n] >= mid) ? 1 : 0;
    atomicAdd(&cnt, c);
    __syncthreads();
    int total = cnt;
    __syncthreads();
    if (total >= KSEL) lo = mid; else hi = mid - 1;
  }

  float ls = 0.f;
  for (int n = t; n < NN; n += 256){
    float p = (keys[n] >= lo) ? __expf(s1[n] - m1) : 0.f;
    wls[n] = p;
    ls += p;
  }
  ls = wave_sum(ls);
  if (lane == 0) red[wv] = ls;
  __syncthreads();
  if (t == 0){
    float z = red[0] + red[1] + red[2] + red[3];
    bc[0] = (z > 0.f) ? 1.f / z : 0.f;
  }
  __syncthreads();
  float zinv = bc[0];
  for (int n = t; n < NN; n += 256) wls[n] *= zinv;
  __syncthreads();

  int c = c0 + lane;
  float ssum = 0.f, smax = -INFINITY;
  for (int n = wv; n < NN; n += 4){
    float xv = x_p[((long)b * NN + n) * HIDD + c];
    float g = wls[n] * xv;
    ssum += g;
    smax = fmaxf(smax, g);
  }
  part_s[wv][lane] = ssum;
  part_m[wv][lane] = smax;
  __syncthreads();
  if (wv == 0){
    float s = part_s[0][lane] + part_s[1][lane] + part_s[2][lane] + part_s[3][lane];
    float m = fmaxf(fmaxf(part_m[0][lane], part_m[1][lane]),
                    fmaxf(part_m[2][lane], part_m[3][lane]));
    long ob = (long)b * 1024 + (long)pool * 512;
    if (F32){
      ((float*)out)[ob + c] = s;
      ((float*)out)[ob + 256 + c] = m;
    } else {
      ((bf16*)out)[ob + c] = __float2bfloat16(s);
      ((bf16*)out)[ob + 256 + c] = __float2bfloat16(m);
    }
  }
}
__global__ void __launch_bounds__(256) k_pool(
    const int* flags, const float* scf, const float* scd, const void* mark,
    const float* x_p, void* out){
  if (flags[0]){
    if (flags[1]) pool_body<true , true >(scf, scd, mark, x_p, out);
    else          pool_body<true , false>(scf, scd, mark, x_p, out);
  } else {
    if (flags[1]) pool_body<false, true >(scf, scd, mark, x_p, out);
    else          pool_body<false, false>(scf, scd, mark, x_p, out);
  }
}

extern "C" void kernel_launch(void* const* d_in, const int* in_sizes, int n_in,
                              void* d_out, int out_size, void* d_ws, size_t ws_size,
                              hipStream_t stream){
  const int*  time_idx = (const int*)d_in[0];
  const int*  op_idx   = (const int*)d_in[1];
  const void* vfeat    = d_in[2];
  const void* dpcs     = d_in[3];
  const void* adj_comp = d_in[4];
  const void* adj_coop = d_in[5];
  const void* dist     = d_in[6];
  const void* time_tab = d_in[7];
  const void* tp_tab   = d_in[8];
  const void* cs_tab   = d_in[9];
  const void* Wc       = d_in[10];
  const void* asrc_c   = d_in[11];
  const void* adst_c   = d_in[12];
  const void* wd_c     = d_in[13];
  const void* Wco      = d_in[14];
  const void* asrc_co  = d_in[15];
  const void* adst_co  = d_in[16];
  const void* wd_co    = d_in[17];
  const void* Wp       = d_in[18];
  const void* bp       = d_in[19];
  const void* vpd      = d_in[20];
  const void* vpf      = d_in[21];

  char* ws = (char*)d_ws;
  size_t o = 0;
  auto alloc = [&](size_t bytes)->char*{
    char* p = ws + o; o = (o + bytes + 255) & ~(size_t)255; return p;
  };
  int*   flags = (int*)alloc(16);
  float* wd_ws = (float*)alloc(8);
  float* distT = (float*)alloc((size_t)NN * NN * 4);
  u64*   adjPc = (u64*)alloc((size_t)NB * NN * NW * 8);
  u64*   adjPo = (u64*)alloc((size_t)NB * NN * NW * 8);
  float* x_ws  = (float*)alloc((size_t)NB * NN * 15 * 4);
  float* h_c   = (float*)alloc((size_t)NB * NN * COMD * 4);
  float* h_o   = (float*)alloc((size_t)NB * NN * COMD * 4);
  float* comp  = (float*)alloc((size_t)NB * NN * COMD * 4);
  float* coop  = (float*)alloc((size_t)NB * NN * COMD * 4);
  short* hB_hi = (short*)alloc((size_t)NB * 65536 * 2);
  short* hB_lo = (short*)alloc((size_t)NB * 65536 * 2);
  float* ed_c  = (float*)alloc((size_t)NB * NN * 4);
  float* es_c  = (float*)alloc((size_t)NB * NN * 4);
  float* ed_o  = (float*)alloc((size_t)NB * NN * 4);
  float* es_o  = (float*)alloc((size_t)NB * NN * 4);
  float* scf   = (float*)alloc((size_t)NB * NN * 4);
  float* scd   = (float*)alloc((size_t)NB * NN * 4);
  float* x_p   = (float*)alloc((size_t)NB * NN * HIDD * 4);

  k_sniff<<<1, 64, 0, stream>>>(dist, adj_comp, wd_c, wd_co, flags, wd_ws);
  k_dist_t<<<dim3((NN * NN + 255) / 256), dim3(256), 0, stream>>>(flags, dist, distT);
  dim3 pg(4, NW, NB);
  k_adj_pack<<<pg, dim3(256), 0, stream>>>(flags, adj_comp, adjPc);
  k_adj_pack<<<pg, dim3(256), 0, stream>>>(flags, adj_coop, adjPo);
  k_embed<<<dim3(NB * NN / 4), dim3(256), 0, stream>>>(
      flags, op_idx, vfeat, cs_tab, tp_tab, Wc, asrc_c, adst_c, x_ws, h_c, ed_c, es_c);
  k_hsplit<<<dim3(32, NB), dim3(256), 0, stream>>>(h_c, hB_hi, hB_lo);
  k_gat<<<dim3((NN + TI - 1) / TI, NB), dim3(256), 0, stream>>>(
      ed_c, es_c, wd_ws, 0, adjPc, distT, hB_hi, hB_lo, comp);
  k_hco<<<dim3(NB * NN / 4), dim3(256), 0, stream>>>(
      flags, x_ws, comp, Wco, asrc_co, adst_co, h_o, ed_o, es_o);
  k_hsplit<<<dim3(32, NB), dim3(256), 0, stream>>>(h_o, hB_hi, hB_lo);
  k_gat<<<dim3((NN + TI - 1) / TI, NB), dim3(256), 0, stream>>>(
      ed_o, es_o, wd_ws, 1, adjPo, distT, hB_hi, hB_lo, coop);
  k_xp<<<dim3(NB * NN / 8), dim3(256), 0, stream>>>(
      flags, time_idx, op_idx, vfeat, time_tab, cs_tab, tp_tab, comp, coop,
      Wp, bp, vpd, vpf, x_p, scf, scd);
  k_pool<<<dim3(NB, 2, 4), dim3(256), 0, stream>>>(flags, scf, scd, dpcs, x_p, d_out);
}

// Round 5
// 790.914 us; speedup vs baseline: 1.7744x; 1.1277x over previous
//
#include <hip/hip_runtime.h>
#include <hip/hip_bf16.h>

#define NB 32
#define NN 1000
#define NW 16        // 64-bit words per packed adjacency row (16*64 = 1024 >= NN)
#define COMD 64
#define HIDD 256
#define KSEL 500
#define TI 16        // dst rows per k_gat block
#define NSPL 16      // n-splits for k_psum
#define ROWS 63      // ceil(NN/NSPL)

typedef __hip_bfloat16 bf16;
typedef unsigned long long u64;
typedef __attribute__((ext_vector_type(4))) float f32x4;
typedef __attribute__((ext_vector_type(8))) short s16x8;

__device__ __forceinline__ float b2f(bf16 x){ return __bfloat162float(x); }

template<bool F32>
__device__ __forceinline__ float ldf(const void* p, long i){
  return F32 ? ((const float*)p)[i] : b2f(((const bf16*)p)[i]);
}
template<bool BINT>
__device__ __forceinline__ bool ldb(const void* p, long i){
  return BINT ? (((const int*)p)[i] != 0) : (((const unsigned char*)p)[i] != 0);
}

__device__ __forceinline__ float wave_sum(float v){
#pragma unroll
  for (int o = 32; o > 0; o >>= 1) v += __shfl_down(v, o, 64);
  return v;
}
__device__ __forceinline__ float wave_max(float v){
#pragma unroll
  for (int o = 32; o > 0; o >>= 1) v = fmaxf(v, __shfl_down(v, o, 64));
  return v;
}
// butterfly variants: ALL lanes end with the result (no broadcast needed)
__device__ __forceinline__ float wave_bsum(float v){
#pragma unroll
  for (int o = 32; o > 0; o >>= 1) v += __shfl_xor(v, o, 64);
  return v;
}
__device__ __forceinline__ float wave_bmax(float v){
#pragma unroll
  for (int o = 32; o > 0; o >>= 1) v = fmaxf(v, __shfl_xor(v, o, 64));
  return v;
}
__device__ __forceinline__ int wave_bsum_i(int v){
#pragma unroll
  for (int o = 32; o > 0; o >>= 1) v += __shfl_xor(v, o, 64);
  return v;
}
__device__ __forceinline__ float rdlane(float v, int l){
  return __uint_as_float((unsigned)__builtin_amdgcn_readlane((int)__float_as_uint(v), l));
}
__device__ __forceinline__ unsigned fkey(float f){
  unsigned u = __float_as_uint(f);
  return (u & 0x80000000u) ? ~u : (u | 0x80000000u);
}
// split fp32 into bf16 hi + bf16 lo with v ≈ hi + lo (residual ~2^-16 rel)
__device__ __forceinline__ void split_bf(float v, short& hi, short& lo){
  unsigned u = __float_as_uint(v);
  float hf = __uint_as_float(u & 0xFFFF0000u);
  hi = (short)(u >> 16);
  float r = v - hf;                 // exact
  lo = (short)(__float_as_uint(r) >> 16);
}

// ---------------- dtype sniffing ----------------
__global__ void k_sniff(const void* dist, const void* adjc,
                        const void* wdc, const void* wdco,
                        int* flags, float* wd_out){
  if (blockIdx.x != 0 || threadIdx.x != 0) return;
  const unsigned* w = (const unsigned*)dist;
  int f32 = 0;
  for (int k = 0; k < 64; ++k) if ((w[k] & 0xFFFFu) >= 0x8000u){ f32 = 1; break; }
  const unsigned* bw = (const unsigned*)adjc;
  int as_int = 1;
  for (int k = 0; k < 64; ++k) if (bw[k] > 1u){ as_int = 0; break; }
  flags[0] = f32; flags[1] = as_int;
  wd_out[0] = f32 ? ((const float*)wdc)[0]  : b2f(((const bf16*)wdc)[0]);
  wd_out[1] = f32 ? ((const float*)wdco)[0] : b2f(((const bf16*)wdco)[0]);
}

// ---------------- distance transpose ----------------
template<bool F32>
__device__ __forceinline__ void dist_t_body(const void* dist, float* distT){
  int t = blockIdx.x * 256 + threadIdx.x;
  if (t >= NN * NN) return;
  int i = t / NN, j = t - i * NN;
  distT[t] = ldf<F32>(dist, (long)j * NN + i);
}
__global__ void k_dist_t(const int* flags, const void* dist, float* distT){
  if (flags[0]) dist_t_body<true>(dist, distT);
  else          dist_t_body<false>(dist, distT);
}

// ---------------- adjacency transpose + bit-pack ----------------
template<bool BINT>
__device__ __forceinline__ void adj_pack_body(const void* adj, u64* adjP){
  __shared__ unsigned char tile[64][256];
  int t = threadIdx.x;
  int i0 = blockIdx.x * 256;
  int w  = blockIdx.y;
  int b  = blockIdx.z;
  long base = (long)b * NN * NN;
#pragma unroll 4
  for (int jj = 0; jj < 64; ++jj){
    int j = w * 64 + jj;
    int i = i0 + t;
    unsigned char v = 0;
    if (j < NN && i < NN) v = ldb<BINT>(adj, base + (long)j * NN + i) ? 1 : 0;
    tile[jj][t] = v;
  }
  __syncthreads();
  int i = i0 + t;
  if (i < NN){
    u64 word = 0;
#pragma unroll
    for (int jj = 0; jj < 64; ++jj)
      word |= (u64)tile[jj][t] << jj;
    adjP[((long)b * NN + i) * NW + w] = word;
  }
}
__global__ void k_adj_pack(const int* flags, const void* adj, u64* adjP){
  if (flags[1]) adj_pack_body<true>(adj, adjP);
  else          adj_pack_body<false>(adj, adjP);
}

// ---------------- embedding + h_c + attention scalars ----------------
template<bool F32>
__device__ __forceinline__ void embed_body(
    const int* op_idx, const void* vf, const void* cs_tab, const void* tp_tab,
    const void* Wc, const void* asrc, const void* adst,
    float* x_out, float* h_out, float* ed_out, float* es_out){
  int t = threadIdx.x;
  int w = t >> 6, lane = t & 63;
  int g = blockIdx.x * 4 + w;          // b*NN + n
  int n = g % NN;
  int op = op_idx[g];
  float xv = 0.f, hacc = 0.f;
#pragma unroll
  for (int f = 0; f < 15; ++f){
    float x_f;
    if (f < 4)      x_f = ldf<F32>(cs_tab, n * 4 + f);
    else if (f < 6) x_f = ldf<F32>(tp_tab, op * 2 + (f - 4));
    else            x_f = ldf<F32>(vf, (long)g * 9 + (f - 6));
    if (lane == f) xv = x_f;
    hacc += x_f * ldf<F32>(Wc, f * COMD + lane);
  }
  if (lane < 15) x_out[g * 15 + lane] = xv;
  h_out[(long)g * COMD + lane] = hacc;
  float sd = wave_sum(hacc * ldf<F32>(adst, lane));
  float ss = wave_sum(hacc * ldf<F32>(asrc, lane));
  if (lane == 0){ ed_out[g] = sd; es_out[g] = ss; }
}
__global__ void __launch_bounds__(256) k_embed(
    const int* flags, const int* op_idx, const void* vf, const void* cs_tab,
    const void* tp_tab, const void* Wc, const void* asrc, const void* adst,
    float* x_out, float* h_out, float* ed_out, float* es_out){
  if (flags[0]) embed_body<true >(op_idx, vf, cs_tab, tp_tab, Wc, asrc, adst, x_out, h_out, ed_out, es_out);
  else          embed_body<false>(op_idx, vf, cs_tab, tp_tab, Wc, asrc, adst, x_out, h_out, ed_out, es_out);
}

// ---------------- h_co = [x, comp] @ Wco ----------------
// LDS float4-broadcast reads for the activation (no readlane->fma hazards)
template<bool F32>
__device__ __forceinline__ void hco_body(
    const float* x_ws, const float* comp, const void* Wco,
    const void* asrc, const void* adst,
    float* h_out, float* ed_out, float* es_out){
  __shared__ float cx[4][80] __attribute__((aligned(16)));
  int t = threadIdx.x;
  int w = t >> 6, lane = t & 63;
  int base = blockIdx.x * 4;
  for (int idx = t; idx < 4 * 79; idx += 256){
    int nl = idx / 79, f = idx - nl * 79;
    int g = base + nl;
    cx[nl][f] = (f < 15) ? x_ws[g * 15 + f] : comp[(long)g * COMD + (f - 15)];
  }
  __syncthreads();
  int g = base + w;
  float hacc = 0.f;
#pragma unroll
  for (int f4 = 0; f4 < 76; f4 += 4){
    float4 sv = *(const float4*)&cx[w][f4];
    float w0 = ldf<F32>(Wco, (f4 + 0) * COMD + lane);
    float w1 = ldf<F32>(Wco, (f4 + 1) * COMD + lane);
    float w2 = ldf<F32>(Wco, (f4 + 2) * COMD + lane);
    float w3 = ldf<F32>(Wco, (f4 + 3) * COMD + lane);
    hacc += sv.x * w0 + sv.y * w1 + sv.z * w2 + sv.w * w3;
  }
#pragma unroll
  for (int f = 76; f < 79; ++f)
    hacc += cx[w][f] * ldf<F32>(Wco, f * COMD + lane);
  h_out[(long)g * COMD + lane] = hacc;
  float sd = wave_sum(hacc * ldf<F32>(adst, lane));
  float ss = wave_sum(hacc * ldf<F32>(asrc, lane));
  if (lane == 0){ ed_out[g] = sd; es_out[g] = ss; }
}
__global__ void __launch_bounds__(256) k_hco(
    const int* flags, const float* x_ws, const float* comp, const void* Wco,
    const void* asrc, const void* adst,
    float* h_out, float* ed_out, float* es_out){
  if (flags[0]) hco_body<true >(x_ws, comp, Wco, asrc, adst, h_out, ed_out, es_out);
  else          hco_body<false>(x_ws, comp, Wco, asrc, adst, h_out, ed_out, es_out);
}

// ---------------- h -> bf16 hi/lo planes in MFMA B-fragment order ----------------
__global__ void __launch_bounds__(256) k_hsplit(
    const float* __restrict__ h, short* __restrict__ hB_hi, short* __restrict__ hB_lo){
  int t = threadIdx.x, kb = blockIdx.x, b = blockIdx.y;
  int g = t >> 6, lane = t & 63;
  s16x8 vhi, vlo;
#pragma unroll
  for (int u = 0; u < 8; ++u){
    int j = kb * 32 + g * 8 + u;
    float v = (j < NN) ? h[((long)b * NN + j) * COMD + lane] : 0.f;
    short hi, lo; split_bf(v, hi, lo);
    vhi[u] = hi; vlo[u] = lo;
  }
  long obase = ((((long)b * 32 + kb) * 4 + g) * 64 + lane) * 8;
  *(s16x8*)&hB_hi[obase] = vhi;
  *(s16x8*)&hB_lo[obase] = vlo;
}

// ---------------- masked-softmax GAT, MFMA phase 3 ----------------
__global__ void __launch_bounds__(256) k_gat(
    const float* __restrict__ ed, const float* __restrict__ es,
    const float* __restrict__ wd_ws, int wd_idx, const u64* __restrict__ adjP,
    const float* __restrict__ distT,
    const short* __restrict__ hB_hi, const short* __restrict__ hB_lo,
    float* __restrict__ reps){
  __shared__ u64 adjW[TI][NW];
  __shared__ short pA_hi[4096] __attribute__((aligned(16)));  // 8 kb x 64 rows x 8
  __shared__ short pA_lo[4096] __attribute__((aligned(16)));
  __shared__ float redm[TI][4], redz[TI][4];
  __shared__ float m_sh[TI], z_sh[TI];
  int t = threadIdx.x;
  int wv = t >> 6, lane = t & 63;
  int b = blockIdx.y;
  int i0 = blockIdx.x * TI;
  float wd = wd_ws[wd_idx];
  const u64* adjPb = adjP + (long)b * NN * NW;

  {
    int ti = t >> 4, w = t & 15;
    int i = i0 + ti;
    adjW[ti][w] = (i < NN) ? adjPb[(long)i * NW + w] : 0ull;
  }
  float ed_i[TI];
#pragma unroll
  for (int ti = 0; ti < TI; ++ti)
    ed_i[ti] = (i0 + ti < NN) ? ed[b * NN + i0 + ti] : 0.f;
  __syncthreads();

  // phase 1: scores into registers (j = c*256 + wv*64 + lane)
  float p[TI][4];
  float m_l[TI];
#pragma unroll
  for (int ti = 0; ti < TI; ++ti) m_l[ti] = -INFINITY;
#pragma unroll
  for (int c = 0; c < 4; ++c){
    int j = c * 256 + wv * 64 + lane;
    float esj = (j < NN) ? es[b * NN + j] : 0.f;
    int jc = (j < NN) ? j : (NN - 1);
#pragma unroll
    for (int ti = 0; ti < TI; ++ti){
      int i = i0 + ti;
      int ic = (i < NN) ? i : (NN - 1);
      u64 word = adjW[ti][c * 4 + wv];
      bool edge = (word >> lane) & 1ull;
      float d = distT[(long)ic * NN + jc];
      float v = ed_i[ti] + esj + wd * d;
      v = fmaxf(v, 0.2f * v);                 // leaky_relu
      float e = edge ? v : -INFINITY;
      p[ti][c] = e;
      m_l[ti] = fmaxf(m_l[ti], e);
    }
  }
#pragma unroll
  for (int ti = 0; ti < TI; ++ti){
    float m = wave_max(m_l[ti]);
    if (lane == 0) redm[ti][wv] = m;
  }
  __syncthreads();
  if (t < TI) m_sh[t] = fmaxf(fmaxf(redm[t][0], redm[t][1]), fmaxf(redm[t][2], redm[t][3]));
  __syncthreads();

  // phase 2: exp + row sums
  float z_l[TI];
#pragma unroll
  for (int ti = 0; ti < TI; ++ti){
    float m = m_sh[ti];
    float zs = 0.f;
#pragma unroll
    for (int c = 0; c < 4; ++c){
      float e = p[ti][c];
      float pp = (e > -INFINITY) ? __expf(e - m) : 0.f;
      p[ti][c] = pp;
      zs += pp;
    }
    z_l[ti] = zs;
  }
#pragma unroll
  for (int ti = 0; ti < TI; ++ti){
    float s = wave_sum(z_l[ti]);
    if (lane == 0) redz[ti][wv] = s;
  }
  __syncthreads();
  if (t < TI){
    float z = redz[t][0] + redz[t][1] + redz[t][2] + redz[t][3];
    z_sh[t] = (z > 0.f) ? 1.f / z : 0.f;
  }

  // phase 3: D = alpha @ h via MFMA (bf16 hi/lo split, fp32 accumulate)
  f32x4 acc = {0.f, 0.f, 0.f, 0.f};
  int wg = (lane >> 3) & 3, wu = lane & 7;
  int kbW = wv * 2 + (lane >> 5);
  int Ag = lane >> 4, Am = lane & 15;
  long hBbase = (long)b * 65536;
#pragma unroll
  for (int c = 0; c < 4; ++c){
    __syncthreads();
    int widx = (kbW * 64 + wg * 16) * 8 + wu;
#pragma unroll
    for (int ti = 0; ti < TI; ++ti){
      short hi, lo; split_bf(p[ti][c], hi, lo);
      pA_hi[widx + ti * 8] = hi;
      pA_lo[widx + ti * 8] = lo;
    }
    __syncthreads();
#pragma unroll
    for (int kbL = 0; kbL < 8; ++kbL){
      int kb = c * 8 + kbL;
      int aidx = (kbL * 64 + Ag * 16 + Am) * 8;
      s16x8 a_hi = *(const s16x8*)&pA_hi[aidx];
      s16x8 a_lo = *(const s16x8*)&pA_lo[aidx];
      long bidx = hBbase + (((long)kb * 4 + Ag) * 64 + wv * 16 + Am) * 8;
      s16x8 b_hi = *(const s16x8*)&hB_hi[bidx];
      s16x8 b_lo = *(const s16x8*)&hB_lo[bidx];
      acc = __builtin_amdgcn_mfma_f32_16x16x32_bf16(a_hi, b_hi, acc, 0, 0, 0);
      acc = __builtin_amdgcn_mfma_f32_16x16x32_bf16(a_hi, b_lo, acc, 0, 0, 0);
      acc = __builtin_amdgcn_mfma_f32_16x16x32_bf16(a_lo, b_hi, acc, 0, 0, 0);
    }
  }
#pragma unroll
  for (int reg = 0; reg < 4; ++reg){
    int ti = (lane >> 4) * 4 + reg;
    int ch = wv * 16 + (lane & 15);
    float v = acc[reg] * z_sh[ti];
    v = (v > 0.f) ? v : expm1f(v);
    if (i0 + ti < NN)
      reps[((long)b * NN + i0 + ti) * COMD + ch] = v;
  }
}

// ---------------- x_p = sag@Wp + bp, fused score dots ----------------
template<bool F32>
__device__ __forceinline__ void xp_body(
    const int* time_idx, const int* op_idx, const void* vf, const void* time_tab,
    const void* cs_tab, const void* tp_tab, const float* comp, const float* coop,
    const void* Wp, const void* bp, const void* vpd, const void* vpf,
    float* x_p, float* scf, float* scd){
  __shared__ float sag[8][148] __attribute__((aligned(16)));
  __shared__ float sred[8][2][4];
  int t = threadIdx.x;
  int wv = t >> 6, lane = t & 63;
  int base = blockIdx.x * 8;
  for (int idx = t; idx < 8 * 147; idx += 256){
    int nl = idx / 147, f = idx - nl * 147;
    int g = base + nl;
    int n = g % NN;
    float v;
    if (f < 4)       v = ldf<F32>(time_tab, time_idx[g] * 4 + f);
    else if (f < 8)  v = ldf<F32>(cs_tab, n * 4 + (f - 4));
    else if (f < 10) v = ldf<F32>(tp_tab, op_idx[g] * 2 + (f - 8));
    else if (f < 19) v = ldf<F32>(vf, (long)g * 9 + (f - 10));
    else if (f < 83) v = comp[(long)g * COMD + (f - 19)];
    else             v = coop[(long)g * COMD + (f - 83)];
    sag[nl][f] = v;
  }
  __syncthreads();
  int hh = t;
  float a[8];
#pragma unroll
  for (int nl = 0; nl < 8; ++nl) a[nl] = 0.f;
  for (int f4 = 0; f4 < 144; f4 += 4){
    float w0 = ldf<F32>(Wp, (f4 + 0) * HIDD + hh);
    float w1 = ldf<F32>(Wp, (f4 + 1) * HIDD + hh);
    float w2 = ldf<F32>(Wp, (f4 + 2) * HIDD + hh);
    float w3 = ldf<F32>(Wp, (f4 + 3) * HIDD + hh);
#pragma unroll
    for (int nl = 0; nl < 8; ++nl){
      float4 sv = *(const float4*)&sag[nl][f4];
      a[nl] += sv.x * w0 + sv.y * w1 + sv.z * w2 + sv.w * w3;
    }
  }
#pragma unroll
  for (int f = 144; f < 147; ++f){
    float wf = ldf<F32>(Wp, f * HIDD + hh);
#pragma unroll
    for (int nl = 0; nl < 8; ++nl)
      a[nl] += sag[nl][f] * wf;
  }
  float bb = ldf<F32>(bp, hh);
#pragma unroll
  for (int nl = 0; nl < 8; ++nl){
    a[nl] += bb;
    x_p[(long)(base + nl) * HIDD + hh] = a[nl];
  }
  float vd = ldf<F32>(vpd, hh), vfl = ldf<F32>(vpf, hh);
#pragma unroll
  for (int nl = 0; nl < 8; ++nl){
    float sD = wave_sum(a[nl] * vd);
    float sF = wave_sum(a[nl] * vfl);
    if (lane == 0){ sred[nl][0][wv] = sF; sred[nl][1][wv] = sD; }
  }
  __syncthreads();
  if (t < 16){
    int nl = t >> 1, st = t & 1;
    float s = sred[nl][st][0] + sred[nl][st][1] + sred[nl][st][2] + sred[nl][st][3];
    if (st == 0) scf[base + nl] = s; else scd[base + nl] = s;
  }
}
__global__ void __launch_bounds__(256) k_xp(
    const int* flags, const int* time_idx, const int* op_idx, const void* vf,
    const void* time_tab, const void* cs_tab, const void* tp_tab,
    const float* comp, const float* coop, const void* Wp, const void* bp,
    const void* vpd, const void* vpf, float* x_p, float* scf, float* scd){
  if (flags[0]) xp_body<true >(time_idx, op_idx, vf, time_tab, cs_tab, tp_tab, comp, coop, Wp, bp, vpd, vpf, x_p, scf, scd);
  else          xp_body<false>(time_idx, op_idx, vf, time_tab, cs_tab, tp_tab, comp, coop, Wp, bp, vpd, vpf, x_p, scf, scd);
}

// ---------------- top-k weights: one wave per (b,pool), zero barriers ----------------
// 16 scores/lane in registers; counts via shfl_xor butterflies (all lanes uniform).
template<bool BINT>
__device__ __forceinline__ void topk_body(
    const float* scf, const float* scd, const void* mark, float* wls){
  int lane = threadIdx.x;           // 64 threads
  int b = blockIdx.x, pool = blockIdx.y;
  const float* sc = (pool == 0) ? scf : scd;
  float v[16]; unsigned key[16];
  float m0 = -INFINITY;
#pragma unroll
  for (int r = 0; r < 16; ++r){
    int n = r * 64 + lane;
    float s = (n < NN) ? sc[b * NN + n] : -INFINITY;
    v[r] = s;
    m0 = fmaxf(m0, s);
  }
  m0 = wave_bmax(m0);
  float m1 = -INFINITY;
#pragma unroll
  for (int r = 0; r < 16; ++r){
    int n = r * 64 + lane;
    bool valid = false;
    if (n < NN){
      bool mk = ldb<BINT>(mark, b * NN + n);
      valid = (pool == 0) ? !mk : mk;
    }
    v[r] = valid ? (v[r] - m0) : -1e8f;
    key[r] = fkey(v[r]);
    if (n < NN) m1 = fmaxf(m1, v[r]);
  }
  m1 = wave_bmax(m1);

  unsigned lo = 0u, hi = 0xFFFFFFFFu;
  while (lo < hi){
    unsigned mid = lo + ((hi - lo) >> 1) + 1u;
    int c = 0;
#pragma unroll
    for (int r = 0; r < 16; ++r) c += (key[r] >= mid) ? 1 : 0;
    c = wave_bsum_i(c);
    if (c >= KSEL) lo = mid; else hi = mid - 1u;
  }

  float p[16];
  float ls = 0.f;
#pragma unroll
  for (int r = 0; r < 16; ++r){
    int n = r * 64 + lane;
    float pp = (n < NN && key[r] >= lo) ? __expf(v[r] - m1) : 0.f;
    p[r] = pp;
    ls += pp;
  }
  ls = wave_bsum(ls);
  float zinv = (ls > 0.f) ? 1.f / ls : 0.f;
  float* w_out = wls + ((long)b * 2 + pool) * 1024;
#pragma unroll
  for (int r = 0; r < 16; ++r){
    int n = r * 64 + lane;
    if (n < NN) w_out[n] = p[r] * zinv;
  }
}
__global__ void k_topk(const int* flags, const float* scf, const float* scd,
                       const void* mark, float* wls){
  if (flags[1]) topk_body<true >(scf, scd, mark, wls);
  else          topk_body<false>(scf, scd, mark, wls);
}

// ---------------- gated partial sums: x_p streamed ONCE for both pools ----------------
__global__ void __launch_bounds__(256) k_psum(
    const float* __restrict__ wls, const float* __restrict__ x_p,
    float* __restrict__ part){
  __shared__ float wf[ROWS], wdd[ROWS];
  int t = threadIdx.x;
  int b = blockIdx.x, z = blockIdx.y;
  int n0 = z * ROWS;
  int ns = min(ROWS, NN - n0);
  if (t < ns){
    wf[t]  = wls[((long)b * 2 + 0) * 1024 + n0 + t];
    wdd[t] = wls[((long)b * 2 + 1) * 1024 + n0 + t];
  }
  __syncthreads();
  float sf = 0.f, mf = -INFINITY, sd = 0.f, md = -INFINITY;
  const float* xb = x_p + ((long)b * NN + n0) * HIDD + t;
  for (int k = 0; k < ns; ++k){
    float xv = xb[(long)k * HIDD];
    float gf = wf[k] * xv;
    float gd = wdd[k] * xv;
    sf += gf; mf = fmaxf(mf, gf);
    sd += gd; md = fmaxf(md, gd);
  }
  long pb = (((long)b * NSPL + z) * 4) * HIDD + t;
  part[pb + 0 * HIDD] = sf;
  part[pb + 1 * HIDD] = mf;
  part[pb + 2 * HIDD] = sd;
  part[pb + 3 * HIDD] = md;
}

// ---------------- final reduce over z-partials ----------------
template<bool F32>
__device__ __forceinline__ void pfin_body(const float* part, void* out){
  int t = threadIdx.x;
  int b = blockIdx.x;
  float sf = 0.f, mf = -INFINITY, sd = 0.f, md = -INFINITY;
#pragma unroll
  for (int z = 0; z < NSPL; ++z){
    long pb = (((long)b * NSPL + z) * 4) * HIDD + t;
    sf += part[pb + 0 * HIDD];
    mf = fmaxf(mf, part[pb + 1 * HIDD]);
    sd += part[pb + 2 * HIDD];
    md = fmaxf(md, part[pb + 3 * HIDD]);
  }
  long ob = (long)b * 1024;
  if (F32){
    ((float*)out)[ob + t] = sf;
    ((float*)out)[ob + 256 + t] = mf;
    ((float*)out)[ob + 512 + t] = sd;
    ((float*)out)[ob + 768 + t] = md;
  } else {
    ((bf16*)out)[ob + t] = __float2bfloat16(sf);
    ((bf16*)out)[ob + 256 + t] = __float2bfloat16(mf);
    ((bf16*)out)[ob + 512 + t] = __float2bfloat16(sd);
    ((bf16*)out)[ob + 768 + t] = __float2bfloat16(md);
  }
}
__global__ void k_pfin(const int* flags, const float* part, void* out){
  if (flags[0]) pfin_body<true >(part, out);
  else          pfin_body<false>(part, out);
}

extern "C" void kernel_launch(void* const* d_in, const int* in_sizes, int n_in,
                              void* d_out, int out_size, void* d_ws, size_t ws_size,
                              hipStream_t stream){
  const int*  time_idx = (const int*)d_in[0];
  const int*  op_idx   = (const int*)d_in[1];
  const void* vfeat    = d_in[2];
  const void* dpcs     = d_in[3];
  const void* adj_comp = d_in[4];
  const void* adj_coop = d_in[5];
  const void* dist     = d_in[6];
  const void* time_tab = d_in[7];
  const void* tp_tab   = d_in[8];
  const void* cs_tab   = d_in[9];
  const void* Wc       = d_in[10];
  const void* asrc_c   = d_in[11];
  const void* adst_c   = d_in[12];
  const void* wd_c     = d_in[13];
  const void* Wco      = d_in[14];
  const void* asrc_co  = d_in[15];
  const void* adst_co  = d_in[16];
  const void* wd_co    = d_in[17];
  const void* Wp       = d_in[18];
  const void* bp       = d_in[19];
  const void* vpd      = d_in[20];
  const void* vpf      = d_in[21];

  char* ws = (char*)d_ws;
  size_t o = 0;
  auto alloc = [&](size_t bytes)->char*{
    char* p = ws + o; o = (o + bytes + 255) & ~(size_t)255; return p;
  };
  int*   flags = (int*)alloc(16);
  float* wd_ws = (float*)alloc(8);
  float* distT = (float*)alloc((size_t)NN * NN * 4);
  u64*   adjPc = (u64*)alloc((size_t)NB * NN * NW * 8);
  u64*   adjPo = (u64*)alloc((size_t)NB * NN * NW * 8);
  float* x_ws  = (float*)alloc((size_t)NB * NN * 15 * 4);
  float* h_c   = (float*)alloc((size_t)NB * NN * COMD * 4);
  float* h_o   = (float*)alloc((size_t)NB * NN * COMD * 4);
  float* comp  = (float*)alloc((size_t)NB * NN * COMD * 4);
  float* coop  = (float*)alloc((size_t)NB * NN * COMD * 4);
  short* hB_hi = (short*)alloc((size_t)NB * 65536 * 2);
  short* hB_lo = (short*)alloc((size_t)NB * 65536 * 2);
  float* ed_c  = (float*)alloc((size_t)NB * NN * 4);
  float* es_c  = (float*)alloc((size_t)NB * NN * 4);
  float* ed_o  = (float*)alloc((size_t)NB * NN * 4);
  float* es_o  = (float*)alloc((size_t)NB * NN * 4);
  float* scf   = (float*)alloc((size_t)NB * NN * 4);
  float* scd   = (float*)alloc((size_t)NB * NN * 4);
  float* wls   = (float*)alloc((size_t)NB * 2 * 1024 * 4);
  float* part  = (float*)alloc((size_t)NB * NSPL * 4 * HIDD * 4);
  float* x_p   = (float*)alloc((size_t)NB * NN * HIDD * 4);

  k_sniff<<<1, 64, 0, stream>>>(dist, adj_comp, wd_c, wd_co, flags, wd_ws);
  k_dist_t<<<dim3((NN * NN + 255) / 256), dim3(256), 0, stream>>>(flags, dist, distT);
  dim3 pg(4, NW, NB);
  k_adj_pack<<<pg, dim3(256), 0, stream>>>(flags, adj_comp, adjPc);
  k_adj_pack<<<pg, dim3(256), 0, stream>>>(flags, adj_coop, adjPo);
  k_embed<<<dim3(NB * NN / 4), dim3(256), 0, stream>>>(
      flags, op_idx, vfeat, cs_tab, tp_tab, Wc, asrc_c, adst_c, x_ws, h_c, ed_c, es_c);
  k_hsplit<<<dim3(32, NB), dim3(256), 0, stream>>>(h_c, hB_hi, hB_lo);
  k_gat<<<dim3((NN + TI - 1) / TI, NB), dim3(256), 0, stream>>>(
      ed_c, es_c, wd_ws, 0, adjPc, distT, hB_hi, hB_lo, comp);
  k_hco<<<dim3(NB * NN / 4), dim3(256), 0, stream>>>(
      flags, x_ws, comp, Wco, asrc_co, adst_co, h_o, ed_o, es_o);
  k_hsplit<<<dim3(32, NB), dim3(256), 0, stream>>>(h_o, hB_hi, hB_lo);
  k_gat<<<dim3((NN + TI - 1) / TI, NB), dim3(256), 0, stream>>>(
      ed_o, es_o, wd_ws, 1, adjPo, distT, hB_hi, hB_lo, coop);
  k_xp<<<dim3(NB * NN / 8), dim3(256), 0, stream>>>(
      flags, time_idx, op_idx, vfeat, time_tab, cs_tab, tp_tab, comp, coop,
      Wp, bp, vpd, vpf, x_p, scf, scd);
  k_topk<<<dim3(NB, 2), dim3(64), 0, stream>>>(flags, scf, scd, dpcs, wls);
  k_psum<<<dim3(NB, NSPL), dim3(256), 0, stream>>>(wls, x_p, part);
  k_pfin<<<dim3(NB), dim3(256), 0, stream>>>(flags, part, d_out);
}

// Round 6
// 648.152 us; speedup vs baseline: 2.1652x; 1.2203x over previous
//
#include <hip/hip_runtime.h>
#include <hip/hip_bf16.h>

#define NB 32
#define NN 1000
#define COMD 64
#define HIDD 256
#define KSEL 500
#define TI 16        // dst rows per k_gat block
#define NSPL 16      // n-splits for k_psum
#define ROWS 63      // ceil(NN/NSPL)

typedef __hip_bfloat16 bf16;
typedef unsigned long long u64;
typedef __attribute__((ext_vector_type(4))) float f32x4;
typedef __attribute__((ext_vector_type(8))) short s16x8;

__device__ __forceinline__ float b2f(bf16 x){ return __bfloat162float(x); }

template<bool F32>
__device__ __forceinline__ float ldf(const void* p, long i){
  return F32 ? ((const float*)p)[i] : b2f(((const bf16*)p)[i]);
}
template<bool BINT>
__device__ __forceinline__ bool ldb(const void* p, long i){
  return BINT ? (((const int*)p)[i] != 0) : (((const unsigned char*)p)[i] != 0);
}

__device__ __forceinline__ float wave_sum(float v){
#pragma unroll
  for (int o = 32; o > 0; o >>= 1) v += __shfl_down(v, o, 64);
  return v;
}
// butterfly variants: ALL lanes end with the result
__device__ __forceinline__ float wave_bsum(float v){
#pragma unroll
  for (int o = 32; o > 0; o >>= 1) v += __shfl_xor(v, o, 64);
  return v;
}
__device__ __forceinline__ float wave_bmax(float v){
#pragma unroll
  for (int o = 32; o > 0; o >>= 1) v = fmaxf(v, __shfl_xor(v, o, 64));
  return v;
}
__device__ __forceinline__ int wave_bsum_i(int v){
#pragma unroll
  for (int o = 32; o > 0; o >>= 1) v += __shfl_xor(v, o, 64);
  return v;
}
__device__ __forceinline__ unsigned fkey(float f){
  unsigned u = __float_as_uint(f);
  return (u & 0x80000000u) ? ~u : (u | 0x80000000u);
}
// split fp32 into bf16 hi + bf16 lo with v ≈ hi + lo (residual ~2^-16 rel)
__device__ __forceinline__ void split_bf(float v, short& hi, short& lo){
  unsigned u = __float_as_uint(v);
  float hf = __uint_as_float(u & 0xFFFF0000u);
  hi = (short)(u >> 16);
  float r = v - hf;                 // exact
  lo = (short)(__float_as_uint(r) >> 16);
}
// write one h value into the MFMA B-fragment hi/lo planes
__device__ __forceinline__ void hB_write(short* hB_hi, short* hB_lo,
                                         int b, int n, int ch, float v){
  int kb = n >> 5, g4 = (n >> 3) & 3, u = n & 7;
  long off = ((((long)b * 32 + kb) * 4 + g4) * 64 + ch) * 8 + u;
  short hi, lo; split_bf(v, hi, lo);
  hB_hi[off] = hi; hB_lo[off] = lo;
}

// ---------------- dtype sniffing ----------------
__global__ void k_sniff(const void* dist, const void* adjc,
                        const void* wdc, const void* wdco,
                        int* flags, float* wd_out){
  if (blockIdx.x != 0 || threadIdx.x != 0) return;
  const unsigned* w = (const unsigned*)dist;
  int f32 = 0;
  for (int k = 0; k < 64; ++k) if ((w[k] & 0xFFFFu) >= 0x8000u){ f32 = 1; break; }
  const unsigned* bw = (const unsigned*)adjc;
  int as_int = 1;
  for (int k = 0; k < 64; ++k) if (bw[k] > 1u){ as_int = 0; break; }
  flags[0] = f32; flags[1] = as_int;
  wd_out[0] = f32 ? ((const float*)wdc)[0]  : b2f(((const bf16*)wdc)[0]);
  wd_out[1] = f32 ? ((const float*)wdco)[0] : b2f(((const bf16*)wdco)[0]);
}

// ---------------- distance transpose (tiled, bf16 out) ----------------
template<bool F32>
__device__ __forceinline__ void dist_t_body(const void* dist, bf16* distTb){
  __shared__ bf16 tile[64][68];      // +4 pad: 2-way bank alias only (free)
  int t = threadIdx.x;
  int wv = t >> 6, lane = t & 63;
  int it = blockIdx.x * 64, jt = blockIdx.y * 64;
#pragma unroll
  for (int r = 0; r < 16; ++r){
    int jl = r * 4 + wv;
    int j = jt + jl, i = it + lane;
    float v = (j < NN && i < NN) ? ldf<F32>(dist, (long)j * NN + i) : 0.f;
    tile[jl][lane] = __float2bfloat16(v);
  }
  __syncthreads();
#pragma unroll
  for (int r = 0; r < 16; ++r){
    int il = r * 4 + wv;
    int i = it + il, j = jt + lane;
    if (i < NN && j < NN) distTb[(long)i * NN + j] = tile[lane][il];
  }
}
__global__ void k_dist_t(const int* flags, const void* dist, bf16* distTb){
  if (flags[0]) dist_t_body<true>(dist, distTb);
  else          dist_t_body<false>(dist, distTb);
}

// ---------------- adjacency pack via ballot ----------------
// adjQ[b][iw][j] bit il = adj[b][j][iw*64+il]  (mask[i][j] = adj[j][i])
template<bool BINT>
__device__ __forceinline__ void adjq_body(const void* adj, u64* adjQ){
  int t = threadIdx.x;
  int wv = t >> 6, lane = t & 63;
  int j0 = blockIdx.x * 64;
  int iw = blockIdx.y, b = blockIdx.z;
  long base = (long)b * NN * NN;
  int i = iw * 64 + lane;
  bool iok = i < NN;
#pragma unroll
  for (int r = 0; r < 16; ++r){
    int j = j0 + wv * 16 + r;
    bool pred = (iok && j < NN) ? ldb<BINT>(adj, base + (long)j * NN + i) : false;
    u64 word = __ballot(pred);
    if (lane == 0) adjQ[((long)b * 16 + iw) * 1024 + j] = word;
  }
}
__global__ void k_adjq(const int* flags, const void* adj, u64* adjQ){
  if (flags[1]) adjq_body<true>(adj, adjQ);
  else          adjq_body<false>(adj, adjQ);
}

// ---------------- embedding + h_c (direct to hB planes) + attn scalars ----------------
template<bool F32>
__device__ __forceinline__ void embed_body(
    const int* op_idx, const void* vf, const void* cs_tab, const void* tp_tab,
    const void* Wc, const void* asrc, const void* adst,
    float* x_out, short* hB_hi, short* hB_lo, float* ed_out, float* es_out){
  int t = threadIdx.x;
  int w = t >> 6, lane = t & 63;
  int g = blockIdx.x * 4 + w;          // b*NN + n
  int b = g / NN, n = g - b * NN;
  int op = op_idx[g];
  float xv = 0.f, hacc = 0.f;
#pragma unroll
  for (int f = 0; f < 15; ++f){
    float x_f;
    if (f < 4)      x_f = ldf<F32>(cs_tab, n * 4 + f);
    else if (f < 6) x_f = ldf<F32>(tp_tab, op * 2 + (f - 4));
    else            x_f = ldf<F32>(vf, (long)g * 9 + (f - 6));
    if (lane == f) xv = x_f;
    hacc += x_f * ldf<F32>(Wc, f * COMD + lane);
  }
  if (lane < 15) x_out[g * 15 + lane] = xv;
  hB_write(hB_hi, hB_lo, b, n, lane, hacc);
  float sd = wave_sum(hacc * ldf<F32>(adst, lane));
  float ss = wave_sum(hacc * ldf<F32>(asrc, lane));
  if (lane == 0){ ed_out[g] = sd; es_out[g] = ss; }
}
__global__ void __launch_bounds__(256) k_embed(
    const int* flags, const int* op_idx, const void* vf, const void* cs_tab,
    const void* tp_tab, const void* Wc, const void* asrc, const void* adst,
    float* x_out, short* hB_hi, short* hB_lo, float* ed_out, float* es_out){
  if (flags[0]) embed_body<true >(op_idx, vf, cs_tab, tp_tab, Wc, asrc, adst, x_out, hB_hi, hB_lo, ed_out, es_out);
  else          embed_body<false>(op_idx, vf, cs_tab, tp_tab, Wc, asrc, adst, x_out, hB_hi, hB_lo, ed_out, es_out);
}

// ---------------- h_co = [x, comp] @ Wco (direct to hB planes) ----------------
template<bool F32>
__device__ __forceinline__ void hco_body(
    const float* x_ws, const float* comp, const void* Wco,
    const void* asrc, const void* adst,
    short* hB_hi, short* hB_lo, float* ed_out, float* es_out){
  __shared__ float cx[4][80] __attribute__((aligned(16)));
  int t = threadIdx.x;
  int w = t >> 6, lane = t & 63;
  int base = blockIdx.x * 4;
  for (int idx = t; idx < 4 * 79; idx += 256){
    int nl = idx / 79, f = idx - nl * 79;
    int g = base + nl;
    cx[nl][f] = (f < 15) ? x_ws[g * 15 + f] : comp[(long)g * COMD + (f - 15)];
  }
  __syncthreads();
  int g = base + w;
  int b = g / NN, n = g - b * NN;
  float hacc = 0.f;
#pragma unroll
  for (int f4 = 0; f4 < 76; f4 += 4){
    float4 sv = *(const float4*)&cx[w][f4];
    float w0 = ldf<F32>(Wco, (f4 + 0) * COMD + lane);
    float w1 = ldf<F32>(Wco, (f4 + 1) * COMD + lane);
    float w2 = ldf<F32>(Wco, (f4 + 2) * COMD + lane);
    float w3 = ldf<F32>(Wco, (f4 + 3) * COMD + lane);
    hacc += sv.x * w0 + sv.y * w1 + sv.z * w2 + sv.w * w3;
  }
#pragma unroll
  for (int f = 76; f < 79; ++f)
    hacc += cx[w][f] * ldf<F32>(Wco, f * COMD + lane);
  hB_write(hB_hi, hB_lo, b, n, lane, hacc);
  float sd = wave_sum(hacc * ldf<F32>(adst, lane));
  float ss = wave_sum(hacc * ldf<F32>(asrc, lane));
  if (lane == 0){ ed_out[g] = sd; es_out[g] = ss; }
}
__global__ void __launch_bounds__(256) k_hco(
    const int* flags, const float* x_ws, const float* comp, const void* Wco,
    const void* asrc, const void* adst,
    short* hB_hi, short* hB_lo, float* ed_out, float* es_out){
  if (flags[0]) hco_body<true >(x_ws, comp, Wco, asrc, adst, hB_hi, hB_lo, ed_out, es_out);
  else          hco_body<false>(x_ws, comp, Wco, asrc, adst, hB_hi, hB_lo, ed_out, es_out);
}

// ---------------- masked-softmax GAT: online softmax + dbuf MFMA ----------------
// 5 barriers total: 1 softmax-stats + 4 staging (double-buffered pA).
__global__ void __launch_bounds__(256) k_gat(
    const float* __restrict__ ed, const float* __restrict__ es,
    const float* __restrict__ wd_ws, int wd_idx, const u64* __restrict__ adjQ,
    const bf16* __restrict__ distTb,
    const short* __restrict__ hB_hi, const short* __restrict__ hB_lo,
    float* __restrict__ reps){
  __shared__ short pA_hi[2][4096] __attribute__((aligned(16)));
  __shared__ short pA_lo[2][4096] __attribute__((aligned(16)));
  __shared__ float redm[TI][4], redz[TI][4];
  int t = threadIdx.x;
  int wv = t >> 6, lane = t & 63;
  int b = blockIdx.y;
  int i0 = blockIdx.x * TI;
  float wd = wd_ws[wd_idx];
  int sb = i0 & 63;
  const u64* adjQb = adjQ + ((long)b * 16 + (i0 >> 6)) * 1024;

  float ed_i[TI];
#pragma unroll
  for (int ti = 0; ti < TI; ++ti)
    ed_i[ti] = (i0 + ti < NN) ? ed[b * NN + i0 + ti] : 0.f;

  // phase 1: scores into registers (j = c*256 + wv*64 + lane)
  float p[TI][4], m_l[TI];
#pragma unroll
  for (int ti = 0; ti < TI; ++ti) m_l[ti] = -INFINITY;
#pragma unroll
  for (int c = 0; c < 4; ++c){
    int j = c * 256 + wv * 64 + lane;
    int jc = (j < NN) ? j : (NN - 1);
    float esj = es[b * NN + jc];
    u64 word = adjQb[j] >> sb;          // adjQ zero-padded for j >= NN
#pragma unroll
    for (int ti = 0; ti < TI; ++ti){
      int ic = (i0 + ti < NN) ? (i0 + ti) : (NN - 1);
      bool edge = (word >> ti) & 1ull;
      float d = b2f(distTb[(long)ic * NN + jc]);
      float v = ed_i[ti] + esj + wd * d;
      v = fmaxf(v, 0.2f * v);           // leaky_relu (0.2 > 0)
      float e = edge ? v : -INFINITY;
      p[ti][c] = e;
      m_l[ti] = fmaxf(m_l[ti], e);
    }
  }
  // per-wave online stats (shuffles only), then ONE barrier to combine
  float z_l[TI];
#pragma unroll
  for (int ti = 0; ti < TI; ++ti){
    float m = wave_bmax(m_l[ti]);
    m_l[ti] = m;
    float zs = 0.f;
#pragma unroll
    for (int c = 0; c < 4; ++c){
      float e = p[ti][c];
      float pp = (e > -INFINITY) ? __expf(e - m) : 0.f;
      p[ti][c] = pp;
      zs += pp;
    }
    z_l[ti] = wave_bsum(zs);
  }
  if (lane == 0){
#pragma unroll
    for (int ti = 0; ti < TI; ++ti){ redm[ti][wv] = m_l[ti]; redz[ti][wv] = z_l[ti]; }
  }
  __syncthreads();
  float s[TI];                          // exp(m_wv - m_i) / z_i, folded into alpha
#pragma unroll
  for (int ti = 0; ti < TI; ++ti){
    float m0 = redm[ti][0], m1 = redm[ti][1], m2 = redm[ti][2], m3 = redm[ti][3];
    float mi = fmaxf(fmaxf(m0, m1), fmaxf(m2, m3));
    float zi = 0.f;
    if (mi > -INFINITY){
      zi = ((m0 > -INFINITY) ? redz[ti][0] * __expf(m0 - mi) : 0.f)
         + ((m1 > -INFINITY) ? redz[ti][1] * __expf(m1 - mi) : 0.f)
         + ((m2 > -INFINITY) ? redz[ti][2] * __expf(m2 - mi) : 0.f)
         + ((m3 > -INFINITY) ? redz[ti][3] * __expf(m3 - mi) : 0.f);
    }
    s[ti] = (zi > 0.f && m_l[ti] > -INFINITY) ? __expf(m_l[ti] - mi) / zi : 0.f;
  }

  // phase 3: D = alpha @ h via MFMA, double-buffered alpha staging
  int wg = (lane >> 3) & 3, wu = lane & 7;
  int kbW = wv * 2 + (lane >> 5);
  int Ag = lane >> 4, Am = lane & 15;
  long hBbase = (long)b * 65536;
  f32x4 acc = {0.f, 0.f, 0.f, 0.f};

  auto stage = [&](int c, int buf){
    int widx = kbW * 512 + wg * 128 + wu;
#pragma unroll
    for (int ti = 0; ti < TI; ++ti){
      float a = p[ti][c] * s[ti];
      short hi, lo; split_bf(a, hi, lo);
      pA_hi[buf][widx + ti * 8] = hi;
      pA_lo[buf][widx + ti * 8] = lo;
    }
  };

  stage(0, 0);
#pragma unroll
  for (int c = 0; c < 4; ++c){
    __syncthreads();
    if (c < 3) stage(c + 1, (c + 1) & 1);
    int buf = c & 1;
#pragma unroll
    for (int kbL = 0; kbL < 8; ++kbL){
      int kb = c * 8 + kbL;
      int aidx = kbL * 512 + Ag * 128 + Am * 8;
      s16x8 a_hi = *(const s16x8*)&pA_hi[buf][aidx];
      s16x8 a_lo = *(const s16x8*)&pA_lo[buf][aidx];
      long bidx = hBbase + (((long)kb * 4 + Ag) * 64 + wv * 16 + Am) * 8;
      s16x8 b_hi = *(const s16x8*)&hB_hi[bidx];
      s16x8 b_lo = *(const s16x8*)&hB_lo[bidx];
      acc = __builtin_amdgcn_mfma_f32_16x16x32_bf16(a_hi, b_hi, acc, 0, 0, 0);
      acc = __builtin_amdgcn_mfma_f32_16x16x32_bf16(a_hi, b_lo, acc, 0, 0, 0);
      acc = __builtin_amdgcn_mfma_f32_16x16x32_bf16(a_lo, b_hi, acc, 0, 0, 0);
    }
  }
  // epilogue: row = (lane>>4)*4+reg (dst), col = lane&15; alpha pre-normalized
#pragma unroll
  for (int reg = 0; reg < 4; ++reg){
    int ti = (lane >> 4) * 4 + reg;
    int ch = wv * 16 + (lane & 15);
    float v = acc[reg];
    v = (v > 0.f) ? v : expm1f(v);
    if (i0 + ti < NN)
      reps[((long)b * NN + i0 + ti) * COMD + ch] = v;
  }
}

// ---------------- x_p = sag@Wp + bp, fused score dots ----------------
template<bool F32>
__device__ __forceinline__ void xp_body(
    const int* time_idx, const int* op_idx, const void* vf, const void* time_tab,
    const void* cs_tab, const void* tp_tab, const float* comp, const float* coop,
    const void* Wp, const void* bp, const void* vpd, const void* vpf,
    float* x_p, float* scf, float* scd){
  __shared__ float sag[8][148] __attribute__((aligned(16)));
  __shared__ float sred[8][2][4];
  int t = threadIdx.x;
  int wv = t >> 6, lane = t & 63;
  int base = blockIdx.x * 8;
  for (int idx = t; idx < 8 * 147; idx += 256){
    int nl = idx / 147, f = idx - nl * 147;
    int g = base + nl;
    int n = g % NN;
    float v;
    if (f < 4)       v = ldf<F32>(time_tab, time_idx[g] * 4 + f);
    else if (f < 8)  v = ldf<F32>(cs_tab, n * 4 + (f - 4));
    else if (f < 10) v = ldf<F32>(tp_tab, op_idx[g] * 2 + (f - 8));
    else if (f < 19) v = ldf<F32>(vf, (long)g * 9 + (f - 10));
    else if (f < 83) v = comp[(long)g * COMD + (f - 19)];
    else             v = coop[(long)g * COMD + (f - 83)];
    sag[nl][f] = v;
  }
  __syncthreads();
  int hh = t;
  float a[8];
#pragma unroll
  for (int nl = 0; nl < 8; ++nl) a[nl] = 0.f;
  for (int f4 = 0; f4 < 144; f4 += 4){
    float w0 = ldf<F32>(Wp, (f4 + 0) * HIDD + hh);
    float w1 = ldf<F32>(Wp, (f4 + 1) * HIDD + hh);
    float w2 = ldf<F32>(Wp, (f4 + 2) * HIDD + hh);
    float w3 = ldf<F32>(Wp, (f4 + 3) * HIDD + hh);
#pragma unroll
    for (int nl = 0; nl < 8; ++nl){
      float4 sv = *(const float4*)&sag[nl][f4];
      a[nl] += sv.x * w0 + sv.y * w1 + sv.z * w2 + sv.w * w3;
    }
  }
#pragma unroll
  for (int f = 144; f < 147; ++f){
    float wf = ldf<F32>(Wp, f * HIDD + hh);
#pragma unroll
    for (int nl = 0; nl < 8; ++nl)
      a[nl] += sag[nl][f] * wf;
  }
  float bb = ldf<F32>(bp, hh);
#pragma unroll
  for (int nl = 0; nl < 8; ++nl){
    a[nl] += bb;
    x_p[(long)(base + nl) * HIDD + hh] = a[nl];
  }
  float vd = ldf<F32>(vpd, hh), vfl = ldf<F32>(vpf, hh);
#pragma unroll
  for (int nl = 0; nl < 8; ++nl){
    float sD = wave_sum(a[nl] * vd);
    float sF = wave_sum(a[nl] * vfl);
    if (lane == 0){ sred[nl][0][wv] = sF; sred[nl][1][wv] = sD; }
  }
  __syncthreads();
  if (t < 16){
    int nl = t >> 1, st = t & 1;
    float s = sred[nl][st][0] + sred[nl][st][1] + sred[nl][st][2] + sred[nl][st][3];
    if (st == 0) scf[base + nl] = s; else scd[base + nl] = s;
  }
}
__global__ void __launch_bounds__(256) k_xp(
    const int* flags, const int* time_idx, const int* op_idx, const void* vf,
    const void* time_tab, const void* cs_tab, const void* tp_tab,
    const float* comp, const float* coop, const void* Wp, const void* bp,
    const void* vpd, const void* vpf, float* x_p, float* scf, float* scd){
  if (flags[0]) xp_body<true >(time_idx, op_idx, vf, time_tab, cs_tab, tp_tab, comp, coop, Wp, bp, vpd, vpf, x_p, scf, scd);
  else          xp_body<false>(time_idx, op_idx, vf, time_tab, cs_tab, tp_tab, comp, coop, Wp, bp, vpd, vpf, x_p, scf, scd);
}

// ---------------- top-k weights: one wave per (b,pool), zero barriers ----------------
template<bool BINT>
__device__ __forceinline__ void topk_body(
    const float* scf, const float* scd, const void* mark, float* wls){
  int lane = threadIdx.x;           // 64 threads
  int b = blockIdx.x, pool = blockIdx.y;
  const float* sc = (pool == 0) ? scf : scd;
  float v[16]; unsigned key[16];
  float m0 = -INFINITY;
#pragma unroll
  for (int r = 0; r < 16; ++r){
    int n = r * 64 + lane;
    float s = (n < NN) ? sc[b * NN + n] : -INFINITY;
    v[r] = s;
    m0 = fmaxf(m0, s);
  }
  m0 = wave_bmax(m0);
  float m1 = -INFINITY;
#pragma unroll
  for (int r = 0; r < 16; ++r){
    int n = r * 64 + lane;
    bool valid = false;
    if (n < NN){
      bool mk = ldb<BINT>(mark, b * NN + n);
      valid = (pool == 0) ? !mk : mk;
    }
    v[r] = valid ? (v[r] - m0) : -1e8f;
    key[r] = fkey(v[r]);
    if (n < NN) m1 = fmaxf(m1, v[r]);
  }
  m1 = wave_bmax(m1);

  unsigned lo = 0u, hi = 0xFFFFFFFFu;
  while (lo < hi){
    unsigned mid = lo + ((hi - lo) >> 1) + 1u;
    int c = 0;
#pragma unroll
    for (int r = 0; r < 16; ++r) c += (key[r] >= mid) ? 1 : 0;
    c = wave_bsum_i(c);
    if (c >= KSEL) lo = mid; else hi = mid - 1u;
  }

  float p[16];
  float ls = 0.f;
#pragma unroll
  for (int r = 0; r < 16; ++r){
    int n = r * 64 + lane;
    float pp = (n < NN && key[r] >= lo) ? __expf(v[r] - m1) : 0.f;
    p[r] = pp;
    ls += pp;
  }
  ls = wave_bsum(ls);
  float zinv = (ls > 0.f) ? 1.f / ls : 0.f;
  float* w_out = wls + ((long)b * 2 + pool) * 1024;
#pragma unroll
  for (int r = 0; r < 16; ++r){
    int n = r * 64 + lane;
    if (n < NN) w_out[n] = p[r] * zinv;
  }
}
__global__ void k_topk(const int* flags, const float* scf, const float* scd,
                       const void* mark, float* wls){
  if (flags[1]) topk_body<true >(scf, scd, mark, wls);
  else          topk_body<false>(scf, scd, mark, wls);
}

// ---------------- gated partial sums: x_p streamed ONCE for both pools ----------------
__global__ void __launch_bounds__(256) k_psum(
    const float* __restrict__ wls, const float* __restrict__ x_p,
    float* __restrict__ part){
  __shared__ float wf[ROWS], wdd[ROWS];
  int t = threadIdx.x;
  int b = blockIdx.x, z = blockIdx.y;
  int n0 = z * ROWS;
  int ns = min(ROWS, NN - n0);
  if (t < ns){
    wf[t]  = wls[((long)b * 2 + 0) * 1024 + n0 + t];
    wdd[t] = wls[((long)b * 2 + 1) * 1024 + n0 + t];
  }
  __syncthreads();
  float sf = 0.f, mf = -INFINITY, sd = 0.f, md = -INFINITY;
  const float* xb = x_p + ((long)b * NN + n0) * HIDD + t;
  for (int k = 0; k < ns; ++k){
    float xv = xb[(long)k * HIDD];
    float gf = wf[k] * xv;
    float gd = wdd[k] * xv;
    sf += gf; mf = fmaxf(mf, gf);
    sd += gd; md = fmaxf(md, gd);
  }
  long pb = (((long)b * NSPL + z) * 4) * HIDD + t;
  part[pb + 0 * HIDD] = sf;
  part[pb + 1 * HIDD] = mf;
  part[pb + 2 * HIDD] = sd;
  part[pb + 3 * HIDD] = md;
}

// ---------------- final reduce over z-partials ----------------
template<bool F32>
__device__ __forceinline__ void pfin_body(const float* part, void* out){
  int t = threadIdx.x;
  int b = blockIdx.x;
  float sf = 0.f, mf = -INFINITY, sd = 0.f, md = -INFINITY;
#pragma unroll
  for (int z = 0; z < NSPL; ++z){
    long pb = (((long)b * NSPL + z) * 4) * HIDD + t;
    sf += part[pb + 0 * HIDD];
    mf = fmaxf(mf, part[pb + 1 * HIDD]);
    sd += part[pb + 2 * HIDD];
    md = fmaxf(md, part[pb + 3 * HIDD]);
  }
  long ob = (long)b * 1024;
  if (F32){
    ((float*)out)[ob + t] = sf;
    ((float*)out)[ob + 256 + t] = mf;
    ((float*)out)[ob + 512 + t] = sd;
    ((float*)out)[ob + 768 + t] = md;
  } else {
    ((bf16*)out)[ob + t] = __float2bfloat16(sf);
    ((bf16*)out)[ob + 256 + t] = __float2bfloat16(mf);
    ((bf16*)out)[ob + 512 + t] = __float2bfloat16(sd);
    ((bf16*)out)[ob + 768 + t] = __float2bfloat16(md);
  }
}
__global__ void k_pfin(const int* flags, const float* part, void* out){
  if (flags[0]) pfin_body<true >(part, out);
  else          pfin_body<false>(part, out);
}

extern "C" void kernel_launch(void* const* d_in, const int* in_sizes, int n_in,
                              void* d_out, int out_size, void* d_ws, size_t ws_size,
                              hipStream_t stream){
  const int*  time_idx = (const int*)d_in[0];
  const int*  op_idx   = (const int*)d_in[1];
  const void* vfeat    = d_in[2];
  const void* dpcs     = d_in[3];
  const void* adj_comp = d_in[4];
  const void* adj_coop = d_in[5];
  const void* dist     = d_in[6];
  const void* time_tab = d_in[7];
  const void* tp_tab   = d_in[8];
  const void* cs_tab   = d_in[9];
  const void* Wc       = d_in[10];
  const void* asrc_c   = d_in[11];
  const void* adst_c   = d_in[12];
  const void* wd_c     = d_in[13];
  const void* Wco      = d_in[14];
  const void* asrc_co  = d_in[15];
  const void* adst_co  = d_in[16];
  const void* wd_co    = d_in[17];
  const void* Wp       = d_in[18];
  const void* bp       = d_in[19];
  const void* vpd      = d_in[20];
  const void* vpf      = d_in[21];

  char* ws = (char*)d_ws;
  size_t o = 0;
  auto alloc = [&](size_t bytes)->char*{
    char* p = ws + o; o = (o + bytes + 255) & ~(size_t)255; return p;
  };
  int*   flags  = (int*)alloc(16);
  float* wd_ws  = (float*)alloc(8);
  bf16*  distTb = (bf16*)alloc((size_t)NN * NN * 2);
  u64*   adjQc  = (u64*)alloc((size_t)NB * 16 * 1024 * 8);
  u64*   adjQo  = (u64*)alloc((size_t)NB * 16 * 1024 * 8);
  float* x_ws   = (float*)alloc((size_t)NB * NN * 15 * 4);
  float* comp   = (float*)alloc((size_t)NB * NN * COMD * 4);
  float* coop   = (float*)alloc((size_t)NB * NN * COMD * 4);
  short* hB_hi  = (short*)alloc((size_t)NB * 65536 * 2);
  short* hB_lo  = (short*)alloc((size_t)NB * 65536 * 2);
  float* ed_c   = (float*)alloc((size_t)NB * NN * 4);
  float* es_c   = (float*)alloc((size_t)NB * NN * 4);
  float* ed_o   = (float*)alloc((size_t)NB * NN * 4);
  float* es_o   = (float*)alloc((size_t)NB * NN * 4);
  float* scf    = (float*)alloc((size_t)NB * NN * 4);
  float* scd    = (float*)alloc((size_t)NB * NN * 4);
  float* wls    = (float*)alloc((size_t)NB * 2 * 1024 * 4);
  float* part   = (float*)alloc((size_t)NB * NSPL * 4 * HIDD * 4);
  float* x_p    = (float*)alloc((size_t)NB * NN * HIDD * 4);

  k_sniff<<<1, 64, 0, stream>>>(dist, adj_comp, wd_c, wd_co, flags, wd_ws);
  k_dist_t<<<dim3(16, 16), dim3(256), 0, stream>>>(flags, dist, distTb);
  dim3 qg(16, 16, NB);
  k_adjq<<<qg, dim3(256), 0, stream>>>(flags, adj_comp, adjQc);
  k_adjq<<<qg, dim3(256), 0, stream>>>(flags, adj_coop, adjQo);
  k_embed<<<dim3(NB * NN / 4), dim3(256), 0, stream>>>(
      flags, op_idx, vfeat, cs_tab, tp_tab, Wc, asrc_c, adst_c,
      x_ws, hB_hi, hB_lo, ed_c, es_c);
  k_gat<<<dim3((NN + TI - 1) / TI, NB), dim3(256), 0, stream>>>(
      ed_c, es_c, wd_ws, 0, adjQc, distTb, hB_hi, hB_lo, comp);
  k_hco<<<dim3(NB * NN / 4), dim3(256), 0, stream>>>(
      flags, x_ws, comp, Wco, asrc_co, adst_co, hB_hi, hB_lo, ed_o, es_o);
  k_gat<<<dim3((NN + TI - 1) / TI, NB), dim3(256), 0, stream>>>(
      ed_o, es_o, wd_ws, 1, adjQo, distTb, hB_hi, hB_lo, coop);
  k_xp<<<dim3(NB * NN / 8), dim3(256), 0, stream>>>(
      flags, time_idx, op_idx, vfeat, time_tab, cs_tab, tp_tab, comp, coop,
      Wp, bp, vpd, vpf, x_p, scf, scd);
  k_topk<<<dim3(NB, 2), dim3(64), 0, stream>>>(flags, scf, scd, dpcs, wls);
  k_psum<<<dim3(NB, NSPL), dim3(256), 0, stream>>>(wls, x_p, part);
  k_pfin<<<dim3(NB), dim3(256), 0, stream>>>(flags, part, d_out);
}

// Round 7
// 613.462 us; speedup vs baseline: 2.2876x; 1.0565x over previous
//
#include <hip/hip_runtime.h>
#include <hip/hip_bf16.h>

#define NB 32
#define NN 1000
#define COMD 64
#define HIDD 256
#define KSEL 500
#define TI 16        // dst rows per k_gat block
#define NSPL 16      // n-splits for k_psum
#define ROWS 63      // ceil(NN/NSPL)

typedef __hip_bfloat16 bf16;
typedef unsigned long long u64;
typedef __attribute__((ext_vector_type(4))) float f32x4;
typedef __attribute__((ext_vector_type(8))) short s16x8;

__device__ __forceinline__ float b2f(bf16 x){ return __bfloat162float(x); }

template<bool F32>
__device__ __forceinline__ float ldf(const void* p, long i){
  return F32 ? ((const float*)p)[i] : b2f(((const bf16*)p)[i]);
}
template<bool BINT>
__device__ __forceinline__ bool ldb(const void* p, long i){
  return BINT ? (((const int*)p)[i] != 0) : (((const unsigned char*)p)[i] != 0);
}

__device__ __forceinline__ float wave_sum(float v){
#pragma unroll
  for (int o = 32; o > 0; o >>= 1) v += __shfl_down(v, o, 64);
  return v;
}
__device__ __forceinline__ float wave_bsum(float v){
#pragma unroll
  for (int o = 32; o > 0; o >>= 1) v += __shfl_xor(v, o, 64);
  return v;
}
__device__ __forceinline__ float wave_bmax(float v){
#pragma unroll
  for (int o = 32; o > 0; o >>= 1) v = fmaxf(v, __shfl_xor(v, o, 64));
  return v;
}
__device__ __forceinline__ int wave_bsum_i(int v){
#pragma unroll
  for (int o = 32; o > 0; o >>= 1) v += __shfl_xor(v, o, 64);
  return v;
}
__device__ __forceinline__ unsigned fkey(float f){
  unsigned u = __float_as_uint(f);
  return (u & 0x80000000u) ? ~u : (u | 0x80000000u);
}
// split fp32 into bf16 hi + bf16 lo with v ≈ hi + lo (residual ~2^-16 rel)
__device__ __forceinline__ void split_bf(float v, short& hi, short& lo){
  unsigned u = __float_as_uint(v);
  float hf = __uint_as_float(u & 0xFFFF0000u);
  hi = (short)(u >> 16);
  float r = v - hf;                 // exact
  lo = (short)(__float_as_uint(r) >> 16);
}
// write one h value into the MFMA B-fragment hi/lo planes (64-col variant)
__device__ __forceinline__ void hB_write(short* hB_hi, short* hB_lo,
                                         int b, int n, int ch, float v){
  int kb = n >> 5, g4 = (n >> 3) & 3, u = n & 7;
  long off = ((((long)b * 32 + kb) * 4 + g4) * 64 + ch) * 8 + u;
  short hi, lo; split_bf(v, hi, lo);
  hB_hi[off] = hi; hB_lo[off] = lo;
}

// ---------------- dtype sniffing ----------------
__global__ void k_sniff(const void* dist, const void* adjc,
                        const void* wdc, const void* wdco,
                        int* flags, float* wd_out){
  if (blockIdx.x != 0 || threadIdx.x != 0) return;
  const unsigned* w = (const unsigned*)dist;
  int f32 = 0;
  for (int k = 0; k < 64; ++k) if ((w[k] & 0xFFFFu) >= 0x8000u){ f32 = 1; break; }
  const unsigned* bw = (const unsigned*)adjc;
  int as_int = 1;
  for (int k = 0; k < 64; ++k) if (bw[k] > 1u){ as_int = 0; break; }
  flags[0] = f32; flags[1] = as_int;
  wd_out[0] = f32 ? ((const float*)wdc)[0]  : b2f(((const bf16*)wdc)[0]);
  wd_out[1] = f32 ? ((const float*)wdco)[0] : b2f(((const bf16*)wdco)[0]);
}

// ---------------- distance transpose (tiled, bf16 out) ----------------
template<bool F32>
__device__ __forceinline__ void dist_t_body(const void* dist, bf16* distTb){
  __shared__ bf16 tile[64][68];
  int t = threadIdx.x;
  int wv = t >> 6, lane = t & 63;
  int it = blockIdx.x * 64, jt = blockIdx.y * 64;
#pragma unroll
  for (int r = 0; r < 16; ++r){
    int jl = r * 4 + wv;
    int j = jt + jl, i = it + lane;
    float v = (j < NN && i < NN) ? ldf<F32>(dist, (long)j * NN + i) : 0.f;
    tile[jl][lane] = __float2bfloat16(v);
  }
  __syncthreads();
#pragma unroll
  for (int r = 0; r < 16; ++r){
    int il = r * 4 + wv;
    int i = it + il, j = jt + lane;
    if (i < NN && j < NN) distTb[(long)i * NN + j] = tile[lane][il];
  }
}
__global__ void k_dist_t(const int* flags, const void* dist, bf16* distTb){
  if (flags[0]) dist_t_body<true>(dist, distTb);
  else          dist_t_body<false>(dist, distTb);
}

// ---------------- adjacency pack via ballot ----------------
template<bool BINT>
__device__ __forceinline__ void adjq_body(const void* adj, u64* adjQ){
  int t = threadIdx.x;
  int wv = t >> 6, lane = t & 63;
  int j0 = blockIdx.x * 64;
  int iw = blockIdx.y, b = blockIdx.z;
  long base = (long)b * NN * NN;
  int i = iw * 64 + lane;
  bool iok = i < NN;
#pragma unroll
  for (int r = 0; r < 16; ++r){
    int j = j0 + wv * 16 + r;
    bool pred = (iok && j < NN) ? ldb<BINT>(adj, base + (long)j * NN + i) : false;
    u64 word = __ballot(pred);
    if (lane == 0) adjQ[((long)b * 16 + iw) * 1024 + j] = word;
  }
}
__global__ void k_adjq(const int* flags, const void* adj, u64* adjQ){
  if (flags[1]) adjq_body<true>(adj, adjQ);
  else          adjq_body<false>(adj, adjQ);
}

// ---------------- Wp -> B-frag planes (K padded to 160) + projected score vecs ----------------
template<bool F32>
__device__ __forceinline__ void wprep_body(
    const void* Wp, const void* vpd, const void* vpf, const void* bp,
    short* WpB_hi, short* WpB_lo, float* wv_ws){
  int f = blockIdx.x;
  int lane = threadIdx.x;            // 64 threads
  if (f < 160){
    float wrow[4];
#pragma unroll
    for (int r = 0; r < 4; ++r){
      int ch = r * 64 + lane;
      wrow[r] = (f < 147) ? ldf<F32>(Wp, (long)f * HIDD + ch) : 0.f;
    }
    int kb = f >> 5, q = (f >> 3) & 3, u = f & 7;
#pragma unroll
    for (int r = 0; r < 4; ++r){
      int ch = r * 64 + lane;
      long off = (((long)(kb * 4 + q)) * 256 + ch) * 8 + u;
      short hi, lo; split_bf(wrow[r], hi, lo);
      WpB_hi[off] = hi; WpB_lo[off] = lo;
    }
    float ad = 0.f, af = 0.f;
#pragma unroll
    for (int r = 0; r < 4; ++r){
      int ch = r * 64 + lane;
      ad += wrow[r] * ldf<F32>(vpd, ch);
      af += wrow[r] * ldf<F32>(vpf, ch);
    }
    ad = wave_bsum(ad); af = wave_bsum(af);
    if (lane == 0){ wv_ws[f] = ad; wv_ws[160 + f] = af; }
  } else {
    float ad = 0.f, af = 0.f;
#pragma unroll
    for (int r = 0; r < 4; ++r){
      int ch = r * 64 + lane;
      float bb = ldf<F32>(bp, ch);
      ad += bb * ldf<F32>(vpd, ch);
      af += bb * ldf<F32>(vpf, ch);
    }
    ad = wave_bsum(ad); af = wave_bsum(af);
    if (lane == 0){ wv_ws[320] = ad; wv_ws[321] = af; }
  }
}
__global__ void k_wprep(const int* flags, const void* Wp, const void* vpd,
                        const void* vpf, const void* bp,
                        short* WpB_hi, short* WpB_lo, float* wv_ws){
  if (flags[0]) wprep_body<true >(Wp, vpd, vpf, bp, WpB_hi, WpB_lo, wv_ws);
  else          wprep_body<false>(Wp, vpd, vpf, bp, WpB_hi, WpB_lo, wv_ws);
}

// ---------------- embedding + h_c (direct to hB planes) + attn scalars ----------------
template<bool F32>
__device__ __forceinline__ void embed_body(
    const int* op_idx, const void* vf, const void* cs_tab, const void* tp_tab,
    const void* Wc, const void* asrc, const void* adst,
    float* x_out, short* hB_hi, short* hB_lo, float* ed_out, float* es_out){
  int t = threadIdx.x;
  int w = t >> 6, lane = t & 63;
  int g = blockIdx.x * 4 + w;
  int b = g / NN, n = g - b * NN;
  int op = op_idx[g];
  float xv = 0.f, hacc = 0.f;
#pragma unroll
  for (int f = 0; f < 15; ++f){
    float x_f;
    if (f < 4)      x_f = ldf<F32>(cs_tab, n * 4 + f);
    else if (f < 6) x_f = ldf<F32>(tp_tab, op * 2 + (f - 4));
    else            x_f = ldf<F32>(vf, (long)g * 9 + (f - 6));
    if (lane == f) xv = x_f;
    hacc += x_f * ldf<F32>(Wc, f * COMD + lane);
  }
  if (lane < 15) x_out[g * 15 + lane] = xv;
  hB_write(hB_hi, hB_lo, b, n, lane, hacc);
  float sd = wave_sum(hacc * ldf<F32>(adst, lane));
  float ss = wave_sum(hacc * ldf<F32>(asrc, lane));
  if (lane == 0){ ed_out[g] = sd; es_out[g] = ss; }
}
__global__ void __launch_bounds__(256) k_embed(
    const int* flags, const int* op_idx, const void* vf, const void* cs_tab,
    const void* tp_tab, const void* Wc, const void* asrc, const void* adst,
    float* x_out, short* hB_hi, short* hB_lo, float* ed_out, float* es_out){
  if (flags[0]) embed_body<true >(op_idx, vf, cs_tab, tp_tab, Wc, asrc, adst, x_out, hB_hi, hB_lo, ed_out, es_out);
  else          embed_body<false>(op_idx, vf, cs_tab, tp_tab, Wc, asrc, adst, x_out, hB_hi, hB_lo, ed_out, es_out);
}

// ---------------- h_co = [x, comp] @ Wco (direct to hB planes) ----------------
template<bool F32>
__device__ __forceinline__ void hco_body(
    const float* x_ws, const float* comp, const void* Wco,
    const void* asrc, const void* adst,
    short* hB_hi, short* hB_lo, float* ed_out, float* es_out){
  __shared__ float cx[4][80] __attribute__((aligned(16)));
  int t = threadIdx.x;
  int w = t >> 6, lane = t & 63;
  int base = blockIdx.x * 4;
  for (int idx = t; idx < 4 * 79; idx += 256){
    int nl = idx / 79, f = idx - nl * 79;
    int g = base + nl;
    cx[nl][f] = (f < 15) ? x_ws[g * 15 + f] : comp[(long)g * COMD + (f - 15)];
  }
  __syncthreads();
  int g = base + w;
  int b = g / NN, n = g - b * NN;
  float hacc = 0.f;
#pragma unroll
  for (int f4 = 0; f4 < 76; f4 += 4){
    float4 sv = *(const float4*)&cx[w][f4];
    float w0 = ldf<F32>(Wco, (f4 + 0) * COMD + lane);
    float w1 = ldf<F32>(Wco, (f4 + 1) * COMD + lane);
    float w2 = ldf<F32>(Wco, (f4 + 2) * COMD + lane);
    float w3 = ldf<F32>(Wco, (f4 + 3) * COMD + lane);
    hacc += sv.x * w0 + sv.y * w1 + sv.z * w2 + sv.w * w3;
  }
#pragma unroll
  for (int f = 76; f < 79; ++f)
    hacc += cx[w][f] * ldf<F32>(Wco, f * COMD + lane);
  hB_write(hB_hi, hB_lo, b, n, lane, hacc);
  float sd = wave_sum(hacc * ldf<F32>(adst, lane));
  float ss = wave_sum(hacc * ldf<F32>(asrc, lane));
  if (lane == 0){ ed_out[g] = sd; es_out[g] = ss; }
}
__global__ void __launch_bounds__(256) k_hco(
    const int* flags, const float* x_ws, const float* comp, const void* Wco,
    const void* asrc, const void* adst,
    short* hB_hi, short* hB_lo, float* ed_out, float* es_out){
  if (flags[0]) hco_body<true >(x_ws, comp, Wco, asrc, adst, hB_hi, hB_lo, ed_out, es_out);
  else          hco_body<false>(x_ws, comp, Wco, asrc, adst, hB_hi, hB_lo, ed_out, es_out);
}

// ---------------- masked-softmax GAT: online softmax + dbuf MFMA ----------------
__global__ void __launch_bounds__(256) k_gat(
    const float* __restrict__ ed, const float* __restrict__ es,
    const float* __restrict__ wd_ws, int wd_idx, const u64* __restrict__ adjQ,
    const bf16* __restrict__ distTb,
    const short* __restrict__ hB_hi, const short* __restrict__ hB_lo,
    float* __restrict__ reps){
  __shared__ short pA_hi[2][4096] __attribute__((aligned(16)));
  __shared__ short pA_lo[2][4096] __attribute__((aligned(16)));
  __shared__ float redm[TI][4], redz[TI][4];
  int t = threadIdx.x;
  int wv = t >> 6, lane = t & 63;
  int b = blockIdx.y;
  int i0 = blockIdx.x * TI;
  float wd = wd_ws[wd_idx];
  int sb = i0 & 63;
  const u64* adjQb = adjQ + ((long)b * 16 + (i0 >> 6)) * 1024;

  float ed_i[TI];
#pragma unroll
  for (int ti = 0; ti < TI; ++ti)
    ed_i[ti] = (i0 + ti < NN) ? ed[b * NN + i0 + ti] : 0.f;

  float p[TI][4], m_l[TI];
#pragma unroll
  for (int ti = 0; ti < TI; ++ti) m_l[ti] = -INFINITY;
#pragma unroll
  for (int c = 0; c < 4; ++c){
    int j = c * 256 + wv * 64 + lane;
    int jc = (j < NN) ? j : (NN - 1);
    float esj = es[b * NN + jc];
    u64 word = adjQb[j] >> sb;
#pragma unroll
    for (int ti = 0; ti < TI; ++ti){
      int ic = (i0 + ti < NN) ? (i0 + ti) : (NN - 1);
      bool edge = (word >> ti) & 1ull;
      float d = b2f(distTb[(long)ic * NN + jc]);
      float v = ed_i[ti] + esj + wd * d;
      v = fmaxf(v, 0.2f * v);
      float e = edge ? v : -INFINITY;
      p[ti][c] = e;
      m_l[ti] = fmaxf(m_l[ti], e);
    }
  }
  float z_l[TI];
#pragma unroll
  for (int ti = 0; ti < TI; ++ti){
    float m = wave_bmax(m_l[ti]);
    m_l[ti] = m;
    float zs = 0.f;
#pragma unroll
    for (int c = 0; c < 4; ++c){
      float e = p[ti][c];
      float pp = (e > -INFINITY) ? __expf(e - m) : 0.f;
      p[ti][c] = pp;
      zs += pp;
    }
    z_l[ti] = wave_bsum(zs);
  }
  if (lane == 0){
#pragma unroll
    for (int ti = 0; ti < TI; ++ti){ redm[ti][wv] = m_l[ti]; redz[ti][wv] = z_l[ti]; }
  }
  __syncthreads();
  float s[TI];
#pragma unroll
  for (int ti = 0; ti < TI; ++ti){
    float m0 = redm[ti][0], m1 = redm[ti][1], m2 = redm[ti][2], m3 = redm[ti][3];
    float mi = fmaxf(fmaxf(m0, m1), fmaxf(m2, m3));
    float zi = 0.f;
    if (mi > -INFINITY){
      zi = ((m0 > -INFINITY) ? redz[ti][0] * __expf(m0 - mi) : 0.f)
         + ((m1 > -INFINITY) ? redz[ti][1] * __expf(m1 - mi) : 0.f)
         + ((m2 > -INFINITY) ? redz[ti][2] * __expf(m2 - mi) : 0.f)
         + ((m3 > -INFINITY) ? redz[ti][3] * __expf(m3 - mi) : 0.f);
    }
    s[ti] = (zi > 0.f && m_l[ti] > -INFINITY) ? __expf(m_l[ti] - mi) / zi : 0.f;
  }

  int wg = (lane >> 3) & 3, wu = lane & 7;
  int kbW = wv * 2 + (lane >> 5);
  int Ag = lane >> 4, Am = lane & 15;
  long hBbase = (long)b * 65536;
  f32x4 acc = {0.f, 0.f, 0.f, 0.f};

  auto stage = [&](int c, int buf){
    int widx = kbW * 512 + wg * 128 + wu;
#pragma unroll
    for (int ti = 0; ti < TI; ++ti){
      float a = p[ti][c] * s[ti];
      short hi, lo; split_bf(a, hi, lo);
      pA_hi[buf][widx + ti * 8] = hi;
      pA_lo[buf][widx + ti * 8] = lo;
    }
  };

  stage(0, 0);
#pragma unroll
  for (int c = 0; c < 4; ++c){
    __syncthreads();
    if (c < 3) stage(c + 1, (c + 1) & 1);
    int buf = c & 1;
#pragma unroll
    for (int kbL = 0; kbL < 8; ++kbL){
      int kb = c * 8 + kbL;
      int aidx = kbL * 512 + Ag * 128 + Am * 8;
      s16x8 a_hi = *(const s16x8*)&pA_hi[buf][aidx];
      s16x8 a_lo = *(const s16x8*)&pA_lo[buf][aidx];
      long bidx = hBbase + (((long)kb * 4 + Ag) * 64 + wv * 16 + Am) * 8;
      s16x8 b_hi = *(const s16x8*)&hB_hi[bidx];
      s16x8 b_lo = *(const s16x8*)&hB_lo[bidx];
      acc = __builtin_amdgcn_mfma_f32_16x16x32_bf16(a_hi, b_hi, acc, 0, 0, 0);
      acc = __builtin_amdgcn_mfma_f32_16x16x32_bf16(a_hi, b_lo, acc, 0, 0, 0);
      acc = __builtin_amdgcn_mfma_f32_16x16x32_bf16(a_lo, b_hi, acc, 0, 0, 0);
    }
  }
#pragma unroll
  for (int reg = 0; reg < 4; ++reg){
    int ti = (lane >> 4) * 4 + reg;
    int ch = wv * 16 + (lane & 15);
    float v = acc[reg];
    v = (v > 0.f) ? v : expm1f(v);
    if (i0 + ti < NN)
      reps[((long)b * NN + i0 + ti) * COMD + ch] = v;
  }
}

// ---------------- x_p = sag@Wp + bp via MFMA; exact-ish fused scores ----------------
// 16 nodes/block (tile may span batch boundary; all per-node indexing is flat g).
template<bool F32>
__device__ __forceinline__ void xp_body(
    const int* time_idx, const int* op_idx, const void* vf, const void* time_tab,
    const void* cs_tab, const void* tp_tab, const float* comp, const float* coop,
    const short* __restrict__ WpB_hi, const short* __restrict__ WpB_lo,
    const float* __restrict__ wv_ws, const void* bp,
    float* x_p, float* scf, float* scd){
  __shared__ float sagF[16][148] __attribute__((aligned(16)));
  __shared__ short sagA_hi[5 * 16 * 40] __attribute__((aligned(16)));  // 40-short row pitch
  __shared__ short sagA_lo[5 * 16 * 40] __attribute__((aligned(16)));
  int t = threadIdx.x;
  int wv = t >> 6, lane = t & 63;
  int base = blockIdx.x * 16;

  // 1) gather sag (f32)
  for (int idx = t; idx < 16 * 147; idx += 256){
    int nl = idx / 147, f = idx - nl * 147;
    int g = base + nl;
    int n = g % NN;
    float v;
    if (f < 4)       v = ldf<F32>(time_tab, time_idx[g] * 4 + f);
    else if (f < 8)  v = ldf<F32>(cs_tab, n * 4 + (f - 4));
    else if (f < 10) v = ldf<F32>(tp_tab, op_idx[g] * 2 + (f - 8));
    else if (f < 19) v = ldf<F32>(vf, (long)g * 9 + (f - 10));
    else if (f < 83) v = comp[(long)g * COMD + (f - 19)];
    else             v = coop[(long)g * COMD + (f - 83)];
    sagF[nl][f] = v;
  }
  __syncthreads();

  // 2a) A-fragment split (K padded to 160)
  for (int idx = t; idx < 16 * 160; idx += 256){
    int m = idx / 160, k = idx - m * 160;
    float v = (k < 147) ? sagF[m][k] : 0.f;
    int kb = k >> 5, q = (k >> 3) & 3, u = k & 7;
    short hi, lo; split_bf(v, hi, lo);
    int off = (kb * 16 + m) * 40 + q * 8 + u;
    sagA_hi[off] = hi; sagA_lo[off] = lo;
  }
  // 2b) fused scores: score = sagF . (Wp@v) + bp.v   (f32, independent of MFMA precision)
  {
    int node = t >> 4, sub = t & 15;
    float ad = 0.f, af = 0.f;
    for (int f = sub; f < 147; f += 16){
      float s = sagF[node][f];
      ad += s * wv_ws[f];
      af += s * wv_ws[160 + f];
    }
#pragma unroll
    for (int o = 8; o > 0; o >>= 1){
      ad += __shfl_xor(ad, o, 64);
      af += __shfl_xor(af, o, 64);
    }
    if (sub == 0){
      scd[base + node] = ad + wv_ws[320];
      scf[base + node] = af + wv_ws[321];
    }
  }
  __syncthreads();

  // 3) MFMA: 5 kb x 4 col-tiles x 3 (hi/lo)
  int Ag = lane >> 4, Am = lane & 15;
  f32x4 acc[4] = {{0,0,0,0},{0,0,0,0},{0,0,0,0},{0,0,0,0}};
#pragma unroll
  for (int kb = 0; kb < 5; ++kb){
    int aoff = (kb * 16 + Am) * 40 + Ag * 8;
    s16x8 a_hi = *(const s16x8*)&sagA_hi[aoff];
    s16x8 a_lo = *(const s16x8*)&sagA_lo[aoff];
#pragma unroll
    for (int ct = 0; ct < 4; ++ct){
      int ch = wv * 64 + ct * 16 + Am;
      long boff = (((long)(kb * 4 + Ag)) * 256 + ch) * 8;
      s16x8 b_hi = *(const s16x8*)&WpB_hi[boff];
      s16x8 b_lo = *(const s16x8*)&WpB_lo[boff];
      acc[ct] = __builtin_amdgcn_mfma_f32_16x16x32_bf16(a_hi, b_hi, acc[ct], 0, 0, 0);
      acc[ct] = __builtin_amdgcn_mfma_f32_16x16x32_bf16(a_hi, b_lo, acc[ct], 0, 0, 0);
      acc[ct] = __builtin_amdgcn_mfma_f32_16x16x32_bf16(a_lo, b_hi, acc[ct], 0, 0, 0);
    }
  }
  // 4) epilogue: + bias, write x_p (C layout: row=(lane>>4)*4+reg, col=lane&15)
#pragma unroll
  for (int ct = 0; ct < 4; ++ct){
    int ch = wv * 64 + ct * 16 + (lane & 15);
    float bb = ldf<F32>(bp, ch);
#pragma unroll
    for (int reg = 0; reg < 4; ++reg){
      int row = (lane >> 4) * 4 + reg;
      x_p[(long)(base + row) * HIDD + ch] = acc[ct][reg] + bb;
    }
  }
}
__global__ void __launch_bounds__(256) k_xp(
    const int* flags, const int* time_idx, const int* op_idx, const void* vf,
    const void* time_tab, const void* cs_tab, const void* tp_tab,
    const float* comp, const float* coop,
    const short* WpB_hi, const short* WpB_lo, const float* wv_ws, const void* bp,
    float* x_p, float* scf, float* scd){
  if (flags[0]) xp_body<true >(time_idx, op_idx, vf, time_tab, cs_tab, tp_tab, comp, coop, WpB_hi, WpB_lo, wv_ws, bp, x_p, scf, scd);
  else          xp_body<false>(time_idx, op_idx, vf, time_tab, cs_tab, tp_tab, comp, coop, WpB_hi, WpB_lo, wv_ws, bp, x_p, scf, scd);
}

// ---------------- top-k weights: one wave per (b,pool), zero barriers ----------------
template<bool BINT>
__device__ __forceinline__ void topk_body(
    const float* scf, const float* scd, const void* mark, float* wls){
  int lane = threadIdx.x;
  int b = blockIdx.x, pool = blockIdx.y;
  const float* sc = (pool == 0) ? scf : scd;
  float v[16]; unsigned key[16];
  float m0 = -INFINITY;
#pragma unroll
  for (int r = 0; r < 16; ++r){
    int n = r * 64 + lane;
    float s = (n < NN) ? sc[b * NN + n] : -INFINITY;
    v[r] = s;
    m0 = fmaxf(m0, s);
  }
  m0 = wave_bmax(m0);
  float m1 = -INFINITY;
#pragma unroll
  for (int r = 0; r < 16; ++r){
    int n = r * 64 + lane;
    bool valid = false;
    if (n < NN){
      bool mk = ldb<BINT>(mark, b * NN + n);
      valid = (pool == 0) ? !mk : mk;
    }
    v[r] = valid ? (v[r] - m0) : -1e8f;
    key[r] = fkey(v[r]);
    if (n < NN) m1 = fmaxf(m1, v[r]);
  }
  m1 = wave_bmax(m1);

  unsigned lo = 0u, hi = 0xFFFFFFFFu;
  while (lo < hi){
    unsigned mid = lo + ((hi - lo) >> 1) + 1u;
    int c = 0;
#pragma unroll
    for (int r = 0; r < 16; ++r) c += (key[r] >= mid) ? 1 : 0;
    c = wave_bsum_i(c);
    if (c >= KSEL) lo = mid; else hi = mid - 1u;
  }

  float p[16];
  float ls = 0.f;
#pragma unroll
  for (int r = 0; r < 16; ++r){
    int n = r * 64 + lane;
    float pp = (n < NN && key[r] >= lo) ? __expf(v[r] - m1) : 0.f;
    p[r] = pp;
    ls += pp;
  }
  ls = wave_bsum(ls);
  float zinv = (ls > 0.f) ? 1.f / ls : 0.f;
  float* w_out = wls + ((long)b * 2 + pool) * 1024;
#pragma unroll
  for (int r = 0; r < 16; ++r){
    int n = r * 64 + lane;
    if (n < NN) w_out[n] = p[r] * zinv;
  }
}
__global__ void k_topk(const int* flags, const float* scf, const float* scd,
                       const void* mark, float* wls){
  if (flags[1]) topk_body<true >(scf, scd, mark, wls);
  else          topk_body<false>(scf, scd, mark, wls);
}

// ---------------- gated partial sums: x_p streamed ONCE for both pools ----------------
__global__ void __launch_bounds__(256) k_psum(
    const float* __restrict__ wls, const float* __restrict__ x_p,
    float* __restrict__ part){
  __shared__ float wf[ROWS], wdd[ROWS];
  int t = threadIdx.x;
  int b = blockIdx.x, z = blockIdx.y;
  int n0 = z * ROWS;
  int ns = min(ROWS, NN - n0);
  if (t < ns){
    wf[t]  = wls[((long)b * 2 + 0) * 1024 + n0 + t];
    wdd[t] = wls[((long)b * 2 + 1) * 1024 + n0 + t];
  }
  __syncthreads();
  float sf = 0.f, mf = -INFINITY, sd = 0.f, md = -INFINITY;
  const float* xb = x_p + ((long)b * NN + n0) * HIDD + t;
  for (int k = 0; k < ns; ++k){
    float xv = xb[(long)k * HIDD];
    float gf = wf[k] * xv;
    float gd = wdd[k] * xv;
    sf += gf; mf = fmaxf(mf, gf);
    sd += gd; md = fmaxf(md, gd);
  }
  long pb = (((long)b * NSPL + z) * 4) * HIDD + t;
  part[pb + 0 * HIDD] = sf;
  part[pb + 1 * HIDD] = mf;
  part[pb + 2 * HIDD] = sd;
  part[pb + 3 * HIDD] = md;
}

// ---------------- final reduce over z-partials ----------------
template<bool F32>
__device__ __forceinline__ void pfin_body(const float* part, void* out){
  int t = threadIdx.x;
  int b = blockIdx.x;
  float sf = 0.f, mf = -INFINITY, sd = 0.f, md = -INFINITY;
#pragma unroll
  for (int z = 0; z < NSPL; ++z){
    long pb = (((long)b * NSPL + z) * 4) * HIDD + t;
    sf += part[pb + 0 * HIDD];
    mf = fmaxf(mf, part[pb + 1 * HIDD]);
    sd += part[pb + 2 * HIDD];
    md = fmaxf(md, part[pb + 3 * HIDD]);
  }
  long ob = (long)b * 1024;
  if (F32){
    ((float*)out)[ob + t] = sf;
    ((float*)out)[ob + 256 + t] = mf;
    ((float*)out)[ob + 512 + t] = sd;
    ((float*)out)[ob + 768 + t] = md;
  } else {
    ((bf16*)out)[ob + t] = __float2bfloat16(sf);
    ((bf16*)out)[ob + 256 + t] = __float2bfloat16(mf);
    ((bf16*)out)[ob + 512 + t] = __float2bfloat16(sd);
    ((bf16*)out)[ob + 768 + t] = __float2bfloat16(md);
  }
}
__global__ void k_pfin(const int* flags, const float* part, void* out){
  if (flags[0]) pfin_body<true >(part, out);
  else          pfin_body<false>(part, out);
}

extern "C" void kernel_launch(void* const* d_in, const int* in_sizes, int n_in,
                              void* d_out, int out_size, void* d_ws, size_t ws_size,
                              hipStream_t stream){
  const int*  time_idx = (const int*)d_in[0];
  const int*  op_idx   = (const int*)d_in[1];
  const void* vfeat    = d_in[2];
  const void* dpcs     = d_in[3];
  const void* adj_comp = d_in[4];
  const void* adj_coop = d_in[5];
  const void* dist     = d_in[6];
  const void* time_tab = d_in[7];
  const void* tp_tab   = d_in[8];
  const void* cs_tab   = d_in[9];
  const void* Wc       = d_in[10];
  const void* asrc_c   = d_in[11];
  const void* adst_c   = d_in[12];
  const void* wd_c     = d_in[13];
  const void* Wco      = d_in[14];
  const void* asrc_co  = d_in[15];
  const void* adst_co  = d_in[16];
  const void* wd_co    = d_in[17];
  const void* Wp       = d_in[18];
  const void* bp       = d_in[19];
  const void* vpd      = d_in[20];
  const void* vpf      = d_in[21];

  char* ws = (char*)d_ws;
  size_t o = 0;
  auto alloc = [&](size_t bytes)->char*{
    char* p = ws + o; o = (o + bytes + 255) & ~(size_t)255; return p;
  };
  int*   flags  = (int*)alloc(16);
  float* wd_ws  = (float*)alloc(8);
  bf16*  distTb = (bf16*)alloc((size_t)NN * NN * 2);
  u64*   adjQc  = (u64*)alloc((size_t)NB * 16 * 1024 * 8);
  u64*   adjQo  = (u64*)alloc((size_t)NB * 16 * 1024 * 8);
  float* x_ws   = (float*)alloc((size_t)NB * NN * 15 * 4);
  float* comp   = (float*)alloc((size_t)NB * NN * COMD * 4);
  float* coop   = (float*)alloc((size_t)NB * NN * COMD * 4);
  short* hB_hi  = (short*)alloc((size_t)NB * 65536 * 2);
  short* hB_lo  = (short*)alloc((size_t)NB * 65536 * 2);
  short* WpB_hi = (short*)alloc((size_t)5 * 4 * 256 * 8 * 2);
  short* WpB_lo = (short*)alloc((size_t)5 * 4 * 256 * 8 * 2);
  float* wv_ws  = (float*)alloc(322 * 4);
  float* ed_c   = (float*)alloc((size_t)NB * NN * 4);
  float* es_c   = (float*)alloc((size_t)NB * NN * 4);
  float* ed_o   = (float*)alloc((size_t)NB * NN * 4);
  float* es_o   = (float*)alloc((size_t)NB * NN * 4);
  float* scf    = (float*)alloc((size_t)NB * NN * 4);
  float* scd    = (float*)alloc((size_t)NB * NN * 4);
  float* wls    = (float*)alloc((size_t)NB * 2 * 1024 * 4);
  float* part   = (float*)alloc((size_t)NB * NSPL * 4 * HIDD * 4);
  float* x_p    = (float*)alloc((size_t)NB * NN * HIDD * 4);

  k_sniff<<<1, 64, 0, stream>>>(dist, adj_comp, wd_c, wd_co, flags, wd_ws);
  k_wprep<<<dim3(161), dim3(64), 0, stream>>>(flags, Wp, vpd, vpf, bp, WpB_hi, WpB_lo, wv_ws);
  k_dist_t<<<dim3(16, 16), dim3(256), 0, stream>>>(flags, dist, distTb);
  dim3 qg(16, 16, NB);
  k_adjq<<<qg, dim3(256), 0, stream>>>(flags, adj_comp, adjQc);
  k_adjq<<<qg, dim3(256), 0, stream>>>(flags, adj_coop, adjQo);
  k_embed<<<dim3(NB * NN / 4), dim3(256), 0, stream>>>(
      flags, op_idx, vfeat, cs_tab, tp_tab, Wc, asrc_c, adst_c,
      x_ws, hB_hi, hB_lo, ed_c, es_c);
  k_gat<<<dim3((NN + TI - 1) / TI, NB), dim3(256), 0, stream>>>(
      ed_c, es_c, wd_ws, 0, adjQc, distTb, hB_hi, hB_lo, comp);
  k_hco<<<dim3(NB * NN / 4), dim3(256), 0, stream>>>(
      flags, x_ws, comp, Wco, asrc_co, adst_co, hB_hi, hB_lo, ed_o, es_o);
  k_gat<<<dim3((NN + TI - 1) / TI, NB), dim3(256), 0, stream>>>(
      ed_o, es_o, wd_ws, 1, adjQo, distTb, hB_hi, hB_lo, coop);
  k_xp<<<dim3(NB * NN / 16), dim3(256), 0, stream>>>(
      flags, time_idx, op_idx, vfeat, time_tab, cs_tab, tp_tab, comp, coop,
      WpB_hi, WpB_lo, wv_ws, bp, x_p, scf, scd);
  k_topk<<<dim3(NB, 2), dim3(64), 0, stream>>>(flags, scf, scd, dpcs, wls);
  k_psum<<<dim3(NB, NSPL), dim3(256), 0, stream>>>(wls, x_p, part);
  k_pfin<<<dim3(NB), dim3(256), 0, stream>>>(flags, part, d_out);
}

// Round 8
// 545.768 us; speedup vs baseline: 2.5714x; 1.1240x over previous
//
#include <hip/hip_runtime.h>
#include <hip/hip_bf16.h>

#define NB 32
#define NN 1000
#define COMD 64
#define HIDD 256
#define KSEL 500
#define TI 16        // dst rows per k_gat block
#define NSPL 32      // n-splits for k_psum
#define ROWS 32      // ceil(NN/NSPL)
#define DSTRIDE 1024 // padded distT row stride

typedef __hip_bfloat16 bf16;
typedef unsigned long long u64;
typedef __attribute__((ext_vector_type(4))) float f32x4;
typedef __attribute__((ext_vector_type(8))) short s16x8;
typedef __attribute__((ext_vector_type(4))) short s16x4;
typedef __attribute__((ext_vector_type(4))) unsigned short u16x4;
typedef __attribute__((ext_vector_type(2))) unsigned long long u64x2;

__device__ __forceinline__ float b2f(bf16 x){ return __bfloat162float(x); }

template<bool F32>
__device__ __forceinline__ float ldf(const void* p, long i){
  return F32 ? ((const float*)p)[i] : b2f(((const bf16*)p)[i]);
}
template<bool BINT>
__device__ __forceinline__ bool ldb(const void* p, long i){
  return BINT ? (((const int*)p)[i] != 0) : (((const unsigned char*)p)[i] != 0);
}

__device__ __forceinline__ float wave_sum(float v){
#pragma unroll
  for (int o = 32; o > 0; o >>= 1) v += __shfl_down(v, o, 64);
  return v;
}
__device__ __forceinline__ float wave_bsum(float v){
#pragma unroll
  for (int o = 32; o > 0; o >>= 1) v += __shfl_xor(v, o, 64);
  return v;
}
__device__ __forceinline__ float wave_bmax(float v){
#pragma unroll
  for (int o = 32; o > 0; o >>= 1) v = fmaxf(v, __shfl_xor(v, o, 64));
  return v;
}
__device__ __forceinline__ int wave_bsum_i(int v){
#pragma unroll
  for (int o = 32; o > 0; o >>= 1) v += __shfl_xor(v, o, 64);
  return v;
}
__device__ __forceinline__ unsigned fkey(float f){
  unsigned u = __float_as_uint(f);
  return (u & 0x80000000u) ? ~u : (u | 0x80000000u);
}
// split fp32 into bf16 hi + bf16 lo with v ≈ hi + lo (residual ~2^-16 rel)
__device__ __forceinline__ void split_bf(float v, short& hi, short& lo){
  unsigned u = __float_as_uint(v);
  float hf = __uint_as_float(u & 0xFFFF0000u);
  hi = (short)(u >> 16);
  float r = v - hf;                 // exact
  lo = (short)(__float_as_uint(r) >> 16);
}
// fp32 -> bf16 (RNE) as short
__device__ __forceinline__ short f2bs(float v){
  bf16 h = __float2bfloat16(v);
  short s; __builtin_memcpy(&s, &h, 2); return s;
}
// write one h value into the MFMA B-fragment hi/lo planes
__device__ __forceinline__ void hB_write(short* hB_hi, short* hB_lo,
                                         int b, int n, int ch, float v){
  int kb = n >> 5, g4 = (n >> 3) & 3, u = n & 7;
  long off = ((((long)b * 32 + kb) * 4 + g4) * 64 + ch) * 8 + u;
  short hi, lo; split_bf(v, hi, lo);
  hB_hi[off] = hi; hB_lo[off] = lo;
}

// ---------------- dtype sniffing ----------------
__global__ void k_sniff(const void* dist, const void* adjc,
                        const void* wdc, const void* wdco,
                        int* flags, float* wd_out){
  if (blockIdx.x != 0 || threadIdx.x != 0) return;
  const unsigned* w = (const unsigned*)dist;
  int f32 = 0;
  for (int k = 0; k < 64; ++k) if ((w[k] & 0xFFFFu) >= 0x8000u){ f32 = 1; break; }
  const unsigned* bw = (const unsigned*)adjc;
  int as_int = 1;
  for (int k = 0; k < 64; ++k) if (bw[k] > 1u){ as_int = 0; break; }
  flags[0] = f32; flags[1] = as_int;
  wd_out[0] = f32 ? ((const float*)wdc)[0]  : b2f(((const bf16*)wdc)[0]);
  wd_out[1] = f32 ? ((const float*)wdco)[0] : b2f(((const bf16*)wdco)[0]);
}

// ---------------- distance transpose (tiled, bf16 out, padded stride) ----------------
template<bool F32>
__device__ __forceinline__ void dist_t_body(const void* dist, bf16* distTb){
  __shared__ bf16 tile[64][68];
  int t = threadIdx.x;
  int wv = t >> 6, lane = t & 63;
  int it = blockIdx.x * 64, jt = blockIdx.y * 64;
#pragma unroll
  for (int r = 0; r < 16; ++r){
    int jl = r * 4 + wv;
    int j = jt + jl, i = it + lane;
    float v = (j < NN && i < NN) ? ldf<F32>(dist, (long)j * NN + i) : 0.f;
    tile[jl][lane] = __float2bfloat16(v);
  }
  __syncthreads();
#pragma unroll
  for (int r = 0; r < 16; ++r){
    int il = r * 4 + wv;
    int i = it + il, j = jt + lane;
    if (i < NN) distTb[(long)i * DSTRIDE + j] = tile[lane][il];
  }
}
__global__ void k_dist_t(const int* flags, const void* dist, bf16* distTb){
  if (flags[0]) dist_t_body<true>(dist, distTb);
  else          dist_t_body<false>(dist, distTb);
}

// ---------------- adjacency pack via ballot ----------------
// adjQ[b][iw][j] bit il = adj[b][j][iw*64+il]
template<bool BINT>
__device__ __forceinline__ void adjq_body(const void* adj, u64* adjQ){
  int t = threadIdx.x;
  int wv = t >> 6, lane = t & 63;
  int j0 = blockIdx.x * 64;
  int iw = blockIdx.y, b = blockIdx.z;
  long base = (long)b * NN * NN;
  int i = iw * 64 + lane;
  bool iok = i < NN;
#pragma unroll
  for (int r = 0; r < 16; ++r){
    int j = j0 + wv * 16 + r;
    bool pred = (iok && j < NN) ? ldb<BINT>(adj, base + (long)j * NN + i) : false;
    u64 word = __ballot(pred);
    if (lane == 0) adjQ[((long)b * 16 + iw) * 1024 + j] = word;
  }
}
__global__ void k_adjq(const int* flags, const void* adj, u64* adjQ){
  if (flags[1]) adjq_body<true>(adj, adjQ);
  else          adjq_body<false>(adj, adjQ);
}

// ---------------- Wp -> B-frag planes (K padded to 160) + projected score vecs ----------------
template<bool F32>
__device__ __forceinline__ void wprep_body(
    const void* Wp, const void* vpd, const void* vpf, const void* bp,
    short* WpB_hi, short* WpB_lo, float* wv_ws){
  int f = blockIdx.x;
  int lane = threadIdx.x;            // 64 threads
  if (f < 160){
    float wrow[4];
#pragma unroll
    for (int r = 0; r < 4; ++r){
      int ch = r * 64 + lane;
      wrow[r] = (f < 147) ? ldf<F32>(Wp, (long)f * HIDD + ch) : 0.f;
    }
    int kb = f >> 5, q = (f >> 3) & 3, u = f & 7;
#pragma unroll
    for (int r = 0; r < 4; ++r){
      int ch = r * 64 + lane;
      long off = (((long)(kb * 4 + q)) * 256 + ch) * 8 + u;
      short hi, lo; split_bf(wrow[r], hi, lo);
      WpB_hi[off] = hi; WpB_lo[off] = lo;
    }
    float ad = 0.f, af = 0.f;
#pragma unroll
    for (int r = 0; r < 4; ++r){
      int ch = r * 64 + lane;
      ad += wrow[r] * ldf<F32>(vpd, ch);
      af += wrow[r] * ldf<F32>(vpf, ch);
    }
    ad = wave_bsum(ad); af = wave_bsum(af);
    if (lane == 0){ wv_ws[f] = ad; wv_ws[160 + f] = af; }
  } else {
    float ad = 0.f, af = 0.f;
#pragma unroll
    for (int r = 0; r < 4; ++r){
      int ch = r * 64 + lane;
      float bb = ldf<F32>(bp, ch);
      ad += bb * ldf<F32>(vpd, ch);
      af += bb * ldf<F32>(vpf, ch);
    }
    ad = wave_bsum(ad); af = wave_bsum(af);
    if (lane == 0){ wv_ws[320] = ad; wv_ws[321] = af; }
  }
}
__global__ void k_wprep(const int* flags, const void* Wp, const void* vpd,
                        const void* vpf, const void* bp,
                        short* WpB_hi, short* WpB_lo, float* wv_ws){
  if (flags[0]) wprep_body<true >(Wp, vpd, vpf, bp, WpB_hi, WpB_lo, wv_ws);
  else          wprep_body<false>(Wp, vpd, vpf, bp, WpB_hi, WpB_lo, wv_ws);
}

// ---------------- embedding + h_c (direct to hB planes) + attn scalars ----------------
template<bool F32>
__device__ __forceinline__ void embed_body(
    const int* op_idx, const void* vf, const void* cs_tab, const void* tp_tab,
    const void* Wc, const void* asrc, const void* adst,
    float* x_out, short* hB_hi, short* hB_lo, float* ed_out, float* es_out){
  int t = threadIdx.x;
  int w = t >> 6, lane = t & 63;
  int g = blockIdx.x * 4 + w;
  int b = g / NN, n = g - b * NN;
  int op = op_idx[g];
  float xv = 0.f, hacc = 0.f;
#pragma unroll
  for (int f = 0; f < 15; ++f){
    float x_f;
    if (f < 4)      x_f = ldf<F32>(cs_tab, n * 4 + f);
    else if (f < 6) x_f = ldf<F32>(tp_tab, op * 2 + (f - 4));
    else            x_f = ldf<F32>(vf, (long)g * 9 + (f - 6));
    if (lane == f) xv = x_f;
    hacc += x_f * ldf<F32>(Wc, f * COMD + lane);
  }
  if (lane < 15) x_out[g * 15 + lane] = xv;
  hB_write(hB_hi, hB_lo, b, n, lane, hacc);
  float sd = wave_sum(hacc * ldf<F32>(adst, lane));
  float ss = wave_sum(hacc * ldf<F32>(asrc, lane));
  if (lane == 0){ ed_out[g] = sd; es_out[g] = ss; }
}
__global__ void __launch_bounds__(256) k_embed(
    const int* flags, const int* op_idx, const void* vf, const void* cs_tab,
    const void* tp_tab, const void* Wc, const void* asrc, const void* adst,
    float* x_out, short* hB_hi, short* hB_lo, float* ed_out, float* es_out){
  if (flags[0]) embed_body<true >(op_idx, vf, cs_tab, tp_tab, Wc, asrc, adst, x_out, hB_hi, hB_lo, ed_out, es_out);
  else          embed_body<false>(op_idx, vf, cs_tab, tp_tab, Wc, asrc, adst, x_out, hB_hi, hB_lo, ed_out, es_out);
}

// ---------------- h_co = [x, comp] @ Wco (direct to hB planes) ----------------
template<bool F32>
__device__ __forceinline__ void hco_body(
    const float* x_ws, const float* comp, const void* Wco,
    const void* asrc, const void* adst,
    short* hB_hi, short* hB_lo, float* ed_out, float* es_out){
  __shared__ float cx[4][80] __attribute__((aligned(16)));
  int t = threadIdx.x;
  int w = t >> 6, lane = t & 63;
  int base = blockIdx.x * 4;
  for (int idx = t; idx < 4 * 79; idx += 256){
    int nl = idx / 79, f = idx - nl * 79;
    int g = base + nl;
    cx[nl][f] = (f < 15) ? x_ws[g * 15 + f] : comp[(long)g * COMD + (f - 15)];
  }
  __syncthreads();
  int g = base + w;
  int b = g / NN, n = g - b * NN;
  float hacc = 0.f;
#pragma unroll
  for (int f4 = 0; f4 < 76; f4 += 4){
    float4 sv = *(const float4*)&cx[w][f4];
    float w0 = ldf<F32>(Wco, (f4 + 0) * COMD + lane);
    float w1 = ldf<F32>(Wco, (f4 + 1) * COMD + lane);
    float w2 = ldf<F32>(Wco, (f4 + 2) * COMD + lane);
    float w3 = ldf<F32>(Wco, (f4 + 3) * COMD + lane);
    hacc += sv.x * w0 + sv.y * w1 + sv.z * w2 + sv.w * w3;
  }
#pragma unroll
  for (int f = 76; f < 79; ++f)
    hacc += cx[w][f] * ldf<F32>(Wco, f * COMD + lane);
  hB_write(hB_hi, hB_lo, b, n, lane, hacc);
  float sd = wave_sum(hacc * ldf<F32>(adst, lane));
  float ss = wave_sum(hacc * ldf<F32>(asrc, lane));
  if (lane == 0){ ed_out[g] = sd; es_out[g] = ss; }
}
__global__ void __launch_bounds__(256) k_hco(
    const int* flags, const float* x_ws, const float* comp, const void* Wco,
    const void* asrc, const void* adst,
    short* hB_hi, short* hB_lo, float* ed_out, float* es_out){
  if (flags[0]) hco_body<true >(x_ws, comp, Wco, asrc, adst, hB_hi, hB_lo, ed_out, es_out);
  else          hco_body<false>(x_ws, comp, Wco, asrc, adst, hB_hi, hB_lo, ed_out, es_out);
}

// ---------------- masked-softmax GAT v3 ----------------
// lane owns j in {4t..4t+3}; analytic block-uniform M (exact: softmax is
// shift-invariant per row); alpha staged bf16-hi only into padded LDS
// (quad-stride 136, kb-stride 544 shorts -> banks spread); z folded in
// epilogue. 2 barriers total.
__global__ void __launch_bounds__(256) k_gat(
    const float* __restrict__ ed, const float* __restrict__ es,
    const float* __restrict__ wd_ws, int wd_idx, const u64* __restrict__ adjQ,
    const bf16* __restrict__ distTb,
    const short* __restrict__ hB_hi, const short* __restrict__ hB_lo,
    float* __restrict__ reps){
  __shared__ short pA[32 * 544] __attribute__((aligned(16)));
  __shared__ float redz[TI][4];
  __shared__ float esred[4];
  int t = threadIdx.x;
  int wv = t >> 6, lane = t & 63;
  int b = blockIdx.y;
  int i0 = blockIdx.x * TI;
  float wd = wd_ws[wd_idx];
  int iw = i0 >> 6, sb = i0 & 63;
  int j0 = t * 4;

  // adjacency words for my 4 j's
  const u64* aq = adjQ + ((long)b * 16 + iw) * 1024 + j0;
  u64x2 wA = *(const u64x2*)&aq[0];
  u64x2 wB = *(const u64x2*)&aq[2];
  unsigned wsh[4] = { (unsigned)(wA[0] >> sb), (unsigned)(wA[1] >> sb),
                      (unsigned)(wB[0] >> sb), (unsigned)(wB[1] >> sb) };
  // es for my 4 j's (slack-padded allocation makes the overread safe)
  float4 es4 = *(const float4*)&es[(long)b * NN + j0];
  float esv[4] = {es4.x, es4.y, es4.z, es4.w};
  float esm = -1e30f;
#pragma unroll
  for (int c = 0; c < 4; ++c)
    esm = fmaxf(esm, (j0 + c < NN) ? esv[c] : -1e30f);
  esm = wave_bmax(esm);
  if (lane == 0) esred[wv] = esm;

  // ed for the 16 dst rows (wave-uniform -> scalar path)
  float ed_i[TI]; float edm = -1e30f;
#pragma unroll
  for (int ti = 0; ti < TI; ++ti){
    int i = i0 + ti;
    float ev = ed[(long)b * NN + ((i < NN) ? i : (NN - 1))];
    ed_i[ti] = ev;
    edm = fmaxf(edm, (i < NN) ? ev : -1e30f);
  }
  __syncthreads();
  float M = fmaxf(fmaxf(esred[0], esred[1]), fmaxf(esred[2], esred[3]))
            + edm + fmaxf(wd, 0.f);
  M = fmaxf(M, 0.f);   // M >= every edge score; softmax exact for any uniform M

  // scores -> exp(e - M) (masked lanes underflow to exactly 0)
  float p[TI][4];
  const bf16* dbase = distTb + j0;
#pragma unroll
  for (int ti = 0; ti < TI; ++ti){
    int i = i0 + ti;
    int ic = (i < NN) ? i : (NN - 1);
    u16x4 d4 = *(const u16x4*)&dbase[(long)ic * DSTRIDE];
    float edti = ed_i[ti];
#pragma unroll
    for (int c = 0; c < 4; ++c){
      float d = __uint_as_float((unsigned)d4[c] << 16);
      float v = edti + esv[c] + wd * d;
      v = fmaxf(v, 0.2f * v);                 // leaky_relu
      bool edge = (wsh[c] >> ti) & 1u;
      float e = edge ? v : -1e30f;
      p[ti][c] = __expf(e - M);
    }
  }

  // z partials + staging (one barrier covers both)
  int kbw = 8 * wv + (lane >> 3);
  int qw = (lane >> 1) & 3;
  int u0 = 4 * (lane & 1);
  int wbase = kbw * 544 + qw * 136 + u0;
#pragma unroll
  for (int ti = 0; ti < TI; ++ti){
    float zs = p[ti][0] + p[ti][1] + p[ti][2] + p[ti][3];
    zs = wave_bsum(zs);
    if (lane == 0) redz[ti][wv] = zs;
    s16x4 s4 = { f2bs(p[ti][0]), f2bs(p[ti][1]), f2bs(p[ti][2]), f2bs(p[ti][3]) };
    *(s16x4*)&pA[wbase + ti * 8] = s4;
  }
  __syncthreads();

  // MFMA: D = alpha_unnorm @ (h_hi + h_lo)
  int q = lane >> 4, m = lane & 15;
  int abase = q * 136 + m * 8;
  int ch = wv * 16 + m;
  const short* bh = hB_hi + (long)b * 65536 + ((long)q * 64 + ch) * 8;
  const short* bl = hB_lo + (long)b * 65536 + ((long)q * 64 + ch) * 8;
  f32x4 acc = {0.f, 0.f, 0.f, 0.f};
#pragma unroll
  for (int kb = 0; kb < 32; ++kb){
    s16x8 a   = *(const s16x8*)&pA[kb * 544 + abase];
    s16x8 bhi = *(const s16x8*)&bh[(long)kb * 2048];
    s16x8 blo = *(const s16x8*)&bl[(long)kb * 2048];
    acc = __builtin_amdgcn_mfma_f32_16x16x32_bf16(a, bhi, acc, 0, 0, 0);
    acc = __builtin_amdgcn_mfma_f32_16x16x32_bf16(a, blo, acc, 0, 0, 0);
  }
  // epilogue: normalize by z, elu, store
#pragma unroll
  for (int reg = 0; reg < 4; ++reg){
    int ti = (lane >> 4) * 4 + reg;
    float z = redz[ti][0] + redz[ti][1] + redz[ti][2] + redz[ti][3];
    float zi = (z > 0.f) ? 1.f / z : 0.f;
    float v = acc[reg] * zi;
    v = (v > 0.f) ? v : expm1f(v);
    int ch2 = wv * 16 + (lane & 15);
    if (i0 + ti < NN)
      reps[((long)b * NN + i0 + ti) * COMD + ch2] = v;
  }
}

// ---------------- x_p = sag@Wp + bp via MFMA; f32 fused scores ----------------
template<bool F32>
__device__ __forceinline__ void xp_body(
    const int* time_idx, const int* op_idx, const void* vf, const void* time_tab,
    const void* cs_tab, const void* tp_tab, const float* comp, const float* coop,
    const short* __restrict__ WpB_hi, const short* __restrict__ WpB_lo,
    const float* __restrict__ wv_ws, const void* bp,
    float* x_p, float* scf, float* scd){
  __shared__ float sagF[16][148] __attribute__((aligned(16)));
  __shared__ short sagA_hi[5 * 16 * 40] __attribute__((aligned(16)));
  __shared__ short sagA_lo[5 * 16 * 40] __attribute__((aligned(16)));
  int t = threadIdx.x;
  int wv = t >> 6, lane = t & 63;
  int base = blockIdx.x * 16;

  for (int idx = t; idx < 16 * 147; idx += 256){
    int nl = idx / 147, f = idx - nl * 147;
    int g = base + nl;
    int n = g % NN;
    float v;
    if (f < 4)       v = ldf<F32>(time_tab, time_idx[g] * 4 + f);
    else if (f < 8)  v = ldf<F32>(cs_tab, n * 4 + (f - 4));
    else if (f < 10) v = ldf<F32>(tp_tab, op_idx[g] * 2 + (f - 8));
    else if (f < 19) v = ldf<F32>(vf, (long)g * 9 + (f - 10));
    else if (f < 83) v = comp[(long)g * COMD + (f - 19)];
    else             v = coop[(long)g * COMD + (f - 83)];
    sagF[nl][f] = v;
  }
  __syncthreads();

  for (int idx = t; idx < 16 * 160; idx += 256){
    int m = idx / 160, k = idx - m * 160;
    float v = (k < 147) ? sagF[m][k] : 0.f;
    int kb = k >> 5, q = (k >> 3) & 3, u = k & 7;
    short hi, lo; split_bf(v, hi, lo);
    int off = (kb * 16 + m) * 40 + q * 8 + u;
    sagA_hi[off] = hi; sagA_lo[off] = lo;
  }
  {
    int node = t >> 4, sub = t & 15;
    float ad = 0.f, af = 0.f;
    for (int f = sub; f < 147; f += 16){
      float s = sagF[node][f];
      ad += s * wv_ws[f];
      af += s * wv_ws[160 + f];
    }
#pragma unroll
    for (int o = 8; o > 0; o >>= 1){
      ad += __shfl_xor(ad, o, 64);
      af += __shfl_xor(af, o, 64);
    }
    if (sub == 0){
      scd[base + node] = ad + wv_ws[320];
      scf[base + node] = af + wv_ws[321];
    }
  }
  __syncthreads();

  int Ag = lane >> 4, Am = lane & 15;
  f32x4 acc[4] = {{0,0,0,0},{0,0,0,0},{0,0,0,0},{0,0,0,0}};
#pragma unroll
  for (int kb = 0; kb < 5; ++kb){
    int aoff = (kb * 16 + Am) * 40 + Ag * 8;
    s16x8 a_hi = *(const s16x8*)&sagA_hi[aoff];
    s16x8 a_lo = *(const s16x8*)&sagA_lo[aoff];
#pragma unroll
    for (int ct = 0; ct < 4; ++ct){
      int ch = wv * 64 + ct * 16 + Am;
      long boff = (((long)(kb * 4 + Ag)) * 256 + ch) * 8;
      s16x8 b_hi = *(const s16x8*)&WpB_hi[boff];
      s16x8 b_lo = *(const s16x8*)&WpB_lo[boff];
      acc[ct] = __builtin_amdgcn_mfma_f32_16x16x32_bf16(a_hi, b_hi, acc[ct], 0, 0, 0);
      acc[ct] = __builtin_amdgcn_mfma_f32_16x16x32_bf16(a_hi, b_lo, acc[ct], 0, 0, 0);
      acc[ct] = __builtin_amdgcn_mfma_f32_16x16x32_bf16(a_lo, b_hi, acc[ct], 0, 0, 0);
    }
  }
#pragma unroll
  for (int ct = 0; ct < 4; ++ct){
    int ch = wv * 64 + ct * 16 + (lane & 15);
    float bb = ldf<F32>(bp, ch);
#pragma unroll
    for (int reg = 0; reg < 4; ++reg){
      int row = (lane >> 4) * 4 + reg;
      x_p[(long)(base + row) * HIDD + ch] = acc[ct][reg] + bb;
    }
  }
}
__global__ void __launch_bounds__(256) k_xp(
    const int* flags, const int* time_idx, const int* op_idx, const void* vf,
    const void* time_tab, const void* cs_tab, const void* tp_tab,
    const float* comp, const float* coop,
    const short* WpB_hi, const short* WpB_lo, const float* wv_ws, const void* bp,
    float* x_p, float* scf, float* scd){
  if (flags[0]) xp_body<true >(time_idx, op_idx, vf, time_tab, cs_tab, tp_tab, comp, coop, WpB_hi, WpB_lo, wv_ws, bp, x_p, scf, scd);
  else          xp_body<false>(time_idx, op_idx, vf, time_tab, cs_tab, tp_tab, comp, coop, WpB_hi, WpB_lo, wv_ws, bp, x_p, scf, scd);
}

// ---------------- top-k weights: one wave per (b,pool), zero barriers ----------------
template<bool BINT>
__device__ __forceinline__ void topk_body(
    const float* scf, const float* scd, const void* mark, float* wls){
  int lane = threadIdx.x;
  int b = blockIdx.x, pool = blockIdx.y;
  const float* sc = (pool == 0) ? scf : scd;
  float v[16]; unsigned key[16];
  float m0 = -INFINITY;
#pragma unroll
  for (int r = 0; r < 16; ++r){
    int n = r * 64 + lane;
    float s = (n < NN) ? sc[b * NN + n] : -INFINITY;
    v[r] = s;
    m0 = fmaxf(m0, s);
  }
  m0 = wave_bmax(m0);
  float m1 = -INFINITY;
#pragma unroll
  for (int r = 0; r < 16; ++r){
    int n = r * 64 + lane;
    bool valid = false;
    if (n < NN){
      bool mk = ldb<BINT>(mark, b * NN + n);
      valid = (pool == 0) ? !mk : mk;
    }
    v[r] = valid ? (v[r] - m0) : -1e8f;
    key[r] = fkey(v[r]);
    if (n < NN) m1 = fmaxf(m1, v[r]);
  }
  m1 = wave_bmax(m1);

  unsigned lo = 0u, hi = 0xFFFFFFFFu;
  while (lo < hi){
    unsigned mid = lo + ((hi - lo) >> 1) + 1u;
    int c = 0;
#pragma unroll
    for (int r = 0; r < 16; ++r) c += (key[r] >= mid) ? 1 : 0;
    c = wave_bsum_i(c);
    if (c >= KSEL) lo = mid; else hi = mid - 1u;
  }

  float p[16];
  float ls = 0.f;
#pragma unroll
  for (int r = 0; r < 16; ++r){
    int n = r * 64 + lane;
    float pp = (n < NN && key[r] >= lo) ? __expf(v[r] - m1) : 0.f;
    p[r] = pp;
    ls += pp;
  }
  ls = wave_bsum(ls);
  float zinv = (ls > 0.f) ? 1.f / ls : 0.f;
  float* w_out = wls + ((long)b * 2 + pool) * 1024;
#pragma unroll
  for (int r = 0; r < 16; ++r){
    int n = r * 64 + lane;
    if (n < NN) w_out[n] = p[r] * zinv;
  }
}
__global__ void k_topk(const int* flags, const float* scf, const float* scd,
                       const void* mark, float* wls){
  if (flags[1]) topk_body<true >(scf, scd, mark, wls);
  else          topk_body<false>(scf, scd, mark, wls);
}

// ---------------- gated partial sums: x_p streamed ONCE for both pools ----------------
__global__ void __launch_bounds__(256) k_psum(
    const float* __restrict__ wls, const float* __restrict__ x_p,
    float* __restrict__ part){
  __shared__ float wf[ROWS], wdd[ROWS];
  int t = threadIdx.x;
  int b = blockIdx.x, z = blockIdx.y;
  int n0 = z * ROWS;
  int ns = min(ROWS, NN - n0);
  if (t < ns){
    wf[t]  = wls[((long)b * 2 + 0) * 1024 + n0 + t];
    wdd[t] = wls[((long)b * 2 + 1) * 1024 + n0 + t];
  }
  __syncthreads();
  float sf = 0.f, mf = -INFINITY, sd = 0.f, md = -INFINITY;
  const float* xb = x_p + ((long)b * NN + n0) * HIDD + t;
  for (int k = 0; k < ns; ++k){
    float xv = xb[(long)k * HIDD];
    float gf = wf[k] * xv;
    float gd = wdd[k] * xv;
    sf += gf; mf = fmaxf(mf, gf);
    sd += gd; md = fmaxf(md, gd);
  }
  long pb = (((long)b * NSPL + z) * 4) * HIDD + t;
  part[pb + 0 * HIDD] = sf;
  part[pb + 1 * HIDD] = mf;
  part[pb + 2 * HIDD] = sd;
  part[pb + 3 * HIDD] = md;
}

// ---------------- final reduce over z-partials ----------------
template<bool F32>
__device__ __forceinline__ void pfin_body(const float* part, void* out){
  int t = threadIdx.x;
  int b = blockIdx.x;
  float sf = 0.f, mf = -INFINITY, sd = 0.f, md = -INFINITY;
#pragma unroll
  for (int z = 0; z < NSPL; ++z){
    long pb = (((long)b * NSPL + z) * 4) * HIDD + t;
    sf += part[pb + 0 * HIDD];
    mf = fmaxf(mf, part[pb + 1 * HIDD]);
    sd += part[pb + 2 * HIDD];
    md = fmaxf(md, part[pb + 3 * HIDD]);
  }
  long ob = (long)b * 1024;
  if (F32){
    ((float*)out)[ob + t] = sf;
    ((float*)out)[ob + 256 + t] = mf;
    ((float*)out)[ob + 512 + t] = sd;
    ((float*)out)[ob + 768 + t] = md;
  } else {
    ((bf16*)out)[ob + t] = __float2bfloat16(sf);
    ((bf16*)out)[ob + 256 + t] = __float2bfloat16(mf);
    ((bf16*)out)[ob + 512 + t] = __float2bfloat16(sd);
    ((bf16*)out)[ob + 768 + t] = __float2bfloat16(md);
  }
}
__global__ void k_pfin(const int* flags, const float* part, void* out){
  if (flags[0]) pfin_body<true >(part, out);
  else          pfin_body<false>(part, out);
}

extern "C" void kernel_launch(void* const* d_in, const int* in_sizes, int n_in,
                              void* d_out, int out_size, void* d_ws, size_t ws_size,
                              hipStream_t stream){
  const int*  time_idx = (const int*)d_in[0];
  const int*  op_idx   = (const int*)d_in[1];
  const void* vfeat    = d_in[2];
  const void* dpcs     = d_in[3];
  const void* adj_comp = d_in[4];
  const void* adj_coop = d_in[5];
  const void* dist     = d_in[6];
  const void* time_tab = d_in[7];
  const void* tp_tab   = d_in[8];
  const void* cs_tab   = d_in[9];
  const void* Wc       = d_in[10];
  const void* asrc_c   = d_in[11];
  const void* adst_c   = d_in[12];
  const void* wd_c     = d_in[13];
  const void* Wco      = d_in[14];
  const void* asrc_co  = d_in[15];
  const void* adst_co  = d_in[16];
  const void* wd_co    = d_in[17];
  const void* Wp       = d_in[18];
  const void* bp       = d_in[19];
  const void* vpd      = d_in[20];
  const void* vpf      = d_in[21];

  char* ws = (char*)d_ws;
  size_t o = 0;
  auto alloc = [&](size_t bytes)->char*{
    char* p = ws + o; o = (o + bytes + 255) & ~(size_t)255; return p;
  };
  int*   flags  = (int*)alloc(16);
  float* wd_ws  = (float*)alloc(8);
  bf16*  distTb = (bf16*)alloc((size_t)NN * DSTRIDE * 2);
  u64*   adjQc  = (u64*)alloc((size_t)NB * 16 * 1024 * 8);
  u64*   adjQo  = (u64*)alloc((size_t)NB * 16 * 1024 * 8);
  float* x_ws   = (float*)alloc((size_t)NB * NN * 15 * 4);
  float* comp   = (float*)alloc((size_t)NB * NN * COMD * 4);
  float* coop   = (float*)alloc((size_t)NB * NN * COMD * 4);
  short* hB_hi  = (short*)alloc((size_t)NB * 65536 * 2);
  short* hB_lo  = (short*)alloc((size_t)NB * 65536 * 2);
  short* WpB_hi = (short*)alloc((size_t)5 * 4 * 256 * 8 * 2);
  short* WpB_lo = (short*)alloc((size_t)5 * 4 * 256 * 8 * 2);
  float* wv_ws  = (float*)alloc(322 * 4);
  float* ed_c   = (float*)alloc((size_t)NB * NN * 4 + 256);  // slack: float4/pad overreads
  float* es_c   = (float*)alloc((size_t)NB * NN * 4 + 256);
  float* ed_o   = (float*)alloc((size_t)NB * NN * 4 + 256);
  float* es_o   = (float*)alloc((size_t)NB * NN * 4 + 256);
  float* scf    = (float*)alloc((size_t)NB * NN * 4);
  float* scd    = (float*)alloc((size_t)NB * NN * 4);
  float* wls    = (float*)alloc((size_t)NB * 2 * 1024 * 4);
  float* part   = (float*)alloc((size_t)NB * NSPL * 4 * HIDD * 4);
  float* x_p    = (float*)alloc((size_t)NB * NN * HIDD * 4);

  k_sniff<<<1, 64, 0, stream>>>(dist, adj_comp, wd_c, wd_co, flags, wd_ws);
  k_wprep<<<dim3(161), dim3(64), 0, stream>>>(flags, Wp, vpd, vpf, bp, WpB_hi, WpB_lo, wv_ws);
  k_dist_t<<<dim3(16, 16), dim3(256), 0, stream>>>(flags, dist, distTb);
  dim3 qg(16, 16, NB);
  k_adjq<<<qg, dim3(256), 0, stream>>>(flags, adj_comp, adjQc);
  k_adjq<<<qg, dim3(256), 0, stream>>>(flags, adj_coop, adjQo);
  k_embed<<<dim3(NB * NN / 4), dim3(256), 0, stream>>>(
      flags, op_idx, vfeat, cs_tab, tp_tab, Wc, asrc_c, adst_c,
      x_ws, hB_hi, hB_lo, ed_c, es_c);
  k_gat<<<dim3((NN + TI - 1) / TI, NB), dim3(256), 0, stream>>>(
      ed_c, es_c, wd_ws, 0, adjQc, distTb, hB_hi, hB_lo, comp);
  k_hco<<<dim3(NB * NN / 4), dim3(256), 0, stream>>>(
      flags, x_ws, comp, Wco, asrc_co, adst_co, hB_hi, hB_lo, ed_o, es_o);
  k_gat<<<dim3((NN + TI - 1) / TI, NB), dim3(256), 0, stream>>>(
      ed_o, es_o, wd_ws, 1, adjQo, distTb, hB_hi, hB_lo, coop);
  k_xp<<<dim3(NB * NN / 16), dim3(256), 0, stream>>>(
      flags, time_idx, op_idx, vfeat, time_tab, cs_tab, tp_tab, comp, coop,
      WpB_hi, WpB_lo, wv_ws, bp, x_p, scf, scd);
  k_topk<<<dim3(NB, 2), dim3(64), 0, stream>>>(flags, scf, scd, dpcs, wls);
  k_psum<<<dim3(NB, NSPL), dim3(256), 0, stream>>>(wls, x_p, part);
  k_pfin<<<dim3(NB), dim3(256), 0, stream>>>(flags, part, d_out);
}